// Round 8
// baseline (1479.919 us; speedup 1.0000x reference)
//
#include <hip/hip_runtime.h>
#include <math.h>

#define N_PIX (512*512)
#define NB 156
#define GH 64

typedef unsigned short u16;
typedef __attribute__((ext_vector_type(8))) short bfrag8;   // 8 bf16 = 4 VGPRs
typedef __attribute__((ext_vector_type(4))) float f32x4;    // MFMA accumulator

// ---------- bf16 split helpers (RNE) ----------
__device__ __forceinline__ u16 f2bf(float x){
  unsigned u = __float_as_uint(x);
  unsigned r = (u + 0x7FFFu + ((u >> 16) & 1u)) >> 16;
  return (u16)r;
}
__device__ __forceinline__ float bf2f(u16 h){
  return __uint_as_float(((unsigned)h) << 16);
}

__device__ __forceinline__ float waveReduceMax(float v){
  #pragma unroll
  for(int o=32;o>0;o>>=1) v = fmaxf(v, __shfl_down(v, o, 64));
  return v;
}
__device__ __forceinline__ float waveReduceSum(float v){
  #pragma unroll
  for(int o=32;o>0;o>>=1) v += __shfl_down(v, o, 64);
  return v;
}

// ---------- derived constants: softmax(scale_weights), clip(alpha) ----------
__global__ void k_prep(const float* __restrict__ sw, const float* __restrict__ alpha, float* __restrict__ cst){
  if(threadIdx.x==0 && blockIdx.x==0){
    float m = fmaxf(sw[0], fmaxf(sw[1], sw[2]));
    float e0=expf(sw[0]-m), e1=expf(sw[1]-m), e2=expf(sw[2]-m);
    float s = e0+e1+e2;
    cst[0]=e0/s; cst[1]=e1/s; cst[2]=e2/s;
    cst[3]=fminf(fmaxf(alpha[0],0.f),1.f);
  }
}

// ---------- CSR build ----------
__global__ void k_count(const int* __restrict__ s0, const int* __restrict__ s1, const int* __restrict__ s2,
                        int* c0, int* c1, int* c2){
  int p = blockIdx.x*256 + threadIdx.x;
  if(p < N_PIX){
    atomicAdd(&c0[s0[p]],1);
    atomicAdd(&c1[s1[p]],1);
    atomicAdd(&c2[s2[p]],1);
  }
}

__global__ __launch_bounds__(256) void k_scan(const int* __restrict__ c0, const int* __restrict__ c1, const int* __restrict__ c2,
                       int* o0, int* o1, int* o2, int* u0, int* u1, int* u2){
  const int* cnt; int* offs; int* cur; int n;
  if(blockIdx.x==0){ cnt=c0; offs=o0; cur=u0; n=2000; }
  else if(blockIdx.x==1){ cnt=c1; offs=o1; cur=u1; n=1000; }
  else { cnt=c2; offs=o2; cur=u2; n=500; }
  __shared__ int l[2048];
  __shared__ int cs[256];
  int t = threadIdx.x;
  for(int i=t;i<2048;i+=256) l[i] = (i<n) ? cnt[i] : 0;
  __syncthreads();
  int s = 0;
  #pragma unroll
  for(int j=0;j<8;j++) s += l[t*8+j];
  cs[t] = s;
  __syncthreads();
  for(int d=1; d<256; d<<=1){
    int v = (t>=d) ? cs[t-d] : 0;
    __syncthreads();
    cs[t] += v;
    __syncthreads();
  }
  int run = cs[t] - s;
  for(int j=0;j<8;j++){
    int idx = t*8+j;
    int o = run;
    run += l[idx];
    if(idx < n){ offs[idx] = o; cur[idx] = o; }
  }
}

__global__ void k_fill(const int* __restrict__ s0, const int* __restrict__ s1, const int* __restrict__ s2,
                       int* u0, int* u1, int* u2, int* L0, int* L1, int* L2){
  int p = blockIdx.x*256 + threadIdx.x;
  if(p < N_PIX){
    int a = atomicAdd(&u0[s0[p]],1); L0[a] = p;
    int b = atomicAdd(&u1[s1[p]],1); L1[b] = p;
    int c = atomicAdd(&u2[s2[p]],1); L2[c] = p;
  }
}

// ---------- fused segment mean over all 3 scales ----------
__global__ __launch_bounds__(128) void k_segmean3(const float* __restrict__ Y,
    const int* __restrict__ o0, const int* __restrict__ c0, const int* __restrict__ l0, float* __restrict__ X0,
    const int* __restrict__ o1, const int* __restrict__ c1, const int* __restrict__ l1, float* __restrict__ X1,
    const int* __restrict__ o2, const int* __restrict__ c2, const int* __restrict__ l2, float* __restrict__ X2){
  int b = blockIdx.x;
  const int *offs, *cnt, *list; float* X; int s;
  if(b < 2000){ s=b;      offs=o0; cnt=c0; list=l0; X=X0; }
  else if(b < 3000){ s=b-2000; offs=o1; cnt=c1; list=l1; X=X1; }
  else { s=b-3000; offs=o2; cnt=c2; list=l2; X=X2; }
  int t = threadIdx.x;
  int n = cnt[s], st = offs[s];
  if(t < 78){
    float ax=0.f, ay=0.f;
    int q = 0;
    for(; q+4<=n; q+=4){
      int p0 = list[st+q], p1 = list[st+q+1], p2 = list[st+q+2], p3 = list[st+q+3];
      float2 v0 = *(const float2*)(Y + (size_t)p0*NB + t*2);
      float2 v1 = *(const float2*)(Y + (size_t)p1*NB + t*2);
      float2 v2 = *(const float2*)(Y + (size_t)p2*NB + t*2);
      float2 v3 = *(const float2*)(Y + (size_t)p3*NB + t*2);
      ax += (v0.x + v1.x) + (v2.x + v3.x);
      ay += (v0.y + v1.y) + (v2.y + v3.y);
    }
    for(; q<n; q++){
      int p0 = list[st+q];
      float2 v0 = *(const float2*)(Y + (size_t)p0*NB + t*2);
      ax += v0.x; ay += v0.y;
    }
    float inv = 1.f / fmaxf((float)n, 1.f);
    float2 r; r.x = ax*inv; r.y = ay*inv;
    *(float2*)(X + (size_t)s*NB + t*2) = r;
  }
}

// ---------- generic small linear: out[n,D] = X[n,K]@W[K,D]+b ----------
__global__ void k_linear(const float* __restrict__ X, const float* __restrict__ W, const float* __restrict__ bias,
                         float* __restrict__ out, int n, int K, int D){
  int gid = blockIdx.x*256 + threadIdx.x;
  if(gid >= n*D) return;
  int r = gid / D, c = gid - r*D;
  const float* xr = X + (size_t)r*K;
  float acc = bias[c];
  for(int k=0;k<K;k++) acc = fmaf(xr[k], W[(size_t)k*D + c], acc);
  out[gid] = acc;
}

// ---------- GAT masked attention, 4 rows per block ----------
template<int D, bool FINAL>
__global__ __launch_bounds__(256) void k_attn4(const float* __restrict__ Hn, const int* __restrict__ A,
                                               float* __restrict__ out, int n){
  __shared__ float sc[4][2048];
  __shared__ float hr[4][GH];
  __shared__ float redm[4][4];
  __shared__ float outp[4][4][GH];   // part, r, c (D==64)
  __shared__ float out3[4][4][4];    // wave, r, c (D==3)
  const int t = threadIdx.x, w = t>>6, lane = t&63;
  const int r0 = blockIdx.x*4;
  if(D==GH){
    hr[w][lane] = Hn[(size_t)(r0 + w)*GH + lane];
  } else {
    if(t < 12) hr[t/3][t%3] = Hn[(size_t)(r0 + t/3)*3 + (t%3)];
  }
  __syncthreads();
  float lm0=-INFINITY, lm1=-INFINITY, lm2=-INFINITY, lm3=-INFINITY;
  for(int j=t; j<n; j+=256){
    float s0,s1,s2,s3;
    if(D==GH){
      const float4* hj = (const float4*)(Hn + (size_t)j*GH);
      s0=s1=s2=s3=0.f;
      #pragma unroll
      for(int k4=0;k4<GH/4;k4++){
        float4 h  = hj[k4];
        float4 a0 = *(const float4*)&hr[0][k4*4];
        float4 a1 = *(const float4*)&hr[1][k4*4];
        float4 a2 = *(const float4*)&hr[2][k4*4];
        float4 a3 = *(const float4*)&hr[3][k4*4];
        s0 = fmaf(a0.x,h.x, fmaf(a0.y,h.y, fmaf(a0.z,h.z, fmaf(a0.w,h.w, s0))));
        s1 = fmaf(a1.x,h.x, fmaf(a1.y,h.y, fmaf(a1.z,h.z, fmaf(a1.w,h.w, s1))));
        s2 = fmaf(a2.x,h.x, fmaf(a2.y,h.y, fmaf(a2.z,h.z, fmaf(a2.w,h.w, s2))));
        s3 = fmaf(a3.x,h.x, fmaf(a3.y,h.y, fmaf(a3.z,h.z, fmaf(a3.w,h.w, s3))));
      }
    } else {
      float h0=Hn[(size_t)j*3+0], h1=Hn[(size_t)j*3+1], h2=Hn[(size_t)j*3+2];
      s0 = hr[0][0]*h0 + hr[0][1]*h1 + hr[0][2]*h2;
      s1 = hr[1][0]*h0 + hr[1][1]*h1 + hr[1][2]*h2;
      s2 = hr[2][0]*h0 + hr[2][1]*h1 + hr[2][2]*h2;
      s3 = hr[3][0]*h0 + hr[3][1]*h1 + hr[3][2]*h2;
    }
    int m0 = A[(size_t)(r0+0)*n + j];
    int m1 = A[(size_t)(r0+1)*n + j];
    int m2 = A[(size_t)(r0+2)*n + j];
    int m3 = A[(size_t)(r0+3)*n + j];
    s0 = (m0>0) ? s0 : -1e9f;
    s1 = (m1>0) ? s1 : -1e9f;
    s2 = (m2>0) ? s2 : -1e9f;
    s3 = (m3>0) ? s3 : -1e9f;
    sc[0][j]=s0; sc[1][j]=s1; sc[2][j]=s2; sc[3][j]=s3;
    lm0=fmaxf(lm0,s0); lm1=fmaxf(lm1,s1); lm2=fmaxf(lm2,s2); lm3=fmaxf(lm3,s3);
  }
  {
    float w0=waveReduceMax(lm0), w1=waveReduceMax(lm1), w2=waveReduceMax(lm2), w3=waveReduceMax(lm3);
    if(lane==0){ redm[0][w]=w0; redm[1][w]=w1; redm[2][w]=w2; redm[3][w]=w3; }
  }
  __syncthreads();
  float m[4];
  #pragma unroll
  for(int r=0;r<4;r++) m[r] = fmaxf(fmaxf(redm[r][0],redm[r][1]), fmaxf(redm[r][2],redm[r][3]));
  __syncthreads();
  float ls0=0.f, ls1=0.f, ls2=0.f, ls3=0.f;
  for(int j=t; j<n; j+=256){
    float e0=expf(sc[0][j]-m[0]); sc[0][j]=e0; ls0+=e0;
    float e1=expf(sc[1][j]-m[1]); sc[1][j]=e1; ls1+=e1;
    float e2=expf(sc[2][j]-m[2]); sc[2][j]=e2; ls2+=e2;
    float e3=expf(sc[3][j]-m[3]); sc[3][j]=e3; ls3+=e3;
  }
  {
    float w0=waveReduceSum(ls0), w1=waveReduceSum(ls1), w2=waveReduceSum(ls2), w3=waveReduceSum(ls3);
    if(lane==0){ redm[0][w]=w0; redm[1][w]=w1; redm[2][w]=w2; redm[3][w]=w3; }
  }
  __syncthreads();   // sums visible AND all sc exp-writes visible
  float S[4];
  #pragma unroll
  for(int r=0;r<4;r++) S[r] = redm[r][0]+redm[r][1]+redm[r][2]+redm[r][3];
  if(D==GH){
    float acc0=0.f, acc1=0.f, acc2=0.f, acc3=0.f;
    const int c = lane, part = w;
    #pragma unroll 2
    for(int j=part; j<n; j+=4){
      float hv = Hn[(size_t)j*GH + c];
      acc0 = fmaf(sc[0][j], hv, acc0);
      acc1 = fmaf(sc[1][j], hv, acc1);
      acc2 = fmaf(sc[2][j], hv, acc2);
      acc3 = fmaf(sc[3][j], hv, acc3);
    }
    outp[part][0][c]=acc0; outp[part][1][c]=acc1; outp[part][2][c]=acc2; outp[part][3][c]=acc3;
    __syncthreads();
    int r = w;
    float tot = outp[0][r][lane]+outp[1][r][lane]+outp[2][r][lane]+outp[3][r][lane];
    out[(size_t)(r0+r)*GH + lane] = fmaxf(tot/S[r], 0.f);
  } else {
    float a00=0,a01=0,a02=0, a10=0,a11=0,a12=0, a20=0,a21=0,a22=0, a30=0,a31=0,a32=0;
    for(int j=t; j<n; j+=256){
      float h0=Hn[(size_t)j*3+0], h1=Hn[(size_t)j*3+1], h2=Hn[(size_t)j*3+2];
      float e0=sc[0][j], e1=sc[1][j], e2=sc[2][j], e3=sc[3][j];
      a00=fmaf(e0,h0,a00); a01=fmaf(e0,h1,a01); a02=fmaf(e0,h2,a02);
      a10=fmaf(e1,h0,a10); a11=fmaf(e1,h1,a11); a12=fmaf(e1,h2,a12);
      a20=fmaf(e2,h0,a20); a21=fmaf(e2,h1,a21); a22=fmaf(e2,h2,a22);
      a30=fmaf(e3,h0,a30); a31=fmaf(e3,h1,a31); a32=fmaf(e3,h2,a32);
    }
    float v[12] = {a00,a01,a02,a10,a11,a12,a20,a21,a22,a30,a31,a32};
    #pragma unroll
    for(int i=0;i<12;i++){
      float ws = waveReduceSum(v[i]);
      if(lane==0) out3[w][i/3][i%3] = ws;
    }
    __syncthreads();
    if(t < 4){
      int r = t;
      float t0 = out3[0][r][0]+out3[1][r][0]+out3[2][r][0]+out3[3][r][0];
      float t1 = out3[0][r][1]+out3[1][r][1]+out3[2][r][1]+out3[3][r][1];
      float t2 = out3[0][r][2]+out3[1][r][2]+out3[2][r][2]+out3[3][r][2];
      float v0 = fmaxf(t0/S[r], 0.f);
      float v1 = fmaxf(t1/S[r], 0.f);
      float v2 = fmaxf(t2/S[r], 0.f);
      if(FINAL){
        float mm = fmaxf(v0, fmaxf(v1,v2));
        float e0=expf(v0-mm), e1=expf(v1-mm), e2=expf(v2-mm);
        float ss = e0+e1+e2;
        out[(size_t)(r0+r)*3+0]=e0/ss; out[(size_t)(r0+r)*3+1]=e1/ss; out[(size_t)(r0+r)*3+2]=e2/ss;
      } else {
        out[(size_t)(r0+r)*3+0]=v0; out[(size_t)(r0+r)*3+1]=v1; out[(size_t)(r0+r)*3+2]=v2;
      }
    }
  }
}

// ---------- fuse scales (no atomics) ----------
__global__ void k_fuse(const int* __restrict__ s0, const int* __restrict__ s1, const int* __restrict__ s2,
                       const float* __restrict__ S0, const float* __restrict__ S1, const float* __restrict__ S2,
                       const float* __restrict__ cst, float* __restrict__ fused){
  int p = blockIdx.x*256 + threadIdx.x;
  if(p >= N_PIX) return;
  float w0=cst[0], w1=cst[1], w2=cst[2];
  int a=s0[p], b=s1[p], c=s2[p];
  #pragma unroll
  for(int e=0;e<3;e++){
    float f = w0*S0[a*3+e] + w1*S1[b*3+e] + w2*S2[c*3+e];
    fused[(size_t)p*3+e] = f;
  }
}

// ---------- superpixel sums of fused via CSR gather (replaces 786k global atomics) ----------
__global__ __launch_bounds__(128) void k_spsum0(const float* __restrict__ fused, const int* __restrict__ offs,
                                                const int* __restrict__ cnt, const int* __restrict__ list,
                                                float* __restrict__ spsum){
  __shared__ float r[2][3];
  int s = blockIdx.x;
  int t = threadIdx.x, w = t>>6, lane = t&63;
  int n = cnt[s], st = offs[s];
  float a0=0.f, a1=0.f, a2=0.f;
  for(int q=t; q<n; q+=128){
    int p = list[st+q];
    a0 += fused[(size_t)p*3+0];
    a1 += fused[(size_t)p*3+1];
    a2 += fused[(size_t)p*3+2];
  }
  a0 = waveReduceSum(a0); a1 = waveReduceSum(a1); a2 = waveReduceSum(a2);
  if(lane==0){ r[w][0]=a0; r[w][1]=a1; r[w][2]=a2; }
  __syncthreads();
  if(t==0){
    spsum[s*3+0]=r[0][0]+r[1][0];
    spsum[s*3+1]=r[0][1]+r[1][1];
    spsum[s*3+2]=r[0][2]+r[1][2];
  }
}

// ---------- PCR: smoothed_sp[r] = softmax(attn[r]) @ (spsum/cnt) ----------
__global__ __launch_bounds__(256) void k_pcr(const float* __restrict__ attn, const float* __restrict__ spsum,
                                             const int* __restrict__ cnt0, float* __restrict__ sm){
  __shared__ float buf[2048];
  __shared__ float red[4];
  __shared__ float r3[256][3];
  int r=blockIdx.x, t=threadIdx.x;
  float lmax=-INFINITY;
  for(int j=t;j<2000;j+=256){ float v=attn[(size_t)r*2000+j]; buf[j]=v; lmax=fmaxf(lmax,v); }
  float wm=waveReduceMax(lmax);
  if((t&63)==0) red[t>>6]=wm;
  __syncthreads();
  float m = fmaxf(fmaxf(red[0],red[1]),fmaxf(red[2],red[3]));
  __syncthreads();
  float lsum=0.f;
  for(int j=t;j<2000;j+=256){ float e=expf(buf[j]-m); buf[j]=e; lsum+=e; }
  float wsu=waveReduceSum(lsum);
  if((t&63)==0) red[t>>6]=wsu;
  __syncthreads();
  float S=red[0]+red[1]+red[2]+red[3];
  float a0=0.f,a1=0.f,a2=0.f;
  for(int j=t;j<2000;j+=256){
    float e=buf[j];
    float inv = 1.f / fmaxf((float)cnt0[j], 1.f);
    a0=fmaf(e, spsum[j*3+0]*inv, a0);
    a1=fmaf(e, spsum[j*3+1]*inv, a1);
    a2=fmaf(e, spsum[j*3+2]*inv, a2);
  }
  r3[t][0]=a0; r3[t][1]=a1; r3[t][2]=a2;
  __syncthreads();
  for(int st=128;st>0;st>>=1){
    if(t<st){ r3[t][0]+=r3[t+st][0]; r3[t][1]+=r3[t+st][1]; r3[t][2]+=r3[t+st][2]; }
    __syncthreads();
  }
  if(t==0){ sm[r*3+0]=r3[0][0]/S; sm[r*3+1]=r3[0][1]/S; sm[r*3+2]=r3[0][2]/S; }
}

// ---------- S_flat + argmax class index ----------
__global__ void k_sflat(const float* __restrict__ fused, const int* __restrict__ s0,
                        const float* __restrict__ sm, const float* __restrict__ cst,
                        float* __restrict__ Sf, int* __restrict__ ci){
  int p = blockIdx.x*256 + threadIdx.x;
  if(p >= N_PIX) return;
  float a = cst[3];
  int s = s0[p];
  float x0 = a*sm[s*3+0] + (1.f-a)*fused[(size_t)p*3+0];
  float x1 = a*sm[s*3+1] + (1.f-a)*fused[(size_t)p*3+1];
  float x2 = a*sm[s*3+2] + (1.f-a)*fused[(size_t)p*3+2];
  Sf[(size_t)p*3+0]=x0; Sf[(size_t)p*3+1]=x1; Sf[(size_t)p*3+2]=x2;
  int c=0; float b=x0;
  if(x1>b){c=1;b=x1;}
  if(x2>b){c=2;}
  ci[p]=c;
}

// ---------- weight pre-pack into MFMA B-fragment order, bf16 hi/lo ----------
__global__ void k_packw(const float* __restrict__ W, int Kreal, int Nreal, int nkt, int nnt,
                        u16* __restrict__ dhi, u16* __restrict__ dlo){
  int gid = blockIdx.x*256 + threadIdx.x;
  int total = nnt*nkt*512;
  if(gid >= total) return;
  int j = gid & 7, l = (gid>>3)&63;
  int rem = gid >> 9;               // nt*nkt + ks
  int ks = rem % nkt;
  int nt = rem / nkt;
  int k = ks*32 + (l>>4)*8 + j;
  int n = nt*16 + (l&15);
  float w = (k < Kreal && n < Nreal) ? W[(size_t)k*Nreal + n] : 0.f;
  u16 hi = f2bf(w);
  dhi[gid] = hi;
  dlo[gid] = f2bf(w - bf2f(hi));
}

// ---------- MFMA MLP (156->128->128->156) + one-pass per-class exp sums ----------
// MODE 0: full (real).  MODE 1: no epilogue.  MODE 2: no per-ks B loads (+no epi).  MODE 3: stage only.
#define MFMA(a,b,c) __builtin_amdgcn_mfma_f32_16x16x32_bf16((a),(b),(c),0,0,0)

template<int MODE>
__global__ __launch_bounds__(256, 4) void k_mlp_mfma(
    const float* __restrict__ Y, const int* __restrict__ ci,
    const u16* __restrict__ P1h, const u16* __restrict__ P1l,
    const u16* __restrict__ P2h, const u16* __restrict__ P2l,
    const u16* __restrict__ P3h, const u16* __restrict__ P3l,
    const float* __restrict__ b1, const float* __restrict__ b2, const float* __restrict__ b3,
    float* __restrict__ gsum, float* __restrict__ gwsum){
  __shared__ u16 SH[32*168];                 // X-hi [32][168]  ->  A-hi [32][136]
  __shared__ u16 SL[32*168];                 // X-lo            ->  A-lo
  __shared__ float csum[480], cwsum[480];    // per-class partial sums [3][160]
  __shared__ int cis[32];
  const int t = threadIdx.x;
  const int lane = t & 63, w = t >> 6;
  const int g = lane >> 4, r16 = lane & 15;
  const size_t p0 = (size_t)blockIdx.x * 32;

  if(MODE==0){
    for(int i=t;i<480;i+=256){ csum[i]=0.f; cwsum[i]=0.f; }
    if(t<32) cis[t] = ci[p0+t];
  }
  // stage Y tile: 32 rows x 39 float4, split to bf16 hi/lo, packed u32 LDS writes
  for(int i=t;i<1248;i+=256){
    int row = i/39, q = i - row*39, c0 = q*4;
    float4 v = *(const float4*)(Y + (p0+row)*NB + c0);
    u16 h0=f2bf(v.x), h1=f2bf(v.y), h2=f2bf(v.z), h3=f2bf(v.w);
    u16 l0=f2bf(v.x-bf2f(h0)), l1=f2bf(v.y-bf2f(h1)), l2=f2bf(v.z-bf2f(h2)), l3=f2bf(v.w-bf2f(h3));
    *(unsigned*)&SH[row*168+c0]   = (unsigned)h0 | ((unsigned)h1<<16);
    *(unsigned*)&SH[row*168+c0+2] = (unsigned)h2 | ((unsigned)h3<<16);
    *(unsigned*)&SL[row*168+c0]   = (unsigned)l0 | ((unsigned)l1<<16);
    *(unsigned*)&SL[row*168+c0+2] = (unsigned)l2 | ((unsigned)l3<<16);
  }
  if(t<64){ int row=t>>1, o=156+(t&1)*2;
    *(unsigned*)&SH[row*168+o]=0u; *(unsigned*)&SL[row*168+o]=0u; }
  __syncthreads();

  if(MODE==3){  // stage-only: read back, keep live, exit
    float z = bf2f(SH[t*2]) + bf2f(SL[t*2]);
    asm volatile("" :: "v"(z));
    return;
  }

  // MODE 2: single preloaded fragment reused for all B operands
  bfrag8 fixh, fixl;
  if(MODE==2){
    fixh = *(const bfrag8*)(P1h + (size_t)lane*8);
    fixl = *(const bfrag8*)(P1l + (size_t)lane*8);
  }

  // ---- layer 1: K=160 (5 ks), N=128; wave w -> ntiles {w, w+4} ----
  {
    f32x4 acc[2][2];
    #pragma unroll
    for(int u=0;u<2;u++)
      #pragma unroll
      for(int mt=0;mt<2;mt++) acc[u][mt] = (f32x4){0.f,0.f,0.f,0.f};
    #pragma unroll
    for(int ks=0;ks<5;ks++){
      bfrag8 bh0, bl0, bh1, bl1;
      if(MODE==2){ bh0=fixh; bl0=fixl; bh1=fixh; bl1=fixl; }
      else{
        bh0 = *(const bfrag8*)(P1h + ((size_t)(w*5+ks))*512 + lane*8);
        bl0 = *(const bfrag8*)(P1l + ((size_t)(w*5+ks))*512 + lane*8);
        bh1 = *(const bfrag8*)(P1h + ((size_t)((w+4)*5+ks))*512 + lane*8);
        bl1 = *(const bfrag8*)(P1l + ((size_t)((w+4)*5+ks))*512 + lane*8);
      }
      #pragma unroll
      for(int mt=0;mt<2;mt++){
        bfrag8 ah = *(const bfrag8*)(SH + (mt*16+r16)*168 + g*8 + ks*32);
        bfrag8 al = *(const bfrag8*)(SL + (mt*16+r16)*168 + g*8 + ks*32);
        acc[0][mt]=MFMA(ah,bh0,acc[0][mt]); acc[0][mt]=MFMA(ah,bl0,acc[0][mt]); acc[0][mt]=MFMA(al,bh0,acc[0][mt]);
        acc[1][mt]=MFMA(ah,bh1,acc[1][mt]); acc[1][mt]=MFMA(ah,bl1,acc[1][mt]); acc[1][mt]=MFMA(al,bh1,acc[1][mt]);
      }
    }
    __syncthreads();   // all waves done reading X
    #pragma unroll
    for(int u=0;u<2;u++){
      int c = (w+u*4)*16 + r16;
      float bv = b1[c];
      #pragma unroll
      for(int mt=0;mt<2;mt++)
        #pragma unroll
        for(int r=0;r<4;r++){
          float v = fmaxf(acc[u][mt][r] + bv, 0.f);
          int row = mt*16 + g*4 + r;
          u16 h = f2bf(v);
          SH[row*136+c] = h; SL[row*136+c] = f2bf(v - bf2f(h));
        }
    }
  }
  __syncthreads();

  // ---- layer 2: K=128 (4 ks), N=128; regs across barrier, overwrite A ----
  {
    f32x4 acc[2][2];
    #pragma unroll
    for(int u=0;u<2;u++)
      #pragma unroll
      for(int mt=0;mt<2;mt++) acc[u][mt] = (f32x4){0.f,0.f,0.f,0.f};
    #pragma unroll
    for(int ks=0;ks<4;ks++){
      bfrag8 bh0, bl0, bh1, bl1;
      if(MODE==2){ bh0=fixh; bl0=fixl; bh1=fixh; bl1=fixl; }
      else{
        bh0 = *(const bfrag8*)(P2h + ((size_t)(w*4+ks))*512 + lane*8);
        bl0 = *(const bfrag8*)(P2l + ((size_t)(w*4+ks))*512 + lane*8);
        bh1 = *(const bfrag8*)(P2h + ((size_t)((w+4)*4+ks))*512 + lane*8);
        bl1 = *(const bfrag8*)(P2l + ((size_t)((w+4)*4+ks))*512 + lane*8);
      }
      #pragma unroll
      for(int mt=0;mt<2;mt++){
        bfrag8 ah = *(const bfrag8*)(SH + (mt*16+r16)*136 + g*8 + ks*32);
        bfrag8 al = *(const bfrag8*)(SL + (mt*16+r16)*136 + g*8 + ks*32);
        acc[0][mt]=MFMA(ah,bh0,acc[0][mt]); acc[0][mt]=MFMA(ah,bl0,acc[0][mt]); acc[0][mt]=MFMA(al,bh0,acc[0][mt]);
        acc[1][mt]=MFMA(ah,bh1,acc[1][mt]); acc[1][mt]=MFMA(ah,bl1,acc[1][mt]); acc[1][mt]=MFMA(al,bh1,acc[1][mt]);
      }
    }
    __syncthreads();   // all waves done reading A(layer1)
    #pragma unroll
    for(int u=0;u<2;u++){
      int c = (w+u*4)*16 + r16;
      float bv = b2[c];
      #pragma unroll
      for(int mt=0;mt<2;mt++)
        #pragma unroll
        for(int r=0;r<4;r++){
          float v = fmaxf(acc[u][mt][r] + bv, 0.f);
          int row = mt*16 + g*4 + r;
          u16 h = f2bf(v);
          SH[row*136+c] = h; SL[row*136+c] = f2bf(v - bf2f(h));
        }
    }
  }
  __syncthreads();

  // ---- layer 3: K=128, 20 subtiles over 4 waves (5 chains/wave) ----
  {
    f32x4 acc[5];
    #pragma unroll
    for(int s=0;s<5;s++) acc[s] = (f32x4){0.f,0.f,0.f,0.f};
    #pragma unroll
    for(int s=0;s<5;s++){
      int idx = w*5 + s, nt = idx>>1, mt = idx&1;
      #pragma unroll
      for(int ks=0;ks<4;ks++){
        bfrag8 bh, bl;
        if(MODE==2){ bh=fixh; bl=fixl; }
        else{
          bh = *(const bfrag8*)(P3h + ((size_t)(nt*4+ks))*512 + lane*8);
          bl = *(const bfrag8*)(P3l + ((size_t)(nt*4+ks))*512 + lane*8);
        }
        bfrag8 ah = *(const bfrag8*)(SH + (mt*16+r16)*136 + g*8 + ks*32);
        bfrag8 al = *(const bfrag8*)(SL + (mt*16+r16)*136 + g*8 + ks*32);
        acc[s]=MFMA(ah,bh,acc[s]); acc[s]=MFMA(ah,bl,acc[s]); acc[s]=MFMA(al,bh,acc[s]);
      }
    }
    if(MODE!=0){  // diagnostic: keep results live, no epilogue
      float z = 0.f;
      #pragma unroll
      for(int s=0;s<5;s++) z += acc[s][0] + acc[s][1] + acc[s][2] + acc[s][3];
      asm volatile("" :: "v"(z));
      return;
    }
    #pragma unroll
    for(int s=0;s<5;s++){
      int idx = w*5 + s, nt = idx>>1, mt = idx&1;
      int c = nt*16 + r16;
      if(c < 156){
        float bv = b3[c];
        #pragma unroll
        for(int r=0;r<4;r++){
          int p = mt*16 + g*4 + r;
          float v = acc[s][r] + bv;
          float e = expf(v);
          float y = Y[(p0+p)*NB + c];
          int cls = cis[p];
          atomicAdd(&csum[cls*160 + c], e);
          atomicAdd(&cwsum[cls*160 + c], e*y);
        }
      }
    }
  }
  __syncthreads();
  // plain per-block store (no global atomics)
  float* gs = gsum  + (size_t)blockIdx.x*480;
  float* gw = gwsum + (size_t)blockIdx.x*480;
  for(int i=t;i<480;i+=256){
    gs[i] = csum[i];
    gw[i] = cwsum[i];
  }
}

// ---------- final M: reduce 8192 per-block slots; one block per (cls,c) ----------
__global__ __launch_bounds__(256) void k_finalM(const float* __restrict__ gsump, const float* __restrict__ gwsump,
                                                float* __restrict__ M){
  __shared__ float rs[4], rw[4];
  int e = blockIdx.x;                 // 0..467
  int cls = e/156, c = e - cls*156;
  int off = cls*160 + c;
  int t = threadIdx.x, w = t>>6, lane = t&63;
  float s=0.f, wv=0.f;
  for(int k=t; k<8192; k+=256){
    s  += gsump[(size_t)k*480 + off];
    wv += gwsump[(size_t)k*480 + off];
  }
  s = waveReduceSum(s); wv = waveReduceSum(wv);
  if(lane==0){ rs[w]=s; rw[w]=wv; }
  __syncthreads();
  if(t==0){
    float S = rs[0]+rs[1]+rs[2]+rs[3];
    float W = rw[0]+rw[1]+rw[2]+rw[3];
    M[e] = (S > 0.f) ? (W / fmaxf(S, 1e-30f)) : 0.f;
  }
}

// ---------- Y_hat = S_flat @ M, float4 stores ----------
__global__ void k_yhat4(const float* __restrict__ Sf, const float* __restrict__ M, float4* __restrict__ out){
  unsigned idx = blockIdx.x*256u + threadIdx.x;   // N_PIX*39 float4s, grid exact
  unsigned p = idx / 39u, q = idx - p*39u;
  unsigned c0 = q*4u;
  float4 m0 = *(const float4*)(M + c0);
  float4 m1 = *(const float4*)(M + 156 + c0);
  float4 m2 = *(const float4*)(M + 312 + c0);
  float s0 = Sf[(size_t)p*3+0], s1 = Sf[(size_t)p*3+1], s2 = Sf[(size_t)p*3+2];
  float4 r;
  r.x = s0*m0.x + s1*m1.x + s2*m2.x;
  r.y = s0*m0.y + s1*m1.y + s2*m2.y;
  r.z = s0*m0.z + s1*m1.z + s2*m2.z;
  r.w = s0*m0.w + s1*m1.w + s2*m2.w;
  out[idx] = r;
}

extern "C" void kernel_launch(void* const* d_in, const int* in_sizes, int n_in,
                              void* d_out, int out_size, void* d_ws, size_t ws_size,
                              hipStream_t stream){
  const float* Y    = (const float*)d_in[0];
  const int*   seg0 = (const int*)d_in[1];
  const int*   A0   = (const int*)d_in[2];
  const int*   seg1 = (const int*)d_in[3];
  const int*   A1   = (const int*)d_in[4];
  const int*   seg2 = (const int*)d_in[5];
  const int*   A2   = (const int*)d_in[6];
  const float* attn = (const float*)d_in[7];
  const float* alpha= (const float*)d_in[8];
  const float* sw   = (const float*)d_in[9];
  const float* W1a[3] = {(const float*)d_in[10], (const float*)d_in[14], (const float*)d_in[18]};
  const float* b1a[3] = {(const float*)d_in[11], (const float*)d_in[15], (const float*)d_in[19]};
  const float* W2a[3] = {(const float*)d_in[12], (const float*)d_in[16], (const float*)d_in[20]};
  const float* b2a[3] = {(const float*)d_in[13], (const float*)d_in[17], (const float*)d_in[21]};
  const float* Wm1=(const float*)d_in[22]; const float* bm1=(const float*)d_in[23];
  const float* Wm2=(const float*)d_in[24]; const float* bm2=(const float*)d_in[25];
  const float* Wm3=(const float*)d_in[26]; const float* bm3=(const float*)d_in[27];
  float* out = (float*)d_out;

  const int nseg[3] = {2000, 1000, 500};
  const int* Aarr[3]   = {A0, A1, A2};

  char* base = (char*)d_ws;
  size_t off = 0;
  auto alloc = [&](size_t bytes)->char*{
    char* r = base + off;
    off += (bytes + 255) & ~(size_t)255;
    return r;
  };
  int* cnt[3]; int* offs[3]; int* cur[3]; int* lst[3]; float* X[3]; float* Ss[3];
  for(int i=0;i<3;i++) cnt[i]  = (int*)alloc((size_t)nseg[i]*4);
  for(int i=0;i<3;i++) offs[i] = (int*)alloc((size_t)nseg[i]*4);
  for(int i=0;i<3;i++) cur[i]  = (int*)alloc((size_t)nseg[i]*4);
  for(int i=0;i<3;i++) lst[i]  = (int*)alloc((size_t)N_PIX*4);
  for(int i=0;i<3;i++) X[i]    = (float*)alloc((size_t)nseg[i]*NB*4);
  float* Hn   = (float*)alloc((size_t)2000*64*4);
  float* x1b  = (float*)alloc((size_t)2000*64*4);
  float* Hn2  = (float*)alloc((size_t)2000*3*4);
  for(int i=0;i<3;i++) Ss[i]   = (float*)alloc((size_t)nseg[i]*3*4);
  float* cst   = (float*)alloc(64);
  float* fused = (float*)alloc((size_t)N_PIX*3*4);
  float* spsum = (float*)alloc((size_t)2000*3*4);
  float* smth  = (float*)alloc((size_t)2000*3*4);
  float* Sf    = (float*)alloc((size_t)N_PIX*3*4);
  int*   ci    = (int*)alloc((size_t)N_PIX*4);
  u16* P1h = (u16*)alloc((size_t)20480*2); u16* P1l = (u16*)alloc((size_t)20480*2);
  u16* P2h = (u16*)alloc((size_t)16384*2); u16* P2l = (u16*)alloc((size_t)16384*2);
  u16* P3h = (u16*)alloc((size_t)20480*2); u16* P3l = (u16*)alloc((size_t)20480*2);
  float* gsump  = (float*)alloc((size_t)8192*480*4);
  float* gwsump = (float*)alloc((size_t)8192*480*4);
  float* Mbuf   = (float*)alloc((size_t)480*4);

  // per-call re-init (replay/poison safe); gsump/gwsump fully overwritten by stores
  for(int i=0;i<3;i++) hipMemsetAsync(cnt[i], 0, (size_t)nseg[i]*4, stream);
  k_prep<<<1,64,0,stream>>>(sw, alpha, cst);

  // weight pre-pack
  k_packw<<<(8*5*512+255)/256,256,0,stream>>>(Wm1, 156, 128, 5, 8, P1h, P1l);
  k_packw<<<(8*4*512+255)/256,256,0,stream>>>(Wm2, 128, 128, 4, 8, P2h, P2l);
  k_packw<<<(10*4*512+255)/256,256,0,stream>>>(Wm3, 128, 156, 4, 10, P3h, P3l);

  // CSR + segment means
  k_count<<<N_PIX/256,256,0,stream>>>(seg0,seg1,seg2,cnt[0],cnt[1],cnt[2]);
  k_scan<<<3,256,0,stream>>>(cnt[0],cnt[1],cnt[2],offs[0],offs[1],offs[2],cur[0],cur[1],cur[2]);
  k_fill<<<N_PIX/256,256,0,stream>>>(seg0,seg1,seg2,cur[0],cur[1],cur[2],lst[0],lst[1],lst[2]);
  k_segmean3<<<3500,128,0,stream>>>(Y,
      offs[0],cnt[0],lst[0],X[0],
      offs[1],cnt[1],lst[1],X[1],
      offs[2],cnt[2],lst[2],X[2]);

  // Multi-scale GAT encoder
  for(int i=0;i<3;i++){
    int n = nseg[i];
    k_linear<<<(n*64+255)/256,256,0,stream>>>(X[i],  W1a[i], b1a[i], Hn,  n, NB, 64);
    k_attn4<64,false><<<n/4,256,0,stream>>>(Hn, Aarr[i], x1b, n);
    k_linear<<<(n*3+255)/256,256,0,stream>>>(x1b, W2a[i], b2a[i], Hn2, n, 64, 3);
    k_attn4<3,true><<<n/4,256,0,stream>>>(Hn2, Aarr[i], Ss[i], n);
  }

  // fuse + spsum gather + PCR
  k_fuse<<<N_PIX/256,256,0,stream>>>(seg0,seg1,seg2,Ss[0],Ss[1],Ss[2],cst,fused);
  k_spsum0<<<2000,128,0,stream>>>(fused, offs[0], cnt[0], lst[0], spsum);
  k_pcr<<<2000,256,0,stream>>>(attn, spsum, cnt[0], smth);
  k_sflat<<<N_PIX/256,256,0,stream>>>(fused, seg0, smth, cst, Sf, ci);

  // ---- DIAGNOSTIC dispatches (half grid, no outputs, asm-live) ----
  k_mlp_mfma<3><<<4096,256,0,stream>>>(Y, ci, P1h,P1l,P2h,P2l,P3h,P3l, bm1,bm2,bm3, gsump, gwsump);
  k_mlp_mfma<2><<<4096,256,0,stream>>>(Y, ci, P1h,P1l,P2h,P2l,P3h,P3l, bm1,bm2,bm3, gsump, gwsump);
  k_mlp_mfma<1><<<4096,256,0,stream>>>(Y, ci, P1h,P1l,P2h,P2l,P3h,P3l, bm1,bm2,bm3, gsump, gwsump);

  // ACDE: real pass (plain stores, no global atomics)
  k_mlp_mfma<0><<<N_PIX/32,256,0,stream>>>(Y, ci, P1h,P1l,P2h,P2l,P3h,P3l, bm1,bm2,bm3, gsump, gwsump);
  k_finalM<<<468,256,0,stream>>>(gsump, gwsump, Mbuf);
  k_yhat4<<<(N_PIX/256)*39,256,0,stream>>>(Sf, Mbuf, (float4*)out);
  (void)in_sizes; (void)n_in; (void)out_size;
}

// Round 10
// 1056.339 us; speedup vs baseline: 1.4010x; 1.4010x over previous
//
#include <hip/hip_runtime.h>
#include <math.h>

#define N_PIX (512*512)
#define NB 156
#define GH 64

typedef unsigned short u16;
typedef __attribute__((ext_vector_type(8))) short bfrag8;   // 8 bf16 = 4 VGPRs
typedef __attribute__((ext_vector_type(4))) float f32x4;    // MFMA accumulator

// ---------- bf16 split helpers (RNE) ----------
__device__ __forceinline__ u16 f2bf(float x){
  unsigned u = __float_as_uint(x);
  unsigned r = (u + 0x7FFFu + ((u >> 16) & 1u)) >> 16;
  return (u16)r;
}
__device__ __forceinline__ float bf2f(u16 h){
  return __uint_as_float(((unsigned)h) << 16);
}

__device__ __forceinline__ float waveReduceMax(float v){
  #pragma unroll
  for(int o=32;o>0;o>>=1) v = fmaxf(v, __shfl_down(v, o, 64));
  return v;
}
__device__ __forceinline__ float waveReduceSum(float v){
  #pragma unroll
  for(int o=32;o>0;o>>=1) v += __shfl_down(v, o, 64);
  return v;
}

// ---------- derived constants: softmax(scale_weights), clip(alpha) ----------
__global__ void k_prep(const float* __restrict__ sw, const float* __restrict__ alpha, float* __restrict__ cst){
  if(threadIdx.x==0 && blockIdx.x==0){
    float m = fmaxf(sw[0], fmaxf(sw[1], sw[2]));
    float e0=expf(sw[0]-m), e1=expf(sw[1]-m), e2=expf(sw[2]-m);
    float s = e0+e1+e2;
    cst[0]=e0/s; cst[1]=e1/s; cst[2]=e2/s;
    cst[3]=fminf(fmaxf(alpha[0],0.f),1.f);
  }
}

// ---------- CSR build ----------
__global__ void k_count(const int* __restrict__ s0, const int* __restrict__ s1, const int* __restrict__ s2,
                        int* c0, int* c1, int* c2){
  int p = blockIdx.x*256 + threadIdx.x;
  if(p < N_PIX){
    atomicAdd(&c0[s0[p]],1);
    atomicAdd(&c1[s1[p]],1);
    atomicAdd(&c2[s2[p]],1);
  }
}

__global__ __launch_bounds__(256) void k_scan(const int* __restrict__ c0, const int* __restrict__ c1, const int* __restrict__ c2,
                       int* o0, int* o1, int* o2, int* u0, int* u1, int* u2){
  const int* cnt; int* offs; int* cur; int n;
  if(blockIdx.x==0){ cnt=c0; offs=o0; cur=u0; n=2000; }
  else if(blockIdx.x==1){ cnt=c1; offs=o1; cur=u1; n=1000; }
  else { cnt=c2; offs=o2; cur=u2; n=500; }
  __shared__ int l[2048];
  __shared__ int cs[256];
  int t = threadIdx.x;
  for(int i=t;i<2048;i+=256) l[i] = (i<n) ? cnt[i] : 0;
  __syncthreads();
  int s = 0;
  #pragma unroll
  for(int j=0;j<8;j++) s += l[t*8+j];
  cs[t] = s;
  __syncthreads();
  for(int d=1; d<256; d<<=1){
    int v = (t>=d) ? cs[t-d] : 0;
    __syncthreads();
    cs[t] += v;
    __syncthreads();
  }
  int run = cs[t] - s;
  for(int j=0;j<8;j++){
    int idx = t*8+j;
    int o = run;
    run += l[idx];
    if(idx < n){ offs[idx] = o; cur[idx] = o; }
  }
}

__global__ void k_fill(const int* __restrict__ s0, const int* __restrict__ s1, const int* __restrict__ s2,
                       int* u0, int* u1, int* u2, int* L0, int* L1, int* L2){
  int p = blockIdx.x*256 + threadIdx.x;
  if(p < N_PIX){
    int a = atomicAdd(&u0[s0[p]],1); L0[a] = p;
    int b = atomicAdd(&u1[s1[p]],1); L1[b] = p;
    int c = atomicAdd(&u2[s2[p]],1); L2[c] = p;
  }
}

// ---------- fused segment mean over all 3 scales ----------
__global__ __launch_bounds__(128) void k_segmean3(const float* __restrict__ Y,
    const int* __restrict__ o0, const int* __restrict__ c0, const int* __restrict__ l0, float* __restrict__ X0,
    const int* __restrict__ o1, const int* __restrict__ c1, const int* __restrict__ l1, float* __restrict__ X1,
    const int* __restrict__ o2, const int* __restrict__ c2, const int* __restrict__ l2, float* __restrict__ X2){
  int b = blockIdx.x;
  const int *offs, *cnt, *list; float* X; int s;
  if(b < 2000){ s=b;      offs=o0; cnt=c0; list=l0; X=X0; }
  else if(b < 3000){ s=b-2000; offs=o1; cnt=c1; list=l1; X=X1; }
  else { s=b-3000; offs=o2; cnt=c2; list=l2; X=X2; }
  int t = threadIdx.x;
  int n = cnt[s], st = offs[s];
  if(t < 78){
    float ax=0.f, ay=0.f;
    int q = 0;
    for(; q+4<=n; q+=4){
      int p0 = list[st+q], p1 = list[st+q+1], p2 = list[st+q+2], p3 = list[st+q+3];
      float2 v0 = *(const float2*)(Y + (size_t)p0*NB + t*2);
      float2 v1 = *(const float2*)(Y + (size_t)p1*NB + t*2);
      float2 v2 = *(const float2*)(Y + (size_t)p2*NB + t*2);
      float2 v3 = *(const float2*)(Y + (size_t)p3*NB + t*2);
      ax += (v0.x + v1.x) + (v2.x + v3.x);
      ay += (v0.y + v1.y) + (v2.y + v3.y);
    }
    for(; q<n; q++){
      int p0 = list[st+q];
      float2 v0 = *(const float2*)(Y + (size_t)p0*NB + t*2);
      ax += v0.x; ay += v0.y;
    }
    float inv = 1.f / fmaxf((float)n, 1.f);
    float2 r; r.x = ax*inv; r.y = ay*inv;
    *(float2*)(X + (size_t)s*NB + t*2) = r;
  }
}

// ---------- generic small linear: out[n,D] = X[n,K]@W[K,D]+b ----------
__global__ void k_linear(const float* __restrict__ X, const float* __restrict__ W, const float* __restrict__ bias,
                         float* __restrict__ out, int n, int K, int D){
  int gid = blockIdx.x*256 + threadIdx.x;
  if(gid >= n*D) return;
  int r = gid / D, c = gid - r*D;
  const float* xr = X + (size_t)r*K;
  float acc = bias[c];
  for(int k=0;k<K;k++) acc = fmaf(xr[k], W[(size_t)k*D + c], acc);
  out[gid] = acc;
}

// ---------- GAT masked attention, 4 rows per block ----------
template<int D, bool FINAL>
__global__ __launch_bounds__(256) void k_attn4(const float* __restrict__ Hn, const int* __restrict__ A,
                                               float* __restrict__ out, int n){
  __shared__ float sc[4][2048];
  __shared__ float hr[4][GH];
  __shared__ float redm[4][4];
  __shared__ float outp[4][4][GH];   // part, r, c (D==64)
  __shared__ float out3[4][4][4];    // wave, r, c (D==3)
  const int t = threadIdx.x, w = t>>6, lane = t&63;
  const int r0 = blockIdx.x*4;
  if(D==GH){
    hr[w][lane] = Hn[(size_t)(r0 + w)*GH + lane];
  } else {
    if(t < 12) hr[t/3][t%3] = Hn[(size_t)(r0 + t/3)*3 + (t%3)];
  }
  __syncthreads();
  float lm0=-INFINITY, lm1=-INFINITY, lm2=-INFINITY, lm3=-INFINITY;
  for(int j=t; j<n; j+=256){
    float s0,s1,s2,s3;
    if(D==GH){
      const float4* hj = (const float4*)(Hn + (size_t)j*GH);
      s0=s1=s2=s3=0.f;
      #pragma unroll
      for(int k4=0;k4<GH/4;k4++){
        float4 h  = hj[k4];
        float4 a0 = *(const float4*)&hr[0][k4*4];
        float4 a1 = *(const float4*)&hr[1][k4*4];
        float4 a2 = *(const float4*)&hr[2][k4*4];
        float4 a3 = *(const float4*)&hr[3][k4*4];
        s0 = fmaf(a0.x,h.x, fmaf(a0.y,h.y, fmaf(a0.z,h.z, fmaf(a0.w,h.w, s0))));
        s1 = fmaf(a1.x,h.x, fmaf(a1.y,h.y, fmaf(a1.z,h.z, fmaf(a1.w,h.w, s1))));
        s2 = fmaf(a2.x,h.x, fmaf(a2.y,h.y, fmaf(a2.z,h.z, fmaf(a2.w,h.w, s2))));
        s3 = fmaf(a3.x,h.x, fmaf(a3.y,h.y, fmaf(a3.z,h.z, fmaf(a3.w,h.w, s3))));
      }
    } else {
      float h0=Hn[(size_t)j*3+0], h1=Hn[(size_t)j*3+1], h2=Hn[(size_t)j*3+2];
      s0 = hr[0][0]*h0 + hr[0][1]*h1 + hr[0][2]*h2;
      s1 = hr[1][0]*h0 + hr[1][1]*h1 + hr[1][2]*h2;
      s2 = hr[2][0]*h0 + hr[2][1]*h1 + hr[2][2]*h2;
      s3 = hr[3][0]*h0 + hr[3][1]*h1 + hr[3][2]*h2;
    }
    int m0 = A[(size_t)(r0+0)*n + j];
    int m1 = A[(size_t)(r0+1)*n + j];
    int m2 = A[(size_t)(r0+2)*n + j];
    int m3 = A[(size_t)(r0+3)*n + j];
    s0 = (m0>0) ? s0 : -1e9f;
    s1 = (m1>0) ? s1 : -1e9f;
    s2 = (m2>0) ? s2 : -1e9f;
    s3 = (m3>0) ? s3 : -1e9f;
    sc[0][j]=s0; sc[1][j]=s1; sc[2][j]=s2; sc[3][j]=s3;
    lm0=fmaxf(lm0,s0); lm1=fmaxf(lm1,s1); lm2=fmaxf(lm2,s2); lm3=fmaxf(lm3,s3);
  }
  {
    float w0=waveReduceMax(lm0), w1=waveReduceMax(lm1), w2=waveReduceMax(lm2), w3=waveReduceMax(lm3);
    if(lane==0){ redm[0][w]=w0; redm[1][w]=w1; redm[2][w]=w2; redm[3][w]=w3; }
  }
  __syncthreads();
  float m[4];
  #pragma unroll
  for(int r=0;r<4;r++) m[r] = fmaxf(fmaxf(redm[r][0],redm[r][1]), fmaxf(redm[r][2],redm[r][3]));
  __syncthreads();
  float ls0=0.f, ls1=0.f, ls2=0.f, ls3=0.f;
  for(int j=t; j<n; j+=256){
    float e0=__expf(sc[0][j]-m[0]); sc[0][j]=e0; ls0+=e0;
    float e1=__expf(sc[1][j]-m[1]); sc[1][j]=e1; ls1+=e1;
    float e2=__expf(sc[2][j]-m[2]); sc[2][j]=e2; ls2+=e2;
    float e3=__expf(sc[3][j]-m[3]); sc[3][j]=e3; ls3+=e3;
  }
  {
    float w0=waveReduceSum(ls0), w1=waveReduceSum(ls1), w2=waveReduceSum(ls2), w3=waveReduceSum(ls3);
    if(lane==0){ redm[0][w]=w0; redm[1][w]=w1; redm[2][w]=w2; redm[3][w]=w3; }
  }
  __syncthreads();   // sums visible AND all sc exp-writes visible
  float S[4];
  #pragma unroll
  for(int r=0;r<4;r++) S[r] = redm[r][0]+redm[r][1]+redm[r][2]+redm[r][3];
  if(D==GH){
    float acc0=0.f, acc1=0.f, acc2=0.f, acc3=0.f;
    const int c = lane, part = w;
    #pragma unroll 2
    for(int j=part; j<n; j+=4){
      float hv = Hn[(size_t)j*GH + c];
      acc0 = fmaf(sc[0][j], hv, acc0);
      acc1 = fmaf(sc[1][j], hv, acc1);
      acc2 = fmaf(sc[2][j], hv, acc2);
      acc3 = fmaf(sc[3][j], hv, acc3);
    }
    outp[part][0][c]=acc0; outp[part][1][c]=acc1; outp[part][2][c]=acc2; outp[part][3][c]=acc3;
    __syncthreads();
    int r = w;
    float tot = outp[0][r][lane]+outp[1][r][lane]+outp[2][r][lane]+outp[3][r][lane];
    out[(size_t)(r0+r)*GH + lane] = fmaxf(tot/S[r], 0.f);
  } else {
    float a00=0,a01=0,a02=0, a10=0,a11=0,a12=0, a20=0,a21=0,a22=0, a30=0,a31=0,a32=0;
    for(int j=t; j<n; j+=256){
      float h0=Hn[(size_t)j*3+0], h1=Hn[(size_t)j*3+1], h2=Hn[(size_t)j*3+2];
      float e0=sc[0][j], e1=sc[1][j], e2=sc[2][j], e3=sc[3][j];
      a00=fmaf(e0,h0,a00); a01=fmaf(e0,h1,a01); a02=fmaf(e0,h2,a02);
      a10=fmaf(e1,h0,a10); a11=fmaf(e1,h1,a11); a12=fmaf(e1,h2,a12);
      a20=fmaf(e2,h0,a20); a21=fmaf(e2,h1,a21); a22=fmaf(e2,h2,a22);
      a30=fmaf(e3,h0,a30); a31=fmaf(e3,h1,a31); a32=fmaf(e3,h2,a32);
    }
    float v[12] = {a00,a01,a02,a10,a11,a12,a20,a21,a22,a30,a31,a32};
    #pragma unroll
    for(int i=0;i<12;i++){
      float ws = waveReduceSum(v[i]);
      if(lane==0) out3[w][i/3][i%3] = ws;
    }
    __syncthreads();
    if(t < 4){
      int r = t;
      float t0 = out3[0][r][0]+out3[1][r][0]+out3[2][r][0]+out3[3][r][0];
      float t1 = out3[0][r][1]+out3[1][r][1]+out3[2][r][1]+out3[3][r][1];
      float t2 = out3[0][r][2]+out3[1][r][2]+out3[2][r][2]+out3[3][r][2];
      float v0 = fmaxf(t0/S[r], 0.f);
      float v1 = fmaxf(t1/S[r], 0.f);
      float v2 = fmaxf(t2/S[r], 0.f);
      if(FINAL){
        float mm = fmaxf(v0, fmaxf(v1,v2));
        float e0=__expf(v0-mm), e1=__expf(v1-mm), e2=__expf(v2-mm);
        float ss = e0+e1+e2;
        out[(size_t)(r0+r)*3+0]=e0/ss; out[(size_t)(r0+r)*3+1]=e1/ss; out[(size_t)(r0+r)*3+2]=e2/ss;
      } else {
        out[(size_t)(r0+r)*3+0]=v0; out[(size_t)(r0+r)*3+1]=v1; out[(size_t)(r0+r)*3+2]=v2;
      }
    }
  }
}

// ---------- fuse scales (no atomics) ----------
__global__ void k_fuse(const int* __restrict__ s0, const int* __restrict__ s1, const int* __restrict__ s2,
                       const float* __restrict__ S0, const float* __restrict__ S1, const float* __restrict__ S2,
                       const float* __restrict__ cst, float* __restrict__ fused){
  int p = blockIdx.x*256 + threadIdx.x;
  if(p >= N_PIX) return;
  float w0=cst[0], w1=cst[1], w2=cst[2];
  int a=s0[p], b=s1[p], c=s2[p];
  #pragma unroll
  for(int e=0;e<3;e++){
    float f = w0*S0[a*3+e] + w1*S1[b*3+e] + w2*S2[c*3+e];
    fused[(size_t)p*3+e] = f;
  }
}

// ---------- superpixel sums of fused via CSR gather ----------
__global__ __launch_bounds__(128) void k_spsum0(const float* __restrict__ fused, const int* __restrict__ offs,
                                                const int* __restrict__ cnt, const int* __restrict__ list,
                                                float* __restrict__ spsum){
  __shared__ float r[2][3];
  int s = blockIdx.x;
  int t = threadIdx.x, w = t>>6, lane = t&63;
  int n = cnt[s], st = offs[s];
  float a0=0.f, a1=0.f, a2=0.f;
  for(int q=t; q<n; q+=128){
    int p = list[st+q];
    a0 += fused[(size_t)p*3+0];
    a1 += fused[(size_t)p*3+1];
    a2 += fused[(size_t)p*3+2];
  }
  a0 = waveReduceSum(a0); a1 = waveReduceSum(a1); a2 = waveReduceSum(a2);
  if(lane==0){ r[w][0]=a0; r[w][1]=a1; r[w][2]=a2; }
  __syncthreads();
  if(t==0){
    spsum[s*3+0]=r[0][0]+r[1][0];
    spsum[s*3+1]=r[0][1]+r[1][1];
    spsum[s*3+2]=r[0][2]+r[1][2];
  }
}

// ---------- PCR: smoothed_sp[r] = softmax(attn[r]) @ (spsum/cnt) ----------
__global__ __launch_bounds__(256) void k_pcr(const float* __restrict__ attn, const float* __restrict__ spsum,
                                             const int* __restrict__ cnt0, float* __restrict__ sm){
  __shared__ float buf[2048];
  __shared__ float red[4];
  __shared__ float r3[256][3];
  int r=blockIdx.x, t=threadIdx.x;
  float lmax=-INFINITY;
  for(int j=t;j<2000;j+=256){ float v=attn[(size_t)r*2000+j]; buf[j]=v; lmax=fmaxf(lmax,v); }
  float wm=waveReduceMax(lmax);
  if((t&63)==0) red[t>>6]=wm;
  __syncthreads();
  float m = fmaxf(fmaxf(red[0],red[1]),fmaxf(red[2],red[3]));
  __syncthreads();
  float lsum=0.f;
  for(int j=t;j<2000;j+=256){ float e=__expf(buf[j]-m); buf[j]=e; lsum+=e; }
  float wsu=waveReduceSum(lsum);
  if((t&63)==0) red[t>>6]=wsu;
  __syncthreads();
  float S=red[0]+red[1]+red[2]+red[3];
  float a0=0.f,a1=0.f,a2=0.f;
  for(int j=t;j<2000;j+=256){
    float e=buf[j];
    float inv = 1.f / fmaxf((float)cnt0[j], 1.f);
    a0=fmaf(e, spsum[j*3+0]*inv, a0);
    a1=fmaf(e, spsum[j*3+1]*inv, a1);
    a2=fmaf(e, spsum[j*3+2]*inv, a2);
  }
  r3[t][0]=a0; r3[t][1]=a1; r3[t][2]=a2;
  __syncthreads();
  for(int st=128;st>0;st>>=1){
    if(t<st){ r3[t][0]+=r3[t+st][0]; r3[t][1]+=r3[t+st][1]; r3[t][2]+=r3[t+st][2]; }
    __syncthreads();
  }
  if(t==0){ sm[r*3+0]=r3[0][0]/S; sm[r*3+1]=r3[0][1]/S; sm[r*3+2]=r3[0][2]/S; }
}

// ---------- S_flat + argmax class index ----------
__global__ void k_sflat(const float* __restrict__ fused, const int* __restrict__ s0,
                        const float* __restrict__ sm, const float* __restrict__ cst,
                        float* __restrict__ Sf, int* __restrict__ ci){
  int p = blockIdx.x*256 + threadIdx.x;
  if(p >= N_PIX) return;
  float a = cst[3];
  int s = s0[p];
  float x0 = a*sm[s*3+0] + (1.f-a)*fused[(size_t)p*3+0];
  float x1 = a*sm[s*3+1] + (1.f-a)*fused[(size_t)p*3+1];
  float x2 = a*sm[s*3+2] + (1.f-a)*fused[(size_t)p*3+2];
  Sf[(size_t)p*3+0]=x0; Sf[(size_t)p*3+1]=x1; Sf[(size_t)p*3+2]=x2;
  int c=0; float b=x0;
  if(x1>b){c=1;b=x1;}
  if(x2>b){c=2;}
  ci[p]=c;
}

// ---------- weight pre-pack into MFMA B-fragment order, bf16 hi/lo ----------
__global__ void k_packw(const float* __restrict__ W, int Kreal, int Nreal, int nkt, int nnt,
                        u16* __restrict__ dhi, u16* __restrict__ dlo){
  int gid = blockIdx.x*256 + threadIdx.x;
  int total = nnt*nkt*512;
  if(gid >= total) return;
  int j = gid & 7, l = (gid>>3)&63;
  int rem = gid >> 9;               // nt*nkt + ks
  int ks = rem % nkt;
  int nt = rem / nkt;
  int k = ks*32 + (l>>4)*8 + j;
  int n = nt*16 + (l&15);
  float w = (k < Kreal && n < Nreal) ? W[(size_t)k*Nreal + n] : 0.f;
  u16 hi = f2bf(w);
  dhi[gid] = hi;
  dlo[gid] = f2bf(w - bf2f(hi));
}

// ---------- MFMA MLP (156->128->128->156) + atomic-free shuffle-reduced epilogue ----------
#define MFMA(a,b,c) __builtin_amdgcn_mfma_f32_16x16x32_bf16((a),(b),(c),0,0,0)

__global__ __launch_bounds__(256, 4) void k_mlp_mfma(
    const float* __restrict__ Y, const int* __restrict__ ci,
    const u16* __restrict__ P1h, const u16* __restrict__ P1l,
    const u16* __restrict__ P2h, const u16* __restrict__ P2l,
    const u16* __restrict__ P3h, const u16* __restrict__ P3l,
    const float* __restrict__ b1, const float* __restrict__ b2, const float* __restrict__ b3,
    float* __restrict__ gsum, float* __restrict__ gwsum){
  __shared__ u16 SH[32*168];                 // X-hi [32][168]  ->  A-hi [32][136]
  __shared__ u16 SL[32*168];                 // X-lo            ->  A-lo
  __shared__ float csum[480], cwsum[480];    // per-class partial sums [3][160]
  __shared__ int cis[32];
  const int t = threadIdx.x;
  const int lane = t & 63, w = t >> 6;
  const int g = lane >> 4, r16 = lane & 15;
  const size_t p0 = (size_t)blockIdx.x * 32;

  for(int i=t;i<480;i+=256){ csum[i]=0.f; cwsum[i]=0.f; }
  if(t<32) cis[t] = ci[p0+t];
  // stage Y tile: 32 rows x 39 float4, split to bf16 hi/lo, packed u32 LDS writes
  for(int i=t;i<1248;i+=256){
    int row = i/39, q = i - row*39, c0 = q*4;
    float4 v = *(const float4*)(Y + (p0+row)*NB + c0);
    u16 h0=f2bf(v.x), h1=f2bf(v.y), h2=f2bf(v.z), h3=f2bf(v.w);
    u16 l0=f2bf(v.x-bf2f(h0)), l1=f2bf(v.y-bf2f(h1)), l2=f2bf(v.z-bf2f(h2)), l3=f2bf(v.w-bf2f(h3));
    *(unsigned*)&SH[row*168+c0]   = (unsigned)h0 | ((unsigned)h1<<16);
    *(unsigned*)&SH[row*168+c0+2] = (unsigned)h2 | ((unsigned)h3<<16);
    *(unsigned*)&SL[row*168+c0]   = (unsigned)l0 | ((unsigned)l1<<16);
    *(unsigned*)&SL[row*168+c0+2] = (unsigned)l2 | ((unsigned)l3<<16);
  }
  if(t<64){ int row=t>>1, o=156+(t&1)*2;
    *(unsigned*)&SH[row*168+o]=0u; *(unsigned*)&SL[row*168+o]=0u; }
  __syncthreads();

  // ---- layer 1: K=160 (5 ks), N=128; wave w -> ntiles {w, w+4} ----
  {
    f32x4 acc[2][2];
    #pragma unroll
    for(int u=0;u<2;u++)
      #pragma unroll
      for(int mt=0;mt<2;mt++) acc[u][mt] = (f32x4){0.f,0.f,0.f,0.f};
    #pragma unroll
    for(int ks=0;ks<5;ks++){
      bfrag8 bh0 = *(const bfrag8*)(P1h + ((size_t)(w*5+ks))*512 + lane*8);
      bfrag8 bl0 = *(const bfrag8*)(P1l + ((size_t)(w*5+ks))*512 + lane*8);
      bfrag8 bh1 = *(const bfrag8*)(P1h + ((size_t)((w+4)*5+ks))*512 + lane*8);
      bfrag8 bl1 = *(const bfrag8*)(P1l + ((size_t)((w+4)*5+ks))*512 + lane*8);
      #pragma unroll
      for(int mt=0;mt<2;mt++){
        bfrag8 ah = *(const bfrag8*)(SH + (mt*16+r16)*168 + g*8 + ks*32);
        bfrag8 al = *(const bfrag8*)(SL + (mt*16+r16)*168 + g*8 + ks*32);
        acc[0][mt]=MFMA(ah,bh0,acc[0][mt]); acc[0][mt]=MFMA(ah,bl0,acc[0][mt]); acc[0][mt]=MFMA(al,bh0,acc[0][mt]);
        acc[1][mt]=MFMA(ah,bh1,acc[1][mt]); acc[1][mt]=MFMA(ah,bl1,acc[1][mt]); acc[1][mt]=MFMA(al,bh1,acc[1][mt]);
      }
    }
    __syncthreads();   // all waves done reading X
    #pragma unroll
    for(int u=0;u<2;u++){
      int c = (w+u*4)*16 + r16;
      float bv = b1[c];
      #pragma unroll
      for(int mt=0;mt<2;mt++)
        #pragma unroll
        for(int r=0;r<4;r++){
          float v = fmaxf(acc[u][mt][r] + bv, 0.f);
          int row = mt*16 + g*4 + r;
          u16 h = f2bf(v);
          SH[row*136+c] = h; SL[row*136+c] = f2bf(v - bf2f(h));
        }
    }
  }
  __syncthreads();

  // ---- layer 2: K=128 (4 ks), N=128; regs across barrier, overwrite A ----
  {
    f32x4 acc[2][2];
    #pragma unroll
    for(int u=0;u<2;u++)
      #pragma unroll
      for(int mt=0;mt<2;mt++) acc[u][mt] = (f32x4){0.f,0.f,0.f,0.f};
    #pragma unroll
    for(int ks=0;ks<4;ks++){
      bfrag8 bh0 = *(const bfrag8*)(P2h + ((size_t)(w*4+ks))*512 + lane*8);
      bfrag8 bl0 = *(const bfrag8*)(P2l + ((size_t)(w*4+ks))*512 + lane*8);
      bfrag8 bh1 = *(const bfrag8*)(P2h + ((size_t)((w+4)*4+ks))*512 + lane*8);
      bfrag8 bl1 = *(const bfrag8*)(P2l + ((size_t)((w+4)*4+ks))*512 + lane*8);
      #pragma unroll
      for(int mt=0;mt<2;mt++){
        bfrag8 ah = *(const bfrag8*)(SH + (mt*16+r16)*136 + g*8 + ks*32);
        bfrag8 al = *(const bfrag8*)(SL + (mt*16+r16)*136 + g*8 + ks*32);
        acc[0][mt]=MFMA(ah,bh0,acc[0][mt]); acc[0][mt]=MFMA(ah,bl0,acc[0][mt]); acc[0][mt]=MFMA(al,bh0,acc[0][mt]);
        acc[1][mt]=MFMA(ah,bh1,acc[1][mt]); acc[1][mt]=MFMA(ah,bl1,acc[1][mt]); acc[1][mt]=MFMA(al,bh1,acc[1][mt]);
      }
    }
    __syncthreads();   // all waves done reading A(layer1)
    #pragma unroll
    for(int u=0;u<2;u++){
      int c = (w+u*4)*16 + r16;
      float bv = b2[c];
      #pragma unroll
      for(int mt=0;mt<2;mt++)
        #pragma unroll
        for(int r=0;r<4;r++){
          float v = fmaxf(acc[u][mt][r] + bv, 0.f);
          int row = mt*16 + g*4 + r;
          u16 h = f2bf(v);
          SH[row*136+c] = h; SL[row*136+c] = f2bf(v - bf2f(h));
        }
    }
  }
  __syncthreads();

  // ---- layer 3: K=128, 20 subtiles over 4 waves (5 chains/wave) + atomic-free epilogue ----
  {
    f32x4 acc[5];
    #pragma unroll
    for(int s=0;s<5;s++) acc[s] = (f32x4){0.f,0.f,0.f,0.f};
    #pragma unroll
    for(int s=0;s<5;s++){
      int idx = w*5 + s, nt = idx>>1, mt = idx&1;
      #pragma unroll
      for(int ks=0;ks<4;ks++){
        bfrag8 bh = *(const bfrag8*)(P3h + ((size_t)(nt*4+ks))*512 + lane*8);
        bfrag8 bl = *(const bfrag8*)(P3l + ((size_t)(nt*4+ks))*512 + lane*8);
        bfrag8 ah = *(const bfrag8*)(SH + (mt*16+r16)*136 + g*8 + ks*32);
        bfrag8 al = *(const bfrag8*)(SL + (mt*16+r16)*136 + g*8 + ks*32);
        acc[s]=MFMA(ah,bh,acc[s]); acc[s]=MFMA(ah,bl,acc[s]); acc[s]=MFMA(al,bh,acc[s]);
      }
    }
    // per-thread class partials: [3 local ntiles][3 classes], explicit regs (no dyn indexing)
    // wave w touches exactly ntiles {ntbase, ntbase+1, ntbase+2}
    const int ntbase = (w*5) >> 1;
    float cs00=0,cs01=0,cs02=0, cs10=0,cs11=0,cs12=0, cs20=0,cs21=0,cs22=0;
    float cw00=0,cw01=0,cw02=0, cw10=0,cw11=0,cw12=0, cw20=0,cw21=0,cw22=0;
    #pragma unroll
    for(int s=0;s<5;s++){
      int idx = w*5 + s, nt = idx>>1, mt = idx&1;
      int ntl = nt - ntbase;          // 0..2
      int c = nt*16 + r16;
      if(c < 156){
        float bv = b3[c];
        #pragma unroll
        for(int r=0;r<4;r++){
          int p = mt*16 + g*4 + r;
          float e = __expf(acc[s][r] + bv);
          float y = Y[(p0+p)*NB + c];
          float ey = e*y;
          int k = cis[p];
          float e0 = (k==0)?e:0.f, e1 = (k==1)?e:0.f, e2 = (k==2)?e:0.f;
          float y0 = (k==0)?ey:0.f, y1 = (k==1)?ey:0.f, y2 = (k==2)?ey:0.f;
          if(ntl==0){ cs00+=e0; cs01+=e1; cs02+=e2; cw00+=y0; cw01+=y1; cw02+=y2; }
          else if(ntl==1){ cs10+=e0; cs11+=e1; cs12+=e2; cw10+=y0; cw11+=y1; cw12+=y2; }
          else { cs20+=e0; cs21+=e1; cs22+=e2; cw20+=y0; cw21+=y1; cw22+=y2; }
        }
      }
    }
    // reduce over the 4 g-groups (lanes l, l^16, l^32, l^48 share r16)
    #define GRED(v) { v += __shfl_xor(v,16,64); v += __shfl_xor(v,32,64); }
    GRED(cs00) GRED(cs01) GRED(cs02) GRED(cs10) GRED(cs11) GRED(cs12) GRED(cs20) GRED(cs21) GRED(cs22)
    GRED(cw00) GRED(cw01) GRED(cw02) GRED(cw10) GRED(cw11) GRED(cw12) GRED(cw20) GRED(cw21) GRED(cw22)
    #undef GRED
    if(g==0){
      // every wave flushes ALL 3 local ntiles (each is touched by construction);
      // <=2-way inter-wave LDS-atomic collision on shared ntiles (nt=2, nt=7)
      #pragma unroll
      for(int ntl=0;ntl<3;ntl++){
        int nt = ntbase + ntl;
        int c = nt*16 + r16;
        if(c < 156){
          float s0 = (ntl==0)?cs00:((ntl==1)?cs10:cs20);
          float s1 = (ntl==0)?cs01:((ntl==1)?cs11:cs21);
          float s2 = (ntl==0)?cs02:((ntl==1)?cs12:cs22);
          float w0 = (ntl==0)?cw00:((ntl==1)?cw10:cw20);
          float w1 = (ntl==0)?cw01:((ntl==1)?cw11:cw21);
          float w2 = (ntl==0)?cw02:((ntl==1)?cw12:cw22);
          atomicAdd(&csum[0*160 + c], s0);
          atomicAdd(&csum[1*160 + c], s1);
          atomicAdd(&csum[2*160 + c], s2);
          atomicAdd(&cwsum[0*160 + c], w0);
          atomicAdd(&cwsum[1*160 + c], w1);
          atomicAdd(&cwsum[2*160 + c], w2);
        }
      }
    }
  }
  __syncthreads();
  // plain per-block store (no global atomics)
  float* gs = gsum  + (size_t)blockIdx.x*480;
  float* gw = gwsum + (size_t)blockIdx.x*480;
  for(int i=t;i<480;i+=256){
    gs[i] = csum[i];
    gw[i] = cwsum[i];
  }
}

// ---------- final M: reduce 8192 per-block slots; one block per (cls,c) ----------
__global__ __launch_bounds__(256) void k_finalM(const float* __restrict__ gsump, const float* __restrict__ gwsump,
                                                float* __restrict__ M){
  __shared__ float rs[4], rw[4];
  int e = blockIdx.x;                 // 0..467
  int cls = e/156, c = e - cls*156;
  int off = cls*160 + c;
  int t = threadIdx.x, w = t>>6, lane = t&63;
  float s=0.f, wv=0.f;
  for(int k=t; k<8192; k+=256){
    s  += gsump[(size_t)k*480 + off];
    wv += gwsump[(size_t)k*480 + off];
  }
  s = waveReduceSum(s); wv = waveReduceSum(wv);
  if(lane==0){ rs[w]=s; rw[w]=wv; }
  __syncthreads();
  if(t==0){
    float S = rs[0]+rs[1]+rs[2]+rs[3];
    float W = rw[0]+rw[1]+rw[2]+rw[3];
    M[e] = (S > 0.f) ? (W / fmaxf(S, 1e-30f)) : 0.f;
  }
}

// ---------- Y_hat = S_flat @ M, float4 stores ----------
__global__ void k_yhat4(const float* __restrict__ Sf, const float* __restrict__ M, float4* __restrict__ out){
  unsigned idx = blockIdx.x*256u + threadIdx.x;   // N_PIX*39 float4s, grid exact
  unsigned p = idx / 39u, q = idx - p*39u;
  unsigned c0 = q*4u;
  float4 m0 = *(const float4*)(M + c0);
  float4 m1 = *(const float4*)(M + 156 + c0);
  float4 m2 = *(const float4*)(M + 312 + c0);
  float s0 = Sf[(size_t)p*3+0], s1 = Sf[(size_t)p*3+1], s2 = Sf[(size_t)p*3+2];
  float4 r;
  r.x = s0*m0.x + s1*m1.x + s2*m2.x;
  r.y = s0*m0.y + s1*m1.y + s2*m2.y;
  r.z = s0*m0.z + s1*m1.z + s2*m2.z;
  r.w = s0*m0.w + s1*m1.w + s2*m2.w;
  out[idx] = r;
}

extern "C" void kernel_launch(void* const* d_in, const int* in_sizes, int n_in,
                              void* d_out, int out_size, void* d_ws, size_t ws_size,
                              hipStream_t stream){
  const float* Y    = (const float*)d_in[0];
  const int*   seg0 = (const int*)d_in[1];
  const int*   A0   = (const int*)d_in[2];
  const int*   seg1 = (const int*)d_in[3];
  const int*   A1   = (const int*)d_in[4];
  const int*   seg2 = (const int*)d_in[5];
  const int*   A2   = (const int*)d_in[6];
  const float* attn = (const float*)d_in[7];
  const float* alpha= (const float*)d_in[8];
  const float* sw   = (const float*)d_in[9];
  const float* W1a[3] = {(const float*)d_in[10], (const float*)d_in[14], (const float*)d_in[18]};
  const float* b1a[3] = {(const float*)d_in[11], (const float*)d_in[15], (const float*)d_in[19]};
  const float* W2a[3] = {(const float*)d_in[12], (const float*)d_in[16], (const float*)d_in[20]};
  const float* b2a[3] = {(const float*)d_in[13], (const float*)d_in[17], (const float*)d_in[21]};
  const float* Wm1=(const float*)d_in[22]; const float* bm1=(const float*)d_in[23];
  const float* Wm2=(const float*)d_in[24]; const float* bm2=(const float*)d_in[25];
  const float* Wm3=(const float*)d_in[26]; const float* bm3=(const float*)d_in[27];
  float* out = (float*)d_out;

  const int nseg[3] = {2000, 1000, 500};
  const int* Aarr[3]   = {A0, A1, A2};

  char* base = (char*)d_ws;
  size_t off = 0;
  auto alloc = [&](size_t bytes)->char*{
    char* r = base + off;
    off += (bytes + 255) & ~(size_t)255;
    return r;
  };
  int* cnt[3]; int* offs[3]; int* cur[3]; int* lst[3]; float* X[3]; float* Ss[3];
  for(int i=0;i<3;i++) cnt[i]  = (int*)alloc((size_t)nseg[i]*4);
  for(int i=0;i<3;i++) offs[i] = (int*)alloc((size_t)nseg[i]*4);
  for(int i=0;i<3;i++) cur[i]  = (int*)alloc((size_t)nseg[i]*4);
  for(int i=0;i<3;i++) lst[i]  = (int*)alloc((size_t)N_PIX*4);
  for(int i=0;i<3;i++) X[i]    = (float*)alloc((size_t)nseg[i]*NB*4);
  float* Hn   = (float*)alloc((size_t)2000*64*4);
  float* x1b  = (float*)alloc((size_t)2000*64*4);
  float* Hn2  = (float*)alloc((size_t)2000*3*4);
  for(int i=0;i<3;i++) Ss[i]   = (float*)alloc((size_t)nseg[i]*3*4);
  float* cst   = (float*)alloc(64);
  float* fused = (float*)alloc((size_t)N_PIX*3*4);
  float* spsum = (float*)alloc((size_t)2000*3*4);
  float* smth  = (float*)alloc((size_t)2000*3*4);
  float* Sf    = (float*)alloc((size_t)N_PIX*3*4);
  int*   ci    = (int*)alloc((size_t)N_PIX*4);
  u16* P1h = (u16*)alloc((size_t)20480*2); u16* P1l = (u16*)alloc((size_t)20480*2);
  u16* P2h = (u16*)alloc((size_t)16384*2); u16* P2l = (u16*)alloc((size_t)16384*2);
  u16* P3h = (u16*)alloc((size_t)20480*2); u16* P3l = (u16*)alloc((size_t)20480*2);
  float* gsump  = (float*)alloc((size_t)8192*480*4);
  float* gwsump = (float*)alloc((size_t)8192*480*4);
  float* Mbuf   = (float*)alloc((size_t)480*4);

  // per-call re-init (replay/poison safe); gsump/gwsump fully overwritten by stores
  for(int i=0;i<3;i++) hipMemsetAsync(cnt[i], 0, (size_t)nseg[i]*4, stream);
  k_prep<<<1,64,0,stream>>>(sw, alpha, cst);

  // weight pre-pack
  k_packw<<<(8*5*512+255)/256,256,0,stream>>>(Wm1, 156, 128, 5, 8, P1h, P1l);
  k_packw<<<(8*4*512+255)/256,256,0,stream>>>(Wm2, 128, 128, 4, 8, P2h, P2l);
  k_packw<<<(10*4*512+255)/256,256,0,stream>>>(Wm3, 128, 156, 4, 10, P3h, P3l);

  // CSR + segment means
  k_count<<<N_PIX/256,256,0,stream>>>(seg0,seg1,seg2,cnt[0],cnt[1],cnt[2]);
  k_scan<<<3,256,0,stream>>>(cnt[0],cnt[1],cnt[2],offs[0],offs[1],offs[2],cur[0],cur[1],cur[2]);
  k_fill<<<N_PIX/256,256,0,stream>>>(seg0,seg1,seg2,cur[0],cur[1],cur[2],lst[0],lst[1],lst[2]);
  k_segmean3<<<3500,128,0,stream>>>(Y,
      offs[0],cnt[0],lst[0],X[0],
      offs[1],cnt[1],lst[1],X[1],
      offs[2],cnt[2],lst[2],X[2]);

  // Multi-scale GAT encoder
  for(int i=0;i<3;i++){
    int n = nseg[i];
    k_linear<<<(n*64+255)/256,256,0,stream>>>(X[i],  W1a[i], b1a[i], Hn,  n, NB, 64);
    k_attn4<64,false><<<n/4,256,0,stream>>>(Hn, Aarr[i], x1b, n);
    k_linear<<<(n*3+255)/256,256,0,stream>>>(x1b, W2a[i], b2a[i], Hn2, n, 64, 3);
    k_attn4<3,true><<<n/4,256,0,stream>>>(Hn2, Aarr[i], Ss[i], n);
  }

  // fuse + spsum gather + PCR
  k_fuse<<<N_PIX/256,256,0,stream>>>(seg0,seg1,seg2,Ss[0],Ss[1],Ss[2],cst,fused);
  k_spsum0<<<2000,128,0,stream>>>(fused, offs[0], cnt[0], lst[0], spsum);
  k_pcr<<<2000,256,0,stream>>>(attn, spsum, cnt[0], smth);
  k_sflat<<<N_PIX/256,256,0,stream>>>(fused, seg0, smth, cst, Sf, ci);

  // ACDE: MFMA MLP + atomic-free epilogue
  k_mlp_mfma<<<N_PIX/32,256,0,stream>>>(Y, ci, P1h,P1l,P2h,P2l,P3h,P3l, bm1,bm2,bm3, gsump, gwsump);
  k_finalM<<<468,256,0,stream>>>(gsump, gwsump, Mbuf);
  k_yhat4<<<(N_PIX/256)*39,256,0,stream>>>(Sf, Mbuf, (float4*)out);
  (void)in_sizes; (void)n_in; (void)out_size;
}

// Round 11
// 874.654 us; speedup vs baseline: 1.6920x; 1.2077x over previous
//
#include <hip/hip_runtime.h>
#include <math.h>

#define N_PIX (512*512)
#define NB 156
#define GH 64

typedef unsigned short u16;
typedef __attribute__((ext_vector_type(8))) short bfrag8;   // 8 bf16 = 4 VGPRs
typedef __attribute__((ext_vector_type(4))) float f32x4;    // MFMA accumulator

// ---------- bf16 split helpers (RNE) ----------
__device__ __forceinline__ u16 f2bf(float x){
  unsigned u = __float_as_uint(x);
  unsigned r = (u + 0x7FFFu + ((u >> 16) & 1u)) >> 16;
  return (u16)r;
}
__device__ __forceinline__ float bf2f(u16 h){
  return __uint_as_float(((unsigned)h) << 16);
}

__device__ __forceinline__ float waveReduceMax(float v){
  #pragma unroll
  for(int o=32;o>0;o>>=1) v = fmaxf(v, __shfl_down(v, o, 64));
  return v;
}
__device__ __forceinline__ float waveReduceSum(float v){
  #pragma unroll
  for(int o=32;o>0;o>>=1) v += __shfl_down(v, o, 64);
  return v;
}

// ---------- derived constants: softmax(scale_weights), clip(alpha) ----------
__global__ void k_prep(const float* __restrict__ sw, const float* __restrict__ alpha, float* __restrict__ cst){
  if(threadIdx.x==0 && blockIdx.x==0){
    float m = fmaxf(sw[0], fmaxf(sw[1], sw[2]));
    float e0=expf(sw[0]-m), e1=expf(sw[1]-m), e2=expf(sw[2]-m);
    float s = e0+e1+e2;
    cst[0]=e0/s; cst[1]=e1/s; cst[2]=e2/s;
    cst[3]=fminf(fmaxf(alpha[0],0.f),1.f);
  }
}

// ---------- CSR build ----------
__global__ void k_count(const int* __restrict__ s0, const int* __restrict__ s1, const int* __restrict__ s2,
                        int* c0, int* c1, int* c2){
  int p = blockIdx.x*256 + threadIdx.x;
  if(p < N_PIX){
    atomicAdd(&c0[s0[p]],1);
    atomicAdd(&c1[s1[p]],1);
    atomicAdd(&c2[s2[p]],1);
  }
}

__global__ __launch_bounds__(256) void k_scan(const int* __restrict__ c0, const int* __restrict__ c1, const int* __restrict__ c2,
                       int* o0, int* o1, int* o2, int* u0, int* u1, int* u2){
  const int* cnt; int* offs; int* cur; int n;
  if(blockIdx.x==0){ cnt=c0; offs=o0; cur=u0; n=2000; }
  else if(blockIdx.x==1){ cnt=c1; offs=o1; cur=u1; n=1000; }
  else { cnt=c2; offs=o2; cur=u2; n=500; }
  __shared__ int l[2048];
  __shared__ int cs[256];
  int t = threadIdx.x;
  for(int i=t;i<2048;i+=256) l[i] = (i<n) ? cnt[i] : 0;
  __syncthreads();
  int s = 0;
  #pragma unroll
  for(int j=0;j<8;j++) s += l[t*8+j];
  cs[t] = s;
  __syncthreads();
  for(int d=1; d<256; d<<=1){
    int v = (t>=d) ? cs[t-d] : 0;
    __syncthreads();
    cs[t] += v;
    __syncthreads();
  }
  int run = cs[t] - s;
  for(int j=0;j<8;j++){
    int idx = t*8+j;
    int o = run;
    run += l[idx];
    if(idx < n){ offs[idx] = o; cur[idx] = o; }
  }
}

__global__ void k_fill(const int* __restrict__ s0, const int* __restrict__ s1, const int* __restrict__ s2,
                       int* u0, int* u1, int* u2, int* L0, int* L1, int* L2){
  int p = blockIdx.x*256 + threadIdx.x;
  if(p < N_PIX){
    int a = atomicAdd(&u0[s0[p]],1); L0[a] = p;
    int b = atomicAdd(&u1[s1[p]],1); L1[b] = p;
    int c = atomicAdd(&u2[s2[p]],1); L2[c] = p;
  }
}

// ---------- fused segment mean over all 3 scales: 192 thr, 2 pixel-groups of 78 lanes ----------
__global__ __launch_bounds__(192) void k_segmean3(const float* __restrict__ Y,
    const int* __restrict__ o0, const int* __restrict__ c0, const int* __restrict__ l0, float* __restrict__ X0,
    const int* __restrict__ o1, const int* __restrict__ c1, const int* __restrict__ l1, float* __restrict__ X1,
    const int* __restrict__ o2, const int* __restrict__ c2, const int* __restrict__ l2, float* __restrict__ X2){
  int b = blockIdx.x;
  const int *offs, *cnt, *list; float* X; int s;
  if(b < 2000){ s=b;      offs=o0; cnt=c0; list=l0; X=X0; }
  else if(b < 3000){ s=b-2000; offs=o1; cnt=c1; list=l1; X=X1; }
  else { s=b-3000; offs=o2; cnt=c2; list=l2; X=X2; }
  __shared__ float part[156];
  int t = threadIdx.x;
  int grp = t / 96, tb = t - grp*96;
  int n = cnt[s], st = offs[s];
  float ax=0.f, ay=0.f;
  if(tb < 78){
    int q = grp;
    for(; q+6<n; q+=8){
      int p0 = list[st+q], p1 = list[st+q+2], p2 = list[st+q+4], p3 = list[st+q+6];
      float2 v0 = *(const float2*)(Y + (size_t)p0*NB + tb*2);
      float2 v1 = *(const float2*)(Y + (size_t)p1*NB + tb*2);
      float2 v2 = *(const float2*)(Y + (size_t)p2*NB + tb*2);
      float2 v3 = *(const float2*)(Y + (size_t)p3*NB + tb*2);
      ax += (v0.x + v1.x) + (v2.x + v3.x);
      ay += (v0.y + v1.y) + (v2.y + v3.y);
    }
    for(; q<n; q+=2){
      int p0 = list[st+q];
      float2 v0 = *(const float2*)(Y + (size_t)p0*NB + tb*2);
      ax += v0.x; ay += v0.y;
    }
  }
  if(grp==1 && tb<78){ part[tb*2]=ax; part[tb*2+1]=ay; }
  __syncthreads();
  if(grp==0 && tb<78){
    float inv = 1.f / fmaxf((float)n, 1.f);
    float2 r; r.x = (ax + part[tb*2])*inv; r.y = (ay + part[tb*2+1])*inv;
    *(float2*)(X + (size_t)s*NB + tb*2) = r;
  }
}

// ---------- batched small linear over all 3 scales (rows 0..3499) ----------
// rows [0,2000) scale0, [2000,3000) scale1, [3000,3500) scale2
__global__ void k_linearB(const float* __restrict__ X, int K, int D,
                          const float* __restrict__ W0, const float* __restrict__ bb0,
                          const float* __restrict__ W1, const float* __restrict__ bb1,
                          const float* __restrict__ W2, const float* __restrict__ bb2,
                          float* __restrict__ out){
  int gid = blockIdx.x*256 + threadIdx.x;
  if(gid >= 3500*D) return;
  int r = gid / D, c = gid - r*D;
  const float* W; const float* bb;
  if(r < 2000){ W=W0; bb=bb0; }
  else if(r < 3000){ W=W1; bb=bb1; }
  else { W=W2; bb=bb2; }
  const float* xr = X + (size_t)r*K;
  float acc = bb[c];
  for(int k=0;k<K;k++) acc = fmaf(xr[k], W[(size_t)k*D + c], acc);
  out[gid] = acc;
}

// ---------- batched GAT masked attention, 4 rows per block, all 3 scales ----------
// grid 875: blocks [0,500) scale0 (n=2000), [500,750) scale1 (n=1000), [750,875) scale2 (n=500)
template<int D, bool FINAL>
__global__ __launch_bounds__(256) void k_attn4B(const float* __restrict__ HnAll,
                                                const int* __restrict__ A0, const int* __restrict__ A1, const int* __restrict__ A2,
                                                float* __restrict__ outAll){
  __shared__ float sc[4][2048];
  __shared__ float hr[4][GH];
  __shared__ float redm[4][4];
  __shared__ float outp[4][4][GH];   // part, r, c (D==64)
  __shared__ float out3[4][4][4];    // wave, r, c (D==3)
  const int t = threadIdx.x, w = t>>6, lane = t&63;
  int b = blockIdx.x;
  int n, r0; size_t base; const int* A;
  if(b < 500){ n=2000; base=0;    r0=b*4;        A=A0; }
  else if(b < 750){ n=1000; base=2000; r0=(b-500)*4; A=A1; }
  else { n=500;  base=3000; r0=(b-750)*4; A=A2; }
  const int OD = FINAL ? 3 : (D==GH ? GH : 3);   // out row width (x1b:64, Hn2-style:3, Ss:3)
  const float* Hn = HnAll + base*D;
  float* out = outAll + base*OD;
  if(D==GH){
    hr[w][lane] = Hn[(size_t)(r0 + w)*GH + lane];
  } else {
    if(t < 12) hr[t/3][t%3] = Hn[(size_t)(r0 + t/3)*3 + (t%3)];
  }
  __syncthreads();
  float lm0=-INFINITY, lm1=-INFINITY, lm2=-INFINITY, lm3=-INFINITY;
  for(int j=t; j<n; j+=256){
    float s0,s1,s2,s3;
    if(D==GH){
      const float4* hj = (const float4*)(Hn + (size_t)j*GH);
      s0=s1=s2=s3=0.f;
      #pragma unroll
      for(int k4=0;k4<GH/4;k4++){
        float4 h  = hj[k4];
        float4 a0 = *(const float4*)&hr[0][k4*4];
        float4 a1 = *(const float4*)&hr[1][k4*4];
        float4 a2 = *(const float4*)&hr[2][k4*4];
        float4 a3 = *(const float4*)&hr[3][k4*4];
        s0 = fmaf(a0.x,h.x, fmaf(a0.y,h.y, fmaf(a0.z,h.z, fmaf(a0.w,h.w, s0))));
        s1 = fmaf(a1.x,h.x, fmaf(a1.y,h.y, fmaf(a1.z,h.z, fmaf(a1.w,h.w, s1))));
        s2 = fmaf(a2.x,h.x, fmaf(a2.y,h.y, fmaf(a2.z,h.z, fmaf(a2.w,h.w, s2))));
        s3 = fmaf(a3.x,h.x, fmaf(a3.y,h.y, fmaf(a3.z,h.z, fmaf(a3.w,h.w, s3))));
      }
    } else {
      float h0=Hn[(size_t)j*3+0], h1=Hn[(size_t)j*3+1], h2=Hn[(size_t)j*3+2];
      s0 = hr[0][0]*h0 + hr[0][1]*h1 + hr[0][2]*h2;
      s1 = hr[1][0]*h0 + hr[1][1]*h1 + hr[1][2]*h2;
      s2 = hr[2][0]*h0 + hr[2][1]*h1 + hr[2][2]*h2;
      s3 = hr[3][0]*h0 + hr[3][1]*h1 + hr[3][2]*h2;
    }
    int m0 = A[(size_t)(r0+0)*n + j];
    int m1 = A[(size_t)(r0+1)*n + j];
    int m2 = A[(size_t)(r0+2)*n + j];
    int m3 = A[(size_t)(r0+3)*n + j];
    s0 = (m0>0) ? s0 : -1e9f;
    s1 = (m1>0) ? s1 : -1e9f;
    s2 = (m2>0) ? s2 : -1e9f;
    s3 = (m3>0) ? s3 : -1e9f;
    sc[0][j]=s0; sc[1][j]=s1; sc[2][j]=s2; sc[3][j]=s3;
    lm0=fmaxf(lm0,s0); lm1=fmaxf(lm1,s1); lm2=fmaxf(lm2,s2); lm3=fmaxf(lm3,s3);
  }
  {
    float w0=waveReduceMax(lm0), w1=waveReduceMax(lm1), w2=waveReduceMax(lm2), w3=waveReduceMax(lm3);
    if(lane==0){ redm[0][w]=w0; redm[1][w]=w1; redm[2][w]=w2; redm[3][w]=w3; }
  }
  __syncthreads();
  float m[4];
  #pragma unroll
  for(int r=0;r<4;r++) m[r] = fmaxf(fmaxf(redm[r][0],redm[r][1]), fmaxf(redm[r][2],redm[r][3]));
  __syncthreads();
  float ls0=0.f, ls1=0.f, ls2=0.f, ls3=0.f;
  for(int j=t; j<n; j+=256){
    float e0=__expf(sc[0][j]-m[0]); sc[0][j]=e0; ls0+=e0;
    float e1=__expf(sc[1][j]-m[1]); sc[1][j]=e1; ls1+=e1;
    float e2=__expf(sc[2][j]-m[2]); sc[2][j]=e2; ls2+=e2;
    float e3=__expf(sc[3][j]-m[3]); sc[3][j]=e3; ls3+=e3;
  }
  {
    float w0=waveReduceSum(ls0), w1=waveReduceSum(ls1), w2=waveReduceSum(ls2), w3=waveReduceSum(ls3);
    if(lane==0){ redm[0][w]=w0; redm[1][w]=w1; redm[2][w]=w2; redm[3][w]=w3; }
  }
  __syncthreads();   // sums visible AND all sc exp-writes visible
  float S[4];
  #pragma unroll
  for(int r=0;r<4;r++) S[r] = redm[r][0]+redm[r][1]+redm[r][2]+redm[r][3];
  if(D==GH){
    float acc0=0.f, acc1=0.f, acc2=0.f, acc3=0.f;
    const int c = lane, part = w;
    #pragma unroll 2
    for(int j=part; j<n; j+=4){
      float hv = Hn[(size_t)j*GH + c];
      acc0 = fmaf(sc[0][j], hv, acc0);
      acc1 = fmaf(sc[1][j], hv, acc1);
      acc2 = fmaf(sc[2][j], hv, acc2);
      acc3 = fmaf(sc[3][j], hv, acc3);
    }
    outp[part][0][c]=acc0; outp[part][1][c]=acc1; outp[part][2][c]=acc2; outp[part][3][c]=acc3;
    __syncthreads();
    int r = w;
    float tot = outp[0][r][lane]+outp[1][r][lane]+outp[2][r][lane]+outp[3][r][lane];
    out[(size_t)(r0+r)*GH + lane] = fmaxf(tot/S[r], 0.f);
  } else {
    float a00=0,a01=0,a02=0, a10=0,a11=0,a12=0, a20=0,a21=0,a22=0, a30=0,a31=0,a32=0;
    for(int j=t; j<n; j+=256){
      float h0=Hn[(size_t)j*3+0], h1=Hn[(size_t)j*3+1], h2=Hn[(size_t)j*3+2];
      float e0=sc[0][j], e1=sc[1][j], e2=sc[2][j], e3=sc[3][j];
      a00=fmaf(e0,h0,a00); a01=fmaf(e0,h1,a01); a02=fmaf(e0,h2,a02);
      a10=fmaf(e1,h0,a10); a11=fmaf(e1,h1,a11); a12=fmaf(e1,h2,a12);
      a20=fmaf(e2,h0,a20); a21=fmaf(e2,h1,a21); a22=fmaf(e2,h2,a22);
      a30=fmaf(e3,h0,a30); a31=fmaf(e3,h1,a31); a32=fmaf(e3,h2,a32);
    }
    float v[12] = {a00,a01,a02,a10,a11,a12,a20,a21,a22,a30,a31,a32};
    #pragma unroll
    for(int i=0;i<12;i++){
      float ws = waveReduceSum(v[i]);
      if(lane==0) out3[w][i/3][i%3] = ws;
    }
    __syncthreads();
    if(t < 4){
      int r = t;
      float t0 = out3[0][r][0]+out3[1][r][0]+out3[2][r][0]+out3[3][r][0];
      float t1 = out3[0][r][1]+out3[1][r][1]+out3[2][r][1]+out3[3][r][1];
      float t2 = out3[0][r][2]+out3[1][r][2]+out3[2][r][2]+out3[3][r][2];
      float v0 = fmaxf(t0/S[r], 0.f);
      float v1 = fmaxf(t1/S[r], 0.f);
      float v2 = fmaxf(t2/S[r], 0.f);
      if(FINAL){
        float mm = fmaxf(v0, fmaxf(v1,v2));
        float e0=__expf(v0-mm), e1=__expf(v1-mm), e2=__expf(v2-mm);
        float ss = e0+e1+e2;
        out[(size_t)(r0+r)*3+0]=e0/ss; out[(size_t)(r0+r)*3+1]=e1/ss; out[(size_t)(r0+r)*3+2]=e2/ss;
      } else {
        out[(size_t)(r0+r)*3+0]=v0; out[(size_t)(r0+r)*3+1]=v1; out[(size_t)(r0+r)*3+2]=v2;
      }
    }
  }
}

// ---------- fuse scales (no atomics) ----------
__global__ void k_fuse(const int* __restrict__ s0, const int* __restrict__ s1, const int* __restrict__ s2,
                       const float* __restrict__ S0, const float* __restrict__ S1, const float* __restrict__ S2,
                       const float* __restrict__ cst, float* __restrict__ fused){
  int p = blockIdx.x*256 + threadIdx.x;
  if(p >= N_PIX) return;
  float w0=cst[0], w1=cst[1], w2=cst[2];
  int a=s0[p], b=s1[p], c=s2[p];
  #pragma unroll
  for(int e=0;e<3;e++){
    float f = w0*S0[a*3+e] + w1*S1[b*3+e] + w2*S2[c*3+e];
    fused[(size_t)p*3+e] = f;
  }
}

// ---------- superpixel sums of fused via CSR gather ----------
__global__ __launch_bounds__(128) void k_spsum0(const float* __restrict__ fused, const int* __restrict__ offs,
                                                const int* __restrict__ cnt, const int* __restrict__ list,
                                                float* __restrict__ spsum){
  __shared__ float r[2][3];
  int s = blockIdx.x;
  int t = threadIdx.x, w = t>>6, lane = t&63;
  int n = cnt[s], st = offs[s];
  float a0=0.f, a1=0.f, a2=0.f;
  for(int q=t; q<n; q+=128){
    int p = list[st+q];
    a0 += fused[(size_t)p*3+0];
    a1 += fused[(size_t)p*3+1];
    a2 += fused[(size_t)p*3+2];
  }
  a0 = waveReduceSum(a0); a1 = waveReduceSum(a1); a2 = waveReduceSum(a2);
  if(lane==0){ r[w][0]=a0; r[w][1]=a1; r[w][2]=a2; }
  __syncthreads();
  if(t==0){
    spsum[s*3+0]=r[0][0]+r[1][0];
    spsum[s*3+1]=r[0][1]+r[1][1];
    spsum[s*3+2]=r[0][2]+r[1][2];
  }
}

// ---------- PCR: smoothed_sp[r] = softmax(attn[r]) @ (spsum/cnt) ----------
__global__ __launch_bounds__(256) void k_pcr(const float* __restrict__ attn, const float* __restrict__ spsum,
                                             const int* __restrict__ cnt0, float* __restrict__ sm){
  __shared__ float buf[2048];
  __shared__ float red[4];
  __shared__ float r3[256][3];
  int r=blockIdx.x, t=threadIdx.x;
  float lmax=-INFINITY;
  for(int j=t;j<2000;j+=256){ float v=attn[(size_t)r*2000+j]; buf[j]=v; lmax=fmaxf(lmax,v); }
  float wm=waveReduceMax(lmax);
  if((t&63)==0) red[t>>6]=wm;
  __syncthreads();
  float m = fmaxf(fmaxf(red[0],red[1]),fmaxf(red[2],red[3]));
  __syncthreads();
  float lsum=0.f;
  for(int j=t;j<2000;j+=256){ float e=__expf(buf[j]-m); buf[j]=e; lsum+=e; }
  float wsu=waveReduceSum(lsum);
  if((t&63)==0) red[t>>6]=wsu;
  __syncthreads();
  float S=red[0]+red[1]+red[2]+red[3];
  float a0=0.f,a1=0.f,a2=0.f;
  for(int j=t;j<2000;j+=256){
    float e=buf[j];
    float inv = 1.f / fmaxf((float)cnt0[j], 1.f);
    a0=fmaf(e, spsum[j*3+0]*inv, a0);
    a1=fmaf(e, spsum[j*3+1]*inv, a1);
    a2=fmaf(e, spsum[j*3+2]*inv, a2);
  }
  r3[t][0]=a0; r3[t][1]=a1; r3[t][2]=a2;
  __syncthreads();
  for(int st=128;st>0;st>>=1){
    if(t<st){ r3[t][0]+=r3[t+st][0]; r3[t][1]+=r3[t+st][1]; r3[t][2]+=r3[t+st][2]; }
    __syncthreads();
  }
  if(t==0){ sm[r*3+0]=r3[0][0]/S; sm[r*3+1]=r3[0][1]/S; sm[r*3+2]=r3[0][2]/S; }
}

// ---------- S_flat + argmax class index ----------
__global__ void k_sflat(const float* __restrict__ fused, const int* __restrict__ s0,
                        const float* __restrict__ sm, const float* __restrict__ cst,
                        float* __restrict__ Sf, int* __restrict__ ci){
  int p = blockIdx.x*256 + threadIdx.x;
  if(p >= N_PIX) return;
  float a = cst[3];
  int s = s0[p];
  float x0 = a*sm[s*3+0] + (1.f-a)*fused[(size_t)p*3+0];
  float x1 = a*sm[s*3+1] + (1.f-a)*fused[(size_t)p*3+1];
  float x2 = a*sm[s*3+2] + (1.f-a)*fused[(size_t)p*3+2];
  Sf[(size_t)p*3+0]=x0; Sf[(size_t)p*3+1]=x1; Sf[(size_t)p*3+2]=x2;
  int c=0; float b=x0;
  if(x1>b){c=1;b=x1;}
  if(x2>b){c=2;}
  ci[p]=c;
}

// ---------- weight pre-pack into MFMA B-fragment order, bf16 hi/lo ----------
__global__ void k_packw(const float* __restrict__ W, int Kreal, int Nreal, int nkt, int nnt,
                        u16* __restrict__ dhi, u16* __restrict__ dlo){
  int gid = blockIdx.x*256 + threadIdx.x;
  int total = nnt*nkt*512;
  if(gid >= total) return;
  int j = gid & 7, l = (gid>>3)&63;
  int rem = gid >> 9;               // nt*nkt + ks
  int ks = rem % nkt;
  int nt = rem / nkt;
  int k = ks*32 + (l>>4)*8 + j;
  int n = nt*16 + (l&15);
  float w = (k < Kreal && n < Nreal) ? W[(size_t)k*Nreal + n] : 0.f;
  u16 hi = f2bf(w);
  dhi[gid] = hi;
  dlo[gid] = f2bf(w - bf2f(hi));
}

// ---------- MFMA MLP (156->128->128->156) + atomic-free shuffle-reduced epilogue ----------
#define MFMA(a,b,c) __builtin_amdgcn_mfma_f32_16x16x32_bf16((a),(b),(c),0,0,0)

__global__ __launch_bounds__(256, 4) void k_mlp_mfma(
    const float* __restrict__ Y, const int* __restrict__ ci,
    const u16* __restrict__ P1h, const u16* __restrict__ P1l,
    const u16* __restrict__ P2h, const u16* __restrict__ P2l,
    const u16* __restrict__ P3h, const u16* __restrict__ P3l,
    const float* __restrict__ b1, const float* __restrict__ b2, const float* __restrict__ b3,
    float* __restrict__ gsum, float* __restrict__ gwsum){
  __shared__ u16 SH[32*168];                 // X-hi [32][168]  ->  A-hi [32][136]
  __shared__ u16 SL[32*168];                 // X-lo            ->  A-lo
  __shared__ float csum[480], cwsum[480];    // per-class partial sums [3][160]
  __shared__ int cis[32];
  const int t = threadIdx.x;
  const int lane = t & 63, w = t >> 6;
  const int g = lane >> 4, r16 = lane & 15;
  const size_t p0 = (size_t)blockIdx.x * 32;

  for(int i=t;i<480;i+=256){ csum[i]=0.f; cwsum[i]=0.f; }
  if(t<32) cis[t] = ci[p0+t];
  // stage Y tile: 32 rows x 39 float4, split to bf16 hi/lo, packed u32 LDS writes
  for(int i=t;i<1248;i+=256){
    int row = i/39, q = i - row*39, c0 = q*4;
    float4 v = *(const float4*)(Y + (p0+row)*NB + c0);
    u16 h0=f2bf(v.x), h1=f2bf(v.y), h2=f2bf(v.z), h3=f2bf(v.w);
    u16 l0=f2bf(v.x-bf2f(h0)), l1=f2bf(v.y-bf2f(h1)), l2=f2bf(v.z-bf2f(h2)), l3=f2bf(v.w-bf2f(h3));
    *(unsigned*)&SH[row*168+c0]   = (unsigned)h0 | ((unsigned)h1<<16);
    *(unsigned*)&SH[row*168+c0+2] = (unsigned)h2 | ((unsigned)h3<<16);
    *(unsigned*)&SL[row*168+c0]   = (unsigned)l0 | ((unsigned)l1<<16);
    *(unsigned*)&SL[row*168+c0+2] = (unsigned)l2 | ((unsigned)l3<<16);
  }
  if(t<64){ int row=t>>1, o=156+(t&1)*2;
    *(unsigned*)&SH[row*168+o]=0u; *(unsigned*)&SL[row*168+o]=0u; }
  __syncthreads();

  // ---- layer 1: K=160 (5 ks), N=128; wave w -> ntiles {w, w+4} ----
  {
    f32x4 acc[2][2];
    #pragma unroll
    for(int u=0;u<2;u++)
      #pragma unroll
      for(int mt=0;mt<2;mt++) acc[u][mt] = (f32x4){0.f,0.f,0.f,0.f};
    #pragma unroll
    for(int ks=0;ks<5;ks++){
      bfrag8 bh0 = *(const bfrag8*)(P1h + ((size_t)(w*5+ks))*512 + lane*8);
      bfrag8 bl0 = *(const bfrag8*)(P1l + ((size_t)(w*5+ks))*512 + lane*8);
      bfrag8 bh1 = *(const bfrag8*)(P1h + ((size_t)((w+4)*5+ks))*512 + lane*8);
      bfrag8 bl1 = *(const bfrag8*)(P1l + ((size_t)((w+4)*5+ks))*512 + lane*8);
      #pragma unroll
      for(int mt=0;mt<2;mt++){
        bfrag8 ah = *(const bfrag8*)(SH + (mt*16+r16)*168 + g*8 + ks*32);
        bfrag8 al = *(const bfrag8*)(SL + (mt*16+r16)*168 + g*8 + ks*32);
        acc[0][mt]=MFMA(ah,bh0,acc[0][mt]); acc[0][mt]=MFMA(ah,bl0,acc[0][mt]); acc[0][mt]=MFMA(al,bh0,acc[0][mt]);
        acc[1][mt]=MFMA(ah,bh1,acc[1][mt]); acc[1][mt]=MFMA(ah,bl1,acc[1][mt]); acc[1][mt]=MFMA(al,bh1,acc[1][mt]);
      }
    }
    __syncthreads();   // all waves done reading X
    #pragma unroll
    for(int u=0;u<2;u++){
      int c = (w+u*4)*16 + r16;
      float bv = b1[c];
      #pragma unroll
      for(int mt=0;mt<2;mt++)
        #pragma unroll
        for(int r=0;r<4;r++){
          float v = fmaxf(acc[u][mt][r] + bv, 0.f);
          int row = mt*16 + g*4 + r;
          u16 h = f2bf(v);
          SH[row*136+c] = h; SL[row*136+c] = f2bf(v - bf2f(h));
        }
    }
  }
  __syncthreads();

  // ---- layer 2: K=128 (4 ks), N=128; regs across barrier, overwrite A ----
  {
    f32x4 acc[2][2];
    #pragma unroll
    for(int u=0;u<2;u++)
      #pragma unroll
      for(int mt=0;mt<2;mt++) acc[u][mt] = (f32x4){0.f,0.f,0.f,0.f};
    #pragma unroll
    for(int ks=0;ks<4;ks++){
      bfrag8 bh0 = *(const bfrag8*)(P2h + ((size_t)(w*4+ks))*512 + lane*8);
      bfrag8 bl0 = *(const bfrag8*)(P2l + ((size_t)(w*4+ks))*512 + lane*8);
      bfrag8 bh1 = *(const bfrag8*)(P2h + ((size_t)((w+4)*4+ks))*512 + lane*8);
      bfrag8 bl1 = *(const bfrag8*)(P2l + ((size_t)((w+4)*4+ks))*512 + lane*8);
      #pragma unroll
      for(int mt=0;mt<2;mt++){
        bfrag8 ah = *(const bfrag8*)(SH + (mt*16+r16)*136 + g*8 + ks*32);
        bfrag8 al = *(const bfrag8*)(SL + (mt*16+r16)*136 + g*8 + ks*32);
        acc[0][mt]=MFMA(ah,bh0,acc[0][mt]); acc[0][mt]=MFMA(ah,bl0,acc[0][mt]); acc[0][mt]=MFMA(al,bh0,acc[0][mt]);
        acc[1][mt]=MFMA(ah,bh1,acc[1][mt]); acc[1][mt]=MFMA(ah,bl1,acc[1][mt]); acc[1][mt]=MFMA(al,bh1,acc[1][mt]);
      }
    }
    __syncthreads();   // all waves done reading A(layer1)
    #pragma unroll
    for(int u=0;u<2;u++){
      int c = (w+u*4)*16 + r16;
      float bv = b2[c];
      #pragma unroll
      for(int mt=0;mt<2;mt++)
        #pragma unroll
        for(int r=0;r<4;r++){
          float v = fmaxf(acc[u][mt][r] + bv, 0.f);
          int row = mt*16 + g*4 + r;
          u16 h = f2bf(v);
          SH[row*136+c] = h; SL[row*136+c] = f2bf(v - bf2f(h));
        }
    }
  }
  __syncthreads();

  // ---- layer 3: K=128, 20 subtiles over 4 waves (5 chains/wave) + atomic-free epilogue ----
  {
    f32x4 acc[5];
    #pragma unroll
    for(int s=0;s<5;s++) acc[s] = (f32x4){0.f,0.f,0.f,0.f};
    #pragma unroll
    for(int s=0;s<5;s++){
      int idx = w*5 + s, nt = idx>>1, mt = idx&1;
      #pragma unroll
      for(int ks=0;ks<4;ks++){
        bfrag8 bh = *(const bfrag8*)(P3h + ((size_t)(nt*4+ks))*512 + lane*8);
        bfrag8 bl = *(const bfrag8*)(P3l + ((size_t)(nt*4+ks))*512 + lane*8);
        bfrag8 ah = *(const bfrag8*)(SH + (mt*16+r16)*136 + g*8 + ks*32);
        bfrag8 al = *(const bfrag8*)(SL + (mt*16+r16)*136 + g*8 + ks*32);
        acc[s]=MFMA(ah,bh,acc[s]); acc[s]=MFMA(ah,bl,acc[s]); acc[s]=MFMA(al,bh,acc[s]);
      }
    }
    // per-thread class partials: [3 local ntiles][3 classes], explicit regs (no dyn indexing)
    const int ntbase = (w*5) >> 1;
    float cs00=0,cs01=0,cs02=0, cs10=0,cs11=0,cs12=0, cs20=0,cs21=0,cs22=0;
    float cw00=0,cw01=0,cw02=0, cw10=0,cw11=0,cw12=0, cw20=0,cw21=0,cw22=0;
    #pragma unroll
    for(int s=0;s<5;s++){
      int idx = w*5 + s, nt = idx>>1, mt = idx&1;
      int ntl = nt - ntbase;          // 0..2
      int c = nt*16 + r16;
      if(c < 156){
        float bv = b3[c];
        #pragma unroll
        for(int r=0;r<4;r++){
          int p = mt*16 + g*4 + r;
          float e = __expf(acc[s][r] + bv);
          float y = Y[(p0+p)*NB + c];
          float ey = e*y;
          int k = cis[p];
          float e0 = (k==0)?e:0.f, e1 = (k==1)?e:0.f, e2 = (k==2)?e:0.f;
          float y0 = (k==0)?ey:0.f, y1 = (k==1)?ey:0.f, y2 = (k==2)?ey:0.f;
          if(ntl==0){ cs00+=e0; cs01+=e1; cs02+=e2; cw00+=y0; cw01+=y1; cw02+=y2; }
          else if(ntl==1){ cs10+=e0; cs11+=e1; cs12+=e2; cw10+=y0; cw11+=y1; cw12+=y2; }
          else { cs20+=e0; cs21+=e1; cs22+=e2; cw20+=y0; cw21+=y1; cw22+=y2; }
        }
      }
    }
    // reduce over the 4 g-groups (lanes l, l^16, l^32, l^48 share r16)
    #define GRED(v) { v += __shfl_xor(v,16,64); v += __shfl_xor(v,32,64); }
    GRED(cs00) GRED(cs01) GRED(cs02) GRED(cs10) GRED(cs11) GRED(cs12) GRED(cs20) GRED(cs21) GRED(cs22)
    GRED(cw00) GRED(cw01) GRED(cw02) GRED(cw10) GRED(cw11) GRED(cw12) GRED(cw20) GRED(cw21) GRED(cw22)
    #undef GRED
    if(g==0){
      #pragma unroll
      for(int ntl=0;ntl<3;ntl++){
        int nt = ntbase + ntl;
        int c = nt*16 + r16;
        if(c < 156){
          float s0 = (ntl==0)?cs00:((ntl==1)?cs10:cs20);
          float s1 = (ntl==0)?cs01:((ntl==1)?cs11:cs21);
          float s2 = (ntl==0)?cs02:((ntl==1)?cs12:cs22);
          float w0 = (ntl==0)?cw00:((ntl==1)?cw10:cw20);
          float w1 = (ntl==0)?cw01:((ntl==1)?cw11:cw21);
          float w2 = (ntl==0)?cw02:((ntl==1)?cw12:cw22);
          atomicAdd(&csum[0*160 + c], s0);
          atomicAdd(&csum[1*160 + c], s1);
          atomicAdd(&csum[2*160 + c], s2);
          atomicAdd(&cwsum[0*160 + c], w0);
          atomicAdd(&cwsum[1*160 + c], w1);
          atomicAdd(&cwsum[2*160 + c], w2);
        }
      }
    }
  }
  __syncthreads();
  // flush: global atomics into 256 rotation slots (hidden under kernel tail; proven r5-r7)
  float* gs = gsum  + (size_t)(blockIdx.x & 255)*480;
  float* gw = gwsum + (size_t)(blockIdx.x & 255)*480;
  for(int i=t;i<480;i+=256){
    atomicAdd(&gs[i], csum[i]);
    atomicAdd(&gw[i], cwsum[i]);
  }
}

// ---------- final M: reduce 256 slots ----------
__global__ void k_finalM(const float* __restrict__ gsump, const float* __restrict__ gwsump, float* __restrict__ M){
  int e = blockIdx.x*256 + threadIdx.x;
  if(e < 468){
    int cls = e/156, c = e - cls*156;
    int off = cls*160 + c;
    float s=0.f, wv=0.f;
    for(int k=0;k<256;k++){ s += gsump[(size_t)k*480 + off]; wv += gwsump[(size_t)k*480 + off]; }
    M[e] = (s > 0.f) ? (wv / fmaxf(s, 1e-30f)) : 0.f;
  }
}

// ---------- Y_hat = S_flat @ M, float4 stores ----------
__global__ void k_yhat4(const float* __restrict__ Sf, const float* __restrict__ M, float4* __restrict__ out){
  unsigned idx = blockIdx.x*256u + threadIdx.x;   // N_PIX*39 float4s, grid exact
  unsigned p = idx / 39u, q = idx - p*39u;
  unsigned c0 = q*4u;
  float4 m0 = *(const float4*)(M + c0);
  float4 m1 = *(const float4*)(M + 156 + c0);
  float4 m2 = *(const float4*)(M + 312 + c0);
  float s0 = Sf[(size_t)p*3+0], s1 = Sf[(size_t)p*3+1], s2 = Sf[(size_t)p*3+2];
  float4 r;
  r.x = s0*m0.x + s1*m1.x + s2*m2.x;
  r.y = s0*m0.y + s1*m1.y + s2*m2.y;
  r.z = s0*m0.z + s1*m1.z + s2*m2.z;
  r.w = s0*m0.w + s1*m1.w + s2*m2.w;
  out[idx] = r;
}

extern "C" void kernel_launch(void* const* d_in, const int* in_sizes, int n_in,
                              void* d_out, int out_size, void* d_ws, size_t ws_size,
                              hipStream_t stream){
  const float* Y    = (const float*)d_in[0];
  const int*   seg0 = (const int*)d_in[1];
  const int*   A0   = (const int*)d_in[2];
  const int*   seg1 = (const int*)d_in[3];
  const int*   A1   = (const int*)d_in[4];
  const int*   seg2 = (const int*)d_in[5];
  const int*   A2   = (const int*)d_in[6];
  const float* attn = (const float*)d_in[7];
  const float* alpha= (const float*)d_in[8];
  const float* sw   = (const float*)d_in[9];
  const float* W1a[3] = {(const float*)d_in[10], (const float*)d_in[14], (const float*)d_in[18]};
  const float* b1a[3] = {(const float*)d_in[11], (const float*)d_in[15], (const float*)d_in[19]};
  const float* W2a[3] = {(const float*)d_in[12], (const float*)d_in[16], (const float*)d_in[20]};
  const float* b2a[3] = {(const float*)d_in[13], (const float*)d_in[17], (const float*)d_in[21]};
  const float* Wm1=(const float*)d_in[22]; const float* bm1=(const float*)d_in[23];
  const float* Wm2=(const float*)d_in[24]; const float* bm2=(const float*)d_in[25];
  const float* Wm3=(const float*)d_in[26]; const float* bm3=(const float*)d_in[27];
  float* out = (float*)d_out;

  const int nseg[3] = {2000, 1000, 500};

  char* base = (char*)d_ws;
  size_t off = 0;
  auto alloc = [&](size_t bytes)->char*{
    char* r = base + off;
    off += (bytes + 255) & ~(size_t)255;
    return r;
  };
  int* cnt[3]; int* offs[3]; int* cur[3]; int* lst[3];
  for(int i=0;i<3;i++) cnt[i]  = (int*)alloc((size_t)nseg[i]*4);
  for(int i=0;i<3;i++) offs[i] = (int*)alloc((size_t)nseg[i]*4);
  for(int i=0;i<3;i++) cur[i]  = (int*)alloc((size_t)nseg[i]*4);
  for(int i=0;i<3;i++) lst[i]  = (int*)alloc((size_t)N_PIX*4);
  float* X_all   = (float*)alloc((size_t)3500*NB*4);    // rows: [0,2000) s0, [2000,3000) s1, [3000,3500) s2
  float* Hn_all  = (float*)alloc((size_t)3500*64*4);
  float* x1b_all = (float*)alloc((size_t)3500*64*4);
  float* Hn2_all = (float*)alloc((size_t)3500*3*4);
  float* Ss_all  = (float*)alloc((size_t)3500*3*4);
  float* cst   = (float*)alloc(64);
  float* fused = (float*)alloc((size_t)N_PIX*3*4);
  float* spsum = (float*)alloc((size_t)2000*3*4);
  float* smth  = (float*)alloc((size_t)2000*3*4);
  float* Sf    = (float*)alloc((size_t)N_PIX*3*4);
  int*   ci    = (int*)alloc((size_t)N_PIX*4);
  u16* P1h = (u16*)alloc((size_t)20480*2); u16* P1l = (u16*)alloc((size_t)20480*2);
  u16* P2h = (u16*)alloc((size_t)16384*2); u16* P2l = (u16*)alloc((size_t)16384*2);
  u16* P3h = (u16*)alloc((size_t)20480*2); u16* P3l = (u16*)alloc((size_t)20480*2);
  float* gsump  = (float*)alloc((size_t)256*480*4);
  float* gwsump = (float*)alloc((size_t)256*480*4);
  float* Mbuf   = (float*)alloc((size_t)480*4);

  float* X0 = X_all;            float* X1 = X_all + (size_t)2000*NB;   float* X2 = X_all + (size_t)3000*NB;
  const float* Ss0 = Ss_all;    const float* Ss1 = Ss_all + 2000*3;    const float* Ss2 = Ss_all + 3000*3;

  // per-call re-init (replay/poison safe)
  for(int i=0;i<3;i++) hipMemsetAsync(cnt[i], 0, (size_t)nseg[i]*4, stream);
  hipMemsetAsync(gsump, 0, (size_t)256*480*4, stream);
  hipMemsetAsync(gwsump, 0, (size_t)256*480*4, stream);
  k_prep<<<1,64,0,stream>>>(sw, alpha, cst);

  // weight pre-pack
  k_packw<<<(8*5*512+255)/256,256,0,stream>>>(Wm1, 156, 128, 5, 8, P1h, P1l);
  k_packw<<<(8*4*512+255)/256,256,0,stream>>>(Wm2, 128, 128, 4, 8, P2h, P2l);
  k_packw<<<(10*4*512+255)/256,256,0,stream>>>(Wm3, 128, 156, 4, 10, P3h, P3l);

  // CSR + segment means
  k_count<<<N_PIX/256,256,0,stream>>>(seg0,seg1,seg2,cnt[0],cnt[1],cnt[2]);
  k_scan<<<3,256,0,stream>>>(cnt[0],cnt[1],cnt[2],offs[0],offs[1],offs[2],cur[0],cur[1],cur[2]);
  k_fill<<<N_PIX/256,256,0,stream>>>(seg0,seg1,seg2,cur[0],cur[1],cur[2],lst[0],lst[1],lst[2]);
  k_segmean3<<<3500,192,0,stream>>>(Y,
      offs[0],cnt[0],lst[0],X0,
      offs[1],cnt[1],lst[1],X1,
      offs[2],cnt[2],lst[2],X2);

  // Multi-scale GAT encoder (batched: 4 launches total)
  k_linearB<<<(3500*64+255)/256,256,0,stream>>>(X_all, NB, 64,
      W1a[0],b1a[0],W1a[1],b1a[1],W1a[2],b1a[2], Hn_all);
  k_attn4B<64,false><<<875,256,0,stream>>>(Hn_all, A0,A1,A2, x1b_all);
  k_linearB<<<(3500*3+255)/256,256,0,stream>>>(x1b_all, 64, 3,
      W2a[0],b2a[0],W2a[1],b2a[1],W2a[2],b2a[2], Hn2_all);
  k_attn4B<3,true><<<875,256,0,stream>>>(Hn2_all, A0,A1,A2, Ss_all);

  // fuse + spsum gather + PCR
  k_fuse<<<N_PIX/256,256,0,stream>>>(seg0,seg1,seg2,Ss0,Ss1,Ss2,cst,fused);
  k_spsum0<<<2000,128,0,stream>>>(fused, offs[0], cnt[0], lst[0], spsum);
  k_pcr<<<2000,256,0,stream>>>(attn, spsum, cnt[0], smth);
  k_sflat<<<N_PIX/256,256,0,stream>>>(fused, seg0, smth, cst, Sf, ci);

  // ACDE: MFMA MLP + atomic-free epilogue, 256-slot atomic flush
  k_mlp_mfma<<<N_PIX/32,256,0,stream>>>(Y, ci, P1h,P1l,P2h,P2l,P3h,P3l, bm1,bm2,bm3, gsump, gwsump);
  k_finalM<<<2,256,0,stream>>>(gsump, gwsump, Mbuf);
  k_yhat4<<<(N_PIX/256)*39,256,0,stream>>>(Sf, Mbuf, (float4*)out);
  (void)in_sizes; (void)n_in; (void)out_size;
}

// Round 12
// 870.796 us; speedup vs baseline: 1.6995x; 1.0044x over previous
//
#include <hip/hip_runtime.h>
#include <hip/hip_bf16.h>
#include <math.h>

#define N_PIX (512*512)
#define NB 156
#define GH 64

typedef unsigned short u16;
typedef __attribute__((ext_vector_type(8))) short bfrag8;   // 8 bf16 = 4 VGPRs
typedef __attribute__((ext_vector_type(4))) float f32x4;    // MFMA accumulator

// ---------- bf16 helpers ----------
__device__ __forceinline__ u16 f2bf(float x){
  unsigned u = __float_as_uint(x);
  unsigned r = (u + 0x7FFFu + ((u >> 16) & 1u)) >> 16;
  return (u16)r;
}
__device__ __forceinline__ float bf2f(u16 h){
  return __uint_as_float(((unsigned)h) << 16);
}
// packed RNE: low 16 = bf16(a), high 16 = bf16(b)  (v_cvt_pk_bf16_f32)
__device__ __forceinline__ unsigned pkbf(float a, float b){
  __hip_bfloat162 h = __float22bfloat162_rn(make_float2(a,b));
  unsigned u; __builtin_memcpy(&u,&h,4); return u;
}

__device__ __forceinline__ float waveReduceMax(float v){
  #pragma unroll
  for(int o=32;o>0;o>>=1) v = fmaxf(v, __shfl_down(v, o, 64));
  return v;
}
__device__ __forceinline__ float waveReduceSum(float v){
  #pragma unroll
  for(int o=32;o>0;o>>=1) v += __shfl_down(v, o, 64);
  return v;
}

// ---------- derived constants: softmax(scale_weights), clip(alpha) ----------
__global__ void k_prep(const float* __restrict__ sw, const float* __restrict__ alpha, float* __restrict__ cst){
  if(threadIdx.x==0 && blockIdx.x==0){
    float m = fmaxf(sw[0], fmaxf(sw[1], sw[2]));
    float e0=expf(sw[0]-m), e1=expf(sw[1]-m), e2=expf(sw[2]-m);
    float s = e0+e1+e2;
    cst[0]=e0/s; cst[1]=e1/s; cst[2]=e2/s;
    cst[3]=fminf(fmaxf(alpha[0],0.f),1.f);
  }
}

// ---------- CSR build ----------
__global__ void k_count(const int* __restrict__ s0, const int* __restrict__ s1, const int* __restrict__ s2,
                        int* c0, int* c1, int* c2){
  int p = blockIdx.x*256 + threadIdx.x;
  if(p < N_PIX){
    atomicAdd(&c0[s0[p]],1);
    atomicAdd(&c1[s1[p]],1);
    atomicAdd(&c2[s2[p]],1);
  }
}

__global__ __launch_bounds__(256) void k_scan(const int* __restrict__ c0, const int* __restrict__ c1, const int* __restrict__ c2,
                       int* o0, int* o1, int* o2, int* u0, int* u1, int* u2){
  const int* cnt; int* offs; int* cur; int n;
  if(blockIdx.x==0){ cnt=c0; offs=o0; cur=u0; n=2000; }
  else if(blockIdx.x==1){ cnt=c1; offs=o1; cur=u1; n=1000; }
  else { cnt=c2; offs=o2; cur=u2; n=500; }
  __shared__ int l[2048];
  __shared__ int cs[256];
  int t = threadIdx.x;
  for(int i=t;i<2048;i+=256) l[i] = (i<n) ? cnt[i] : 0;
  __syncthreads();
  int s = 0;
  #pragma unroll
  for(int j=0;j<8;j++) s += l[t*8+j];
  cs[t] = s;
  __syncthreads();
  for(int d=1; d<256; d<<=1){
    int v = (t>=d) ? cs[t-d] : 0;
    __syncthreads();
    cs[t] += v;
    __syncthreads();
  }
  int run = cs[t] - s;
  for(int j=0;j<8;j++){
    int idx = t*8+j;
    int o = run;
    run += l[idx];
    if(idx < n){ offs[idx] = o; cur[idx] = o; }
  }
}

__global__ void k_fill(const int* __restrict__ s0, const int* __restrict__ s1, const int* __restrict__ s2,
                       int* u0, int* u1, int* u2, int* L0, int* L1, int* L2){
  int p = blockIdx.x*256 + threadIdx.x;
  if(p < N_PIX){
    int a = atomicAdd(&u0[s0[p]],1); L0[a] = p;
    int b = atomicAdd(&u1[s1[p]],1); L1[b] = p;
    int c = atomicAdd(&u2[s2[p]],1); L2[c] = p;
  }
}

// ---------- fused segment mean over all 3 scales: 192 thr, 2 pixel-groups of 78 lanes ----------
__global__ __launch_bounds__(192) void k_segmean3(const float* __restrict__ Y,
    const int* __restrict__ o0, const int* __restrict__ c0, const int* __restrict__ l0, float* __restrict__ X0,
    const int* __restrict__ o1, const int* __restrict__ c1, const int* __restrict__ l1, float* __restrict__ X1,
    const int* __restrict__ o2, const int* __restrict__ c2, const int* __restrict__ l2, float* __restrict__ X2){
  int b = blockIdx.x;
  const int *offs, *cnt, *list; float* X; int s;
  if(b < 2000){ s=b;      offs=o0; cnt=c0; list=l0; X=X0; }
  else if(b < 3000){ s=b-2000; offs=o1; cnt=c1; list=l1; X=X1; }
  else { s=b-3000; offs=o2; cnt=c2; list=l2; X=X2; }
  __shared__ float part[156];
  int t = threadIdx.x;
  int grp = t / 96, tb = t - grp*96;
  int n = cnt[s], st = offs[s];
  float ax=0.f, ay=0.f;
  if(tb < 78){
    int q = grp;
    for(; q+6<n; q+=8){
      int p0 = list[st+q], p1 = list[st+q+2], p2 = list[st+q+4], p3 = list[st+q+6];
      float2 v0 = *(const float2*)(Y + (size_t)p0*NB + tb*2);
      float2 v1 = *(const float2*)(Y + (size_t)p1*NB + tb*2);
      float2 v2 = *(const float2*)(Y + (size_t)p2*NB + tb*2);
      float2 v3 = *(const float2*)(Y + (size_t)p3*NB + tb*2);
      ax += (v0.x + v1.x) + (v2.x + v3.x);
      ay += (v0.y + v1.y) + (v2.y + v3.y);
    }
    for(; q<n; q+=2){
      int p0 = list[st+q];
      float2 v0 = *(const float2*)(Y + (size_t)p0*NB + tb*2);
      ax += v0.x; ay += v0.y;
    }
  }
  if(grp==1 && tb<78){ part[tb*2]=ax; part[tb*2+1]=ay; }
  __syncthreads();
  if(grp==0 && tb<78){
    float inv = 1.f / fmaxf((float)n, 1.f);
    float2 r; r.x = (ax + part[tb*2])*inv; r.y = (ay + part[tb*2+1])*inv;
    *(float2*)(X + (size_t)s*NB + tb*2) = r;
  }
}

// ---------- batched small linear over all 3 scales (rows 0..3499) ----------
__global__ void k_linearB(const float* __restrict__ X, int K, int D,
                          const float* __restrict__ W0, const float* __restrict__ bb0,
                          const float* __restrict__ W1, const float* __restrict__ bb1,
                          const float* __restrict__ W2, const float* __restrict__ bb2,
                          float* __restrict__ out){
  int gid = blockIdx.x*256 + threadIdx.x;
  if(gid >= 3500*D) return;
  int r = gid / D, c = gid - r*D;
  const float* W; const float* bb;
  if(r < 2000){ W=W0; bb=bb0; }
  else if(r < 3000){ W=W1; bb=bb1; }
  else { W=W2; bb=bb2; }
  const float* xr = X + (size_t)r*K;
  float acc = bb[c];
  for(int k=0;k<K;k++) acc = fmaf(xr[k], W[(size_t)k*D + c], acc);
  out[gid] = acc;
}

// ---------- batched GAT masked attention, 4 rows per block, all 3 scales ----------
template<int D, bool FINAL>
__global__ __launch_bounds__(256) void k_attn4B(const float* __restrict__ HnAll,
                                                const int* __restrict__ A0, const int* __restrict__ A1, const int* __restrict__ A2,
                                                float* __restrict__ outAll){
  __shared__ float sc[4][2048];
  __shared__ float hr[4][GH];
  __shared__ float redm[4][4];
  __shared__ float outp[4][4][GH];   // part, r, c (D==64)
  __shared__ float out3[4][4][4];    // wave, r, c (D==3)
  const int t = threadIdx.x, w = t>>6, lane = t&63;
  int b = blockIdx.x;
  int n, r0; size_t base; const int* A;
  if(b < 500){ n=2000; base=0;    r0=b*4;        A=A0; }
  else if(b < 750){ n=1000; base=2000; r0=(b-500)*4; A=A1; }
  else { n=500;  base=3000; r0=(b-750)*4; A=A2; }
  const int OD = FINAL ? 3 : (D==GH ? GH : 3);
  const float* Hn = HnAll + base*D;
  float* out = outAll + base*OD;
  if(D==GH){
    hr[w][lane] = Hn[(size_t)(r0 + w)*GH + lane];
  } else {
    if(t < 12) hr[t/3][t%3] = Hn[(size_t)(r0 + t/3)*3 + (t%3)];
  }
  __syncthreads();
  float lm0=-INFINITY, lm1=-INFINITY, lm2=-INFINITY, lm3=-INFINITY;
  for(int j=t; j<n; j+=256){
    float s0,s1,s2,s3;
    if(D==GH){
      const float4* hj = (const float4*)(Hn + (size_t)j*GH);
      s0=s1=s2=s3=0.f;
      #pragma unroll
      for(int k4=0;k4<GH/4;k4++){
        float4 h  = hj[k4];
        float4 a0 = *(const float4*)&hr[0][k4*4];
        float4 a1 = *(const float4*)&hr[1][k4*4];
        float4 a2 = *(const float4*)&hr[2][k4*4];
        float4 a3 = *(const float4*)&hr[3][k4*4];
        s0 = fmaf(a0.x,h.x, fmaf(a0.y,h.y, fmaf(a0.z,h.z, fmaf(a0.w,h.w, s0))));
        s1 = fmaf(a1.x,h.x, fmaf(a1.y,h.y, fmaf(a1.z,h.z, fmaf(a1.w,h.w, s1))));
        s2 = fmaf(a2.x,h.x, fmaf(a2.y,h.y, fmaf(a2.z,h.z, fmaf(a2.w,h.w, s2))));
        s3 = fmaf(a3.x,h.x, fmaf(a3.y,h.y, fmaf(a3.z,h.z, fmaf(a3.w,h.w, s3))));
      }
    } else {
      float h0=Hn[(size_t)j*3+0], h1=Hn[(size_t)j*3+1], h2=Hn[(size_t)j*3+2];
      s0 = hr[0][0]*h0 + hr[0][1]*h1 + hr[0][2]*h2;
      s1 = hr[1][0]*h0 + hr[1][1]*h1 + hr[1][2]*h2;
      s2 = hr[2][0]*h0 + hr[2][1]*h1 + hr[2][2]*h2;
      s3 = hr[3][0]*h0 + hr[3][1]*h1 + hr[3][2]*h2;
    }
    int m0 = A[(size_t)(r0+0)*n + j];
    int m1 = A[(size_t)(r0+1)*n + j];
    int m2 = A[(size_t)(r0+2)*n + j];
    int m3 = A[(size_t)(r0+3)*n + j];
    s0 = (m0>0) ? s0 : -1e9f;
    s1 = (m1>0) ? s1 : -1e9f;
    s2 = (m2>0) ? s2 : -1e9f;
    s3 = (m3>0) ? s3 : -1e9f;
    sc[0][j]=s0; sc[1][j]=s1; sc[2][j]=s2; sc[3][j]=s3;
    lm0=fmaxf(lm0,s0); lm1=fmaxf(lm1,s1); lm2=fmaxf(lm2,s2); lm3=fmaxf(lm3,s3);
  }
  {
    float w0=waveReduceMax(lm0), w1=waveReduceMax(lm1), w2=waveReduceMax(lm2), w3=waveReduceMax(lm3);
    if(lane==0){ redm[0][w]=w0; redm[1][w]=w1; redm[2][w]=w2; redm[3][w]=w3; }
  }
  __syncthreads();
  float m[4];
  #pragma unroll
  for(int r=0;r<4;r++) m[r] = fmaxf(fmaxf(redm[r][0],redm[r][1]), fmaxf(redm[r][2],redm[r][3]));
  __syncthreads();
  float ls0=0.f, ls1=0.f, ls2=0.f, ls3=0.f;
  for(int j=t; j<n; j+=256){
    float e0=__expf(sc[0][j]-m[0]); sc[0][j]=e0; ls0+=e0;
    float e1=__expf(sc[1][j]-m[1]); sc[1][j]=e1; ls1+=e1;
    float e2=__expf(sc[2][j]-m[2]); sc[2][j]=e2; ls2+=e2;
    float e3=__expf(sc[3][j]-m[3]); sc[3][j]=e3; ls3+=e3;
  }
  {
    float w0=waveReduceSum(ls0), w1=waveReduceSum(ls1), w2=waveReduceSum(ls2), w3=waveReduceSum(ls3);
    if(lane==0){ redm[0][w]=w0; redm[1][w]=w1; redm[2][w]=w2; redm[3][w]=w3; }
  }
  __syncthreads();
  float S[4];
  #pragma unroll
  for(int r=0;r<4;r++) S[r] = redm[r][0]+redm[r][1]+redm[r][2]+redm[r][3];
  if(D==GH){
    float acc0=0.f, acc1=0.f, acc2=0.f, acc3=0.f;
    const int c = lane, part = w;
    #pragma unroll 2
    for(int j=part; j<n; j+=4){
      float hv = Hn[(size_t)j*GH + c];
      acc0 = fmaf(sc[0][j], hv, acc0);
      acc1 = fmaf(sc[1][j], hv, acc1);
      acc2 = fmaf(sc[2][j], hv, acc2);
      acc3 = fmaf(sc[3][j], hv, acc3);
    }
    outp[part][0][c]=acc0; outp[part][1][c]=acc1; outp[part][2][c]=acc2; outp[part][3][c]=acc3;
    __syncthreads();
    int r = w;
    float tot = outp[0][r][lane]+outp[1][r][lane]+outp[2][r][lane]+outp[3][r][lane];
    out[(size_t)(r0+r)*GH + lane] = fmaxf(tot/S[r], 0.f);
  } else {
    float a00=0,a01=0,a02=0, a10=0,a11=0,a12=0, a20=0,a21=0,a22=0, a30=0,a31=0,a32=0;
    for(int j=t; j<n; j+=256){
      float h0=Hn[(size_t)j*3+0], h1=Hn[(size_t)j*3+1], h2=Hn[(size_t)j*3+2];
      float e0=sc[0][j], e1=sc[1][j], e2=sc[2][j], e3=sc[3][j];
      a00=fmaf(e0,h0,a00); a01=fmaf(e0,h1,a01); a02=fmaf(e0,h2,a02);
      a10=fmaf(e1,h0,a10); a11=fmaf(e1,h1,a11); a12=fmaf(e1,h2,a12);
      a20=fmaf(e2,h0,a20); a21=fmaf(e2,h1,a21); a22=fmaf(e2,h2,a22);
      a30=fmaf(e3,h0,a30); a31=fmaf(e3,h1,a31); a32=fmaf(e3,h2,a32);
    }
    float v[12] = {a00,a01,a02,a10,a11,a12,a20,a21,a22,a30,a31,a32};
    #pragma unroll
    for(int i=0;i<12;i++){
      float ws = waveReduceSum(v[i]);
      if(lane==0) out3[w][i/3][i%3] = ws;
    }
    __syncthreads();
    if(t < 4){
      int r = t;
      float t0 = out3[0][r][0]+out3[1][r][0]+out3[2][r][0]+out3[3][r][0];
      float t1 = out3[0][r][1]+out3[1][r][1]+out3[2][r][1]+out3[3][r][1];
      float t2 = out3[0][r][2]+out3[1][r][2]+out3[2][r][2]+out3[3][r][2];
      float v0 = fmaxf(t0/S[r], 0.f);
      float v1 = fmaxf(t1/S[r], 0.f);
      float v2 = fmaxf(t2/S[r], 0.f);
      if(FINAL){
        float mm = fmaxf(v0, fmaxf(v1,v2));
        float e0=__expf(v0-mm), e1=__expf(v1-mm), e2=__expf(v2-mm);
        float ss = e0+e1+e2;
        out[(size_t)(r0+r)*3+0]=e0/ss; out[(size_t)(r0+r)*3+1]=e1/ss; out[(size_t)(r0+r)*3+2]=e2/ss;
      } else {
        out[(size_t)(r0+r)*3+0]=v0; out[(size_t)(r0+r)*3+1]=v1; out[(size_t)(r0+r)*3+2]=v2;
      }
    }
  }
}

// ---------- superpixel sums of fused (computed inline) via CSR gather ----------
__global__ __launch_bounds__(128) void k_spsum0(const int* __restrict__ seg1, const int* __restrict__ seg2,
                                                const float* __restrict__ S0, const float* __restrict__ S1, const float* __restrict__ S2,
                                                const float* __restrict__ cst,
                                                const int* __restrict__ offs, const int* __restrict__ cnt,
                                                const int* __restrict__ list, float* __restrict__ spsum){
  __shared__ float r[2][3];
  int s = blockIdx.x;
  int t = threadIdx.x, w = t>>6, lane = t&63;
  int n = cnt[s], st = offs[s];
  float w0=cst[0], w1=cst[1], w2=cst[2];
  float s00=w0*S0[s*3+0], s01=w0*S0[s*3+1], s02=w0*S0[s*3+2];  // block-constant scale0 term
  float a0=0.f, a1=0.f, a2=0.f;
  for(int q=t; q<n; q+=128){
    int p = list[st+q];
    int b = seg1[p], c = seg2[p];
    a0 += s00 + w1*S1[b*3+0] + w2*S2[c*3+0];
    a1 += s01 + w1*S1[b*3+1] + w2*S2[c*3+1];
    a2 += s02 + w1*S1[b*3+2] + w2*S2[c*3+2];
  }
  a0 = waveReduceSum(a0); a1 = waveReduceSum(a1); a2 = waveReduceSum(a2);
  if(lane==0){ r[w][0]=a0; r[w][1]=a1; r[w][2]=a2; }
  __syncthreads();
  if(t==0){
    spsum[s*3+0]=r[0][0]+r[1][0];
    spsum[s*3+1]=r[0][1]+r[1][1];
    spsum[s*3+2]=r[0][2]+r[1][2];
  }
}

// ---------- PCR: smoothed_sp[r] = softmax(attn[r]) @ (spsum/cnt) ----------
__global__ __launch_bounds__(256) void k_pcr(const float* __restrict__ attn, const float* __restrict__ spsum,
                                             const int* __restrict__ cnt0, float* __restrict__ sm){
  __shared__ float buf[2048];
  __shared__ float red[4];
  __shared__ float r3[256][3];
  int r=blockIdx.x, t=threadIdx.x;
  float lmax=-INFINITY;
  for(int j=t;j<2000;j+=256){ float v=attn[(size_t)r*2000+j]; buf[j]=v; lmax=fmaxf(lmax,v); }
  float wm=waveReduceMax(lmax);
  if((t&63)==0) red[t>>6]=wm;
  __syncthreads();
  float m = fmaxf(fmaxf(red[0],red[1]),fmaxf(red[2],red[3]));
  __syncthreads();
  float lsum=0.f;
  for(int j=t;j<2000;j+=256){ float e=__expf(buf[j]-m); buf[j]=e; lsum+=e; }
  float wsu=waveReduceSum(lsum);
  if((t&63)==0) red[t>>6]=wsu;
  __syncthreads();
  float S=red[0]+red[1]+red[2]+red[3];
  float a0=0.f,a1=0.f,a2=0.f;
  for(int j=t;j<2000;j+=256){
    float e=buf[j];
    float inv = 1.f / fmaxf((float)cnt0[j], 1.f);
    a0=fmaf(e, spsum[j*3+0]*inv, a0);
    a1=fmaf(e, spsum[j*3+1]*inv, a1);
    a2=fmaf(e, spsum[j*3+2]*inv, a2);
  }
  r3[t][0]=a0; r3[t][1]=a1; r3[t][2]=a2;
  __syncthreads();
  for(int st=128;st>0;st>>=1){
    if(t<st){ r3[t][0]+=r3[t+st][0]; r3[t][1]+=r3[t+st][1]; r3[t][2]+=r3[t+st][2]; }
    __syncthreads();
  }
  if(t==0){ sm[r*3+0]=r3[0][0]/S; sm[r*3+1]=r3[0][1]/S; sm[r*3+2]=r3[0][2]/S; }
}

// ---------- S_flat (fused computed inline) + argmax class index ----------
__global__ void k_sflat(const int* __restrict__ s0g, const int* __restrict__ s1g, const int* __restrict__ s2g,
                        const float* __restrict__ S0, const float* __restrict__ S1, const float* __restrict__ S2,
                        const float* __restrict__ sm, const float* __restrict__ cst,
                        float* __restrict__ Sf, int* __restrict__ ci){
  int p = blockIdx.x*256 + threadIdx.x;
  if(p >= N_PIX) return;
  float a = cst[3];
  float w0=cst[0], w1=cst[1], w2=cst[2];
  int sa=s0g[p], sb=s1g[p], sc_=s2g[p];
  float f0 = w0*S0[sa*3+0] + w1*S1[sb*3+0] + w2*S2[sc_*3+0];
  float f1 = w0*S0[sa*3+1] + w1*S1[sb*3+1] + w2*S2[sc_*3+1];
  float f2 = w0*S0[sa*3+2] + w1*S1[sb*3+2] + w2*S2[sc_*3+2];
  float x0 = a*sm[sa*3+0] + (1.f-a)*f0;
  float x1 = a*sm[sa*3+1] + (1.f-a)*f1;
  float x2 = a*sm[sa*3+2] + (1.f-a)*f2;
  Sf[(size_t)p*3+0]=x0; Sf[(size_t)p*3+1]=x1; Sf[(size_t)p*3+2]=x2;
  int c=0; float b=x0;
  if(x1>b){c=1;b=x1;}
  if(x2>b){c=2;}
  ci[p]=c;
}

// ---------- weight pre-pack into MFMA B-fragment order, bf16 hi/lo ----------
__global__ void k_packw(const float* __restrict__ W, int Kreal, int Nreal, int nkt, int nnt,
                        u16* __restrict__ dhi, u16* __restrict__ dlo){
  int gid = blockIdx.x*256 + threadIdx.x;
  int total = nnt*nkt*512;
  if(gid >= total) return;
  int j = gid & 7, l = (gid>>3)&63;
  int rem = gid >> 9;               // nt*nkt + ks
  int ks = rem % nkt;
  int nt = rem / nkt;
  int k = ks*32 + (l>>4)*8 + j;
  int n = nt*16 + (l&15);
  float w = (k < Kreal && n < Nreal) ? W[(size_t)k*Nreal + n] : 0.f;
  u16 hi = f2bf(w);
  dhi[gid] = hi;
  dlo[gid] = f2bf(w - bf2f(hi));
}

// ---------- MFMA MLP (156->128->128->156), packed-cvt staging/epilogues ----------
#define MFMA(a,b,c) __builtin_amdgcn_mfma_f32_16x16x32_bf16((a),(b),(c),0,0,0)

__global__ __launch_bounds__(256, 4) void k_mlp_mfma(
    const float* __restrict__ Y, const int* __restrict__ ci,
    const u16* __restrict__ P1h, const u16* __restrict__ P1l,
    const u16* __restrict__ P2h, const u16* __restrict__ P2l,
    const u16* __restrict__ P3h, const u16* __restrict__ P3l,
    const float* __restrict__ b1, const float* __restrict__ b2, const float* __restrict__ b3,
    float* __restrict__ gsum, float* __restrict__ gwsum){
  __shared__ u16 SH[32*168];                 // X-hi [32][168]  ->  A-hi [32][136]
  __shared__ u16 SL[32*168];                 // X-lo            ->  A-lo
  __shared__ float csum[480], cwsum[480];    // per-class partial sums [3][160]
  __shared__ int cis[32];
  const int t = threadIdx.x;
  const int lane = t & 63, w = t >> 6;
  const int g = lane >> 4, r16 = lane & 15;
  const size_t p0 = (size_t)blockIdx.x * 32;

  for(int i=t;i<480;i+=256){ csum[i]=0.f; cwsum[i]=0.f; }
  if(t<32) cis[t] = ci[p0+t];
  // stage Y tile: 32 rows x 39 float4, packed bf16 hi/lo split (v_cvt_pk_bf16_f32)
  for(int i=t;i<1248;i+=256){
    int row = i/39, q = i - row*39, c0 = q*4;
    float4 v = *(const float4*)(Y + (p0+row)*NB + c0);
    unsigned h01 = pkbf(v.x, v.y), h23 = pkbf(v.z, v.w);
    float l0 = v.x - __uint_as_float(h01 << 16);
    float l1 = v.y - __uint_as_float(h01 & 0xFFFF0000u);
    float l2 = v.z - __uint_as_float(h23 << 16);
    float l3 = v.w - __uint_as_float(h23 & 0xFFFF0000u);
    *(unsigned*)&SH[row*168+c0]   = h01;
    *(unsigned*)&SH[row*168+c0+2] = h23;
    *(unsigned*)&SL[row*168+c0]   = pkbf(l0, l1);
    *(unsigned*)&SL[row*168+c0+2] = pkbf(l2, l3);
  }
  if(t<64){ int row=t>>1, o=156+(t&1)*2;
    *(unsigned*)&SH[row*168+o]=0u; *(unsigned*)&SL[row*168+o]=0u; }
  __syncthreads();

  // ---- layer 1: K=160 (5 ks), N=128; wave w -> ntiles {w, w+4} ----
  {
    f32x4 acc[2][2];
    #pragma unroll
    for(int u=0;u<2;u++)
      #pragma unroll
      for(int mt=0;mt<2;mt++) acc[u][mt] = (f32x4){0.f,0.f,0.f,0.f};
    #pragma unroll
    for(int ks=0;ks<5;ks++){
      bfrag8 bh0 = *(const bfrag8*)(P1h + ((size_t)(w*5+ks))*512 + lane*8);
      bfrag8 bl0 = *(const bfrag8*)(P1l + ((size_t)(w*5+ks))*512 + lane*8);
      bfrag8 bh1 = *(const bfrag8*)(P1h + ((size_t)((w+4)*5+ks))*512 + lane*8);
      bfrag8 bl1 = *(const bfrag8*)(P1l + ((size_t)((w+4)*5+ks))*512 + lane*8);
      #pragma unroll
      for(int mt=0;mt<2;mt++){
        bfrag8 ah = *(const bfrag8*)(SH + (mt*16+r16)*168 + g*8 + ks*32);
        bfrag8 al = *(const bfrag8*)(SL + (mt*16+r16)*168 + g*8 + ks*32);
        acc[0][mt]=MFMA(ah,bh0,acc[0][mt]); acc[0][mt]=MFMA(ah,bl0,acc[0][mt]); acc[0][mt]=MFMA(al,bh0,acc[0][mt]);
        acc[1][mt]=MFMA(ah,bh1,acc[1][mt]); acc[1][mt]=MFMA(ah,bl1,acc[1][mt]); acc[1][mt]=MFMA(al,bh1,acc[1][mt]);
      }
    }
    __syncthreads();   // all waves done reading X
    #pragma unroll
    for(int u=0;u<2;u++){
      int c = (w+u*4)*16 + r16;
      float bv = b1[c];
      #pragma unroll
      for(int mt=0;mt<2;mt++){
        float v0 = fmaxf(acc[u][mt][0] + bv, 0.f);
        float v1 = fmaxf(acc[u][mt][1] + bv, 0.f);
        float v2 = fmaxf(acc[u][mt][2] + bv, 0.f);
        float v3 = fmaxf(acc[u][mt][3] + bv, 0.f);
        unsigned h01 = pkbf(v0,v1), h23 = pkbf(v2,v3);
        float l0 = v0 - __uint_as_float(h01<<16);
        float l1 = v1 - __uint_as_float(h01 & 0xFFFF0000u);
        float l2 = v2 - __uint_as_float(h23<<16);
        float l3 = v3 - __uint_as_float(h23 & 0xFFFF0000u);
        unsigned q01 = pkbf(l0,l1), q23 = pkbf(l2,l3);
        int rb = (mt*16 + g*4)*136 + c;
        SH[rb      ] = (u16)h01; SH[rb+136 ] = (u16)(h01>>16);
        SH[rb+272  ] = (u16)h23; SH[rb+408 ] = (u16)(h23>>16);
        SL[rb      ] = (u16)q01; SL[rb+136 ] = (u16)(q01>>16);
        SL[rb+272  ] = (u16)q23; SL[rb+408 ] = (u16)(q23>>16);
      }
    }
  }
  __syncthreads();

  // ---- layer 2: K=128 (4 ks), N=128; regs across barrier, overwrite A ----
  {
    f32x4 acc[2][2];
    #pragma unroll
    for(int u=0;u<2;u++)
      #pragma unroll
      for(int mt=0;mt<2;mt++) acc[u][mt] = (f32x4){0.f,0.f,0.f,0.f};
    #pragma unroll
    for(int ks=0;ks<4;ks++){
      bfrag8 bh0 = *(const bfrag8*)(P2h + ((size_t)(w*4+ks))*512 + lane*8);
      bfrag8 bl0 = *(const bfrag8*)(P2l + ((size_t)(w*4+ks))*512 + lane*8);
      bfrag8 bh1 = *(const bfrag8*)(P2h + ((size_t)((w+4)*4+ks))*512 + lane*8);
      bfrag8 bl1 = *(const bfrag8*)(P2l + ((size_t)((w+4)*4+ks))*512 + lane*8);
      #pragma unroll
      for(int mt=0;mt<2;mt++){
        bfrag8 ah = *(const bfrag8*)(SH + (mt*16+r16)*136 + g*8 + ks*32);
        bfrag8 al = *(const bfrag8*)(SL + (mt*16+r16)*136 + g*8 + ks*32);
        acc[0][mt]=MFMA(ah,bh0,acc[0][mt]); acc[0][mt]=MFMA(ah,bl0,acc[0][mt]); acc[0][mt]=MFMA(al,bh0,acc[0][mt]);
        acc[1][mt]=MFMA(ah,bh1,acc[1][mt]); acc[1][mt]=MFMA(ah,bl1,acc[1][mt]); acc[1][mt]=MFMA(al,bh1,acc[1][mt]);
      }
    }
    __syncthreads();   // all waves done reading A(layer1)
    #pragma unroll
    for(int u=0;u<2;u++){
      int c = (w+u*4)*16 + r16;
      float bv = b2[c];
      #pragma unroll
      for(int mt=0;mt<2;mt++){
        float v0 = fmaxf(acc[u][mt][0] + bv, 0.f);
        float v1 = fmaxf(acc[u][mt][1] + bv, 0.f);
        float v2 = fmaxf(acc[u][mt][2] + bv, 0.f);
        float v3 = fmaxf(acc[u][mt][3] + bv, 0.f);
        unsigned h01 = pkbf(v0,v1), h23 = pkbf(v2,v3);
        float l0 = v0 - __uint_as_float(h01<<16);
        float l1 = v1 - __uint_as_float(h01 & 0xFFFF0000u);
        float l2 = v2 - __uint_as_float(h23<<16);
        float l3 = v3 - __uint_as_float(h23 & 0xFFFF0000u);
        unsigned q01 = pkbf(l0,l1), q23 = pkbf(l2,l3);
        int rb = (mt*16 + g*4)*136 + c;
        SH[rb      ] = (u16)h01; SH[rb+136 ] = (u16)(h01>>16);
        SH[rb+272  ] = (u16)h23; SH[rb+408 ] = (u16)(h23>>16);
        SL[rb      ] = (u16)q01; SL[rb+136 ] = (u16)(q01>>16);
        SL[rb+272  ] = (u16)q23; SL[rb+408 ] = (u16)(q23>>16);
      }
    }
  }
  __syncthreads();

  // ---- layer 3: K=128, 20 subtiles over 4 waves (5 chains/wave) + atomic-free epilogue ----
  {
    f32x4 acc[5];
    #pragma unroll
    for(int s=0;s<5;s++) acc[s] = (f32x4){0.f,0.f,0.f,0.f};
    #pragma unroll
    for(int s=0;s<5;s++){
      int idx = w*5 + s, nt = idx>>1, mt = idx&1;
      #pragma unroll
      for(int ks=0;ks<4;ks++){
        bfrag8 bh = *(const bfrag8*)(P3h + ((size_t)(nt*4+ks))*512 + lane*8);
        bfrag8 bl = *(const bfrag8*)(P3l + ((size_t)(nt*4+ks))*512 + lane*8);
        bfrag8 ah = *(const bfrag8*)(SH + (mt*16+r16)*136 + g*8 + ks*32);
        bfrag8 al = *(const bfrag8*)(SL + (mt*16+r16)*136 + g*8 + ks*32);
        acc[s]=MFMA(ah,bh,acc[s]); acc[s]=MFMA(ah,bl,acc[s]); acc[s]=MFMA(al,bh,acc[s]);
      }
    }
    const int ntbase = (w*5) >> 1;
    float cs00=0,cs01=0,cs02=0, cs10=0,cs11=0,cs12=0, cs20=0,cs21=0,cs22=0;
    float cw00=0,cw01=0,cw02=0, cw10=0,cw11=0,cw12=0, cw20=0,cw21=0,cw22=0;
    #pragma unroll
    for(int s=0;s<5;s++){
      int idx = w*5 + s, nt = idx>>1, mt = idx&1;
      int ntl = nt - ntbase;          // 0..2
      int c = nt*16 + r16;
      if(c < 156){
        float bv = b3[c];
        #pragma unroll
        for(int r=0;r<4;r++){
          int p = mt*16 + g*4 + r;
          float e = __expf(acc[s][r] + bv);
          float y = Y[(p0+p)*NB + c];
          float ey = e*y;
          int k = cis[p];
          float e0 = (k==0)?e:0.f, e1 = (k==1)?e:0.f, e2 = (k==2)?e:0.f;
          float y0 = (k==0)?ey:0.f, y1 = (k==1)?ey:0.f, y2 = (k==2)?ey:0.f;
          if(ntl==0){ cs00+=e0; cs01+=e1; cs02+=e2; cw00+=y0; cw01+=y1; cw02+=y2; }
          else if(ntl==1){ cs10+=e0; cs11+=e1; cs12+=e2; cw10+=y0; cw11+=y1; cw12+=y2; }
          else { cs20+=e0; cs21+=e1; cs22+=e2; cw20+=y0; cw21+=y1; cw22+=y2; }
        }
      }
    }
    #define GRED(v) { v += __shfl_xor(v,16,64); v += __shfl_xor(v,32,64); }
    GRED(cs00) GRED(cs01) GRED(cs02) GRED(cs10) GRED(cs11) GRED(cs12) GRED(cs20) GRED(cs21) GRED(cs22)
    GRED(cw00) GRED(cw01) GRED(cw02) GRED(cw10) GRED(cw11) GRED(cw12) GRED(cw20) GRED(cw21) GRED(cw22)
    #undef GRED
    if(g==0){
      #pragma unroll
      for(int ntl=0;ntl<3;ntl++){
        int nt = ntbase + ntl;
        int c = nt*16 + r16;
        if(c < 156){
          float s0 = (ntl==0)?cs00:((ntl==1)?cs10:cs20);
          float s1 = (ntl==0)?cs01:((ntl==1)?cs11:cs21);
          float s2 = (ntl==0)?cs02:((ntl==1)?cs12:cs22);
          float w0 = (ntl==0)?cw00:((ntl==1)?cw10:cw20);
          float w1 = (ntl==0)?cw01:((ntl==1)?cw11:cw21);
          float w2 = (ntl==0)?cw02:((ntl==1)?cw12:cw22);
          atomicAdd(&csum[0*160 + c], s0);
          atomicAdd(&csum[1*160 + c], s1);
          atomicAdd(&csum[2*160 + c], s2);
          atomicAdd(&cwsum[0*160 + c], w0);
          atomicAdd(&cwsum[1*160 + c], w1);
          atomicAdd(&cwsum[2*160 + c], w2);
        }
      }
    }
  }
  __syncthreads();
  float* gs = gsum  + (size_t)(blockIdx.x & 255)*480;
  float* gw = gwsum + (size_t)(blockIdx.x & 255)*480;
  for(int i=t;i<480;i+=256){
    atomicAdd(&gs[i], csum[i]);
    atomicAdd(&gw[i], cwsum[i]);
  }
}

// ---------- final M: reduce 256 slots ----------
__global__ void k_finalM(const float* __restrict__ gsump, const float* __restrict__ gwsump, float* __restrict__ M){
  int e = blockIdx.x*256 + threadIdx.x;
  if(e < 468){
    int cls = e/156, c = e - cls*156;
    int off = cls*160 + c;
    float s=0.f, wv=0.f;
    for(int k=0;k<256;k++){ s += gsump[(size_t)k*480 + off]; wv += gwsump[(size_t)k*480 + off]; }
    M[e] = (s > 0.f) ? (wv / fmaxf(s, 1e-30f)) : 0.f;
  }
}

// ---------- Y_hat = S_flat @ M, float4 stores ----------
__global__ void k_yhat4(const float* __restrict__ Sf, const float* __restrict__ M, float4* __restrict__ out){
  unsigned idx = blockIdx.x*256u + threadIdx.x;   // N_PIX*39 float4s, grid exact
  unsigned p = idx / 39u, q = idx - p*39u;
  unsigned c0 = q*4u;
  float4 m0 = *(const float4*)(M + c0);
  float4 m1 = *(const float4*)(M + 156 + c0);
  float4 m2 = *(const float4*)(M + 312 + c0);
  float s0 = Sf[(size_t)p*3+0], s1 = Sf[(size_t)p*3+1], s2 = Sf[(size_t)p*3+2];
  float4 r;
  r.x = s0*m0.x + s1*m1.x + s2*m2.x;
  r.y = s0*m0.y + s1*m1.y + s2*m2.y;
  r.z = s0*m0.z + s1*m1.z + s2*m2.z;
  r.w = s0*m0.w + s1*m1.w + s2*m2.w;
  out[idx] = r;
}

extern "C" void kernel_launch(void* const* d_in, const int* in_sizes, int n_in,
                              void* d_out, int out_size, void* d_ws, size_t ws_size,
                              hipStream_t stream){
  const float* Y    = (const float*)d_in[0];
  const int*   seg0 = (const int*)d_in[1];
  const int*   A0   = (const int*)d_in[2];
  const int*   seg1 = (const int*)d_in[3];
  const int*   A1   = (const int*)d_in[4];
  const int*   seg2 = (const int*)d_in[5];
  const int*   A2   = (const int*)d_in[6];
  const float* attn = (const float*)d_in[7];
  const float* alpha= (const float*)d_in[8];
  const float* sw   = (const float*)d_in[9];
  const float* W1a[3] = {(const float*)d_in[10], (const float*)d_in[14], (const float*)d_in[18]};
  const float* b1a[3] = {(const float*)d_in[11], (const float*)d_in[15], (const float*)d_in[19]};
  const float* W2a[3] = {(const float*)d_in[12], (const float*)d_in[16], (const float*)d_in[20]};
  const float* b2a[3] = {(const float*)d_in[13], (const float*)d_in[17], (const float*)d_in[21]};
  const float* Wm1=(const float*)d_in[22]; const float* bm1=(const float*)d_in[23];
  const float* Wm2=(const float*)d_in[24]; const float* bm2=(const float*)d_in[25];
  const float* Wm3=(const float*)d_in[26]; const float* bm3=(const float*)d_in[27];
  float* out = (float*)d_out;

  char* base = (char*)d_ws;
  size_t off = 0;
  auto alloc = [&](size_t bytes)->char*{
    char* r = base + off;
    off += (bytes + 255) & ~(size_t)255;
    return r;
  };
  int* cntAll = (int*)alloc((size_t)3500*4);
  int* cnt[3] = {cntAll, cntAll+2000, cntAll+3000};
  int* offs[3]; int* cur[3]; int* lst[3];
  for(int i=0;i<3;i++) offs[i] = (int*)alloc((size_t)(i==0?2000:(i==1?1000:500))*4);
  for(int i=0;i<3;i++) cur[i]  = (int*)alloc((size_t)(i==0?2000:(i==1?1000:500))*4);
  for(int i=0;i<3;i++) lst[i]  = (int*)alloc((size_t)N_PIX*4);
  float* X_all   = (float*)alloc((size_t)3500*NB*4);
  float* Hn_all  = (float*)alloc((size_t)3500*64*4);
  float* x1b_all = (float*)alloc((size_t)3500*64*4);
  float* Hn2_all = (float*)alloc((size_t)3500*3*4);
  float* Ss_all  = (float*)alloc((size_t)3500*3*4);
  float* cst   = (float*)alloc(64);
  float* spsum = (float*)alloc((size_t)2000*3*4);
  float* smth  = (float*)alloc((size_t)2000*3*4);
  float* Sf    = (float*)alloc((size_t)N_PIX*3*4);
  int*   ci    = (int*)alloc((size_t)N_PIX*4);
  u16* P1h = (u16*)alloc((size_t)20480*2); u16* P1l = (u16*)alloc((size_t)20480*2);
  u16* P2h = (u16*)alloc((size_t)16384*2); u16* P2l = (u16*)alloc((size_t)16384*2);
  u16* P3h = (u16*)alloc((size_t)20480*2); u16* P3l = (u16*)alloc((size_t)20480*2);
  float* gsump  = (float*)alloc((size_t)256*480*4);
  float* gwsump = (float*)alloc((size_t)256*480*4);
  float* Mbuf   = (float*)alloc((size_t)480*4);

  float* X0 = X_all;            float* X1 = X_all + (size_t)2000*NB;   float* X2 = X_all + (size_t)3000*NB;
  const float* Ss0 = Ss_all;    const float* Ss1 = Ss_all + 2000*3;    const float* Ss2 = Ss_all + 3000*3;

  // per-call re-init (replay/poison safe)
  hipMemsetAsync(cntAll, 0, (size_t)3500*4, stream);
  hipMemsetAsync(gsump, 0, (size_t)256*480*4, stream);
  hipMemsetAsync(gwsump, 0, (size_t)256*480*4, stream);
  k_prep<<<1,64,0,stream>>>(sw, alpha, cst);

  // weight pre-pack
  k_packw<<<(8*5*512+255)/256,256,0,stream>>>(Wm1, 156, 128, 5, 8, P1h, P1l);
  k_packw<<<(8*4*512+255)/256,256,0,stream>>>(Wm2, 128, 128, 4, 8, P2h, P2l);
  k_packw<<<(10*4*512+255)/256,256,0,stream>>>(Wm3, 128, 156, 4, 10, P3h, P3l);

  // CSR + segment means
  k_count<<<N_PIX/256,256,0,stream>>>(seg0,seg1,seg2,cnt[0],cnt[1],cnt[2]);
  k_scan<<<3,256,0,stream>>>(cnt[0],cnt[1],cnt[2],offs[0],offs[1],offs[2],cur[0],cur[1],cur[2]);
  k_fill<<<N_PIX/256,256,0,stream>>>(seg0,seg1,seg2,cur[0],cur[1],cur[2],lst[0],lst[1],lst[2]);
  k_segmean3<<<3500,192,0,stream>>>(Y,
      offs[0],cnt[0],lst[0],X0,
      offs[1],cnt[1],lst[1],X1,
      offs[2],cnt[2],lst[2],X2);

  // Multi-scale GAT encoder (batched: 4 launches total)
  k_linearB<<<(3500*64+255)/256,256,0,stream>>>(X_all, NB, 64,
      W1a[0],b1a[0],W1a[1],b1a[1],W1a[2],b1a[2], Hn_all);
  k_attn4B<64,false><<<875,256,0,stream>>>(Hn_all, A0,A1,A2, x1b_all);
  k_linearB<<<(3500*3+255)/256,256,0,stream>>>(x1b_all, 64, 3,
      W2a[0],b2a[0],W2a[1],b2a[1],W2a[2],b2a[2], Hn2_all);
  k_attn4B<3,true><<<875,256,0,stream>>>(Hn2_all, A0,A1,A2, Ss_all);

  // spsum (fused inline) + PCR + sflat (fused inline)
  k_spsum0<<<2000,128,0,stream>>>(seg1, seg2, Ss0, Ss1, Ss2, cst, offs[0], cnt[0], lst[0], spsum);
  k_pcr<<<2000,256,0,stream>>>(attn, spsum, cnt[0], smth);
  k_sflat<<<N_PIX/256,256,0,stream>>>(seg0, seg1, seg2, Ss0, Ss1, Ss2, smth, cst, Sf, ci);

  // ACDE: MFMA MLP + atomic-free epilogue, 256-slot atomic flush
  k_mlp_mfma<<<N_PIX/32,256,0,stream>>>(Y, ci, P1h,P1l,P2h,P2l,P3h,P3l, bm1,bm2,bm3, gsump, gwsump);
  k_finalM<<<2,256,0,stream>>>(gsump, gwsump, Mbuf);
  k_yhat4<<<(N_PIX/256)*39,256,0,stream>>>(Sf, Mbuf, (float4*)out);
  (void)in_sizes; (void)n_in; (void)out_size;
}

// Round 13
// 840.987 us; speedup vs baseline: 1.7597x; 1.0354x over previous
//
#include <hip/hip_runtime.h>
#include <hip/hip_bf16.h>
#include <math.h>

#define N_PIX (512*512)
#define NB 156
#define GH 64

typedef unsigned short u16;
typedef __attribute__((ext_vector_type(8))) short bfrag8;   // 8 bf16 = 4 VGPRs
typedef __attribute__((ext_vector_type(4))) float f32x4;    // MFMA accumulator

// ---------- bf16 helpers ----------
__device__ __forceinline__ u16 f2bf(float x){
  unsigned u = __float_as_uint(x);
  unsigned r = (u + 0x7FFFu + ((u >> 16) & 1u)) >> 16;
  return (u16)r;
}
__device__ __forceinline__ float bf2f(u16 h){
  return __uint_as_float(((unsigned)h) << 16);
}
// packed RNE: low 16 = bf16(a), high 16 = bf16(b)  (v_cvt_pk_bf16_f32)
__device__ __forceinline__ unsigned pkbf(float a, float b){
  __hip_bfloat162 h = __float22bfloat162_rn(make_float2(a,b));
  unsigned u; __builtin_memcpy(&u,&h,4); return u;
}

__device__ __forceinline__ float waveReduceMax(float v){
  #pragma unroll
  for(int o=32;o>0;o>>=1) v = fmaxf(v, __shfl_down(v, o, 64));
  return v;
}
__device__ __forceinline__ float waveReduceSum(float v){
  #pragma unroll
  for(int o=32;o>0;o>>=1) v += __shfl_down(v, o, 64);
  return v;
}

// ---------- derived constants: softmax(scale_weights), clip(alpha) ----------
__global__ void k_prep(const float* __restrict__ sw, const float* __restrict__ alpha, float* __restrict__ cst){
  if(threadIdx.x==0 && blockIdx.x==0){
    float m = fmaxf(sw[0], fmaxf(sw[1], sw[2]));
    float e0=expf(sw[0]-m), e1=expf(sw[1]-m), e2=expf(sw[2]-m);
    float s = e0+e1+e2;
    cst[0]=e0/s; cst[1]=e1/s; cst[2]=e2/s;
    cst[3]=fminf(fmaxf(alpha[0],0.f),1.f);
  }
}

// ---------- CSR build ----------
__global__ void k_count(const int* __restrict__ s0, const int* __restrict__ s1, const int* __restrict__ s2,
                        int* c0, int* c1, int* c2){
  int p = blockIdx.x*256 + threadIdx.x;
  if(p < N_PIX){
    atomicAdd(&c0[s0[p]],1);
    atomicAdd(&c1[s1[p]],1);
    atomicAdd(&c2[s2[p]],1);
  }
}

__global__ __launch_bounds__(256) void k_scan(const int* __restrict__ c0, const int* __restrict__ c1, const int* __restrict__ c2,
                       int* o0, int* o1, int* o2, int* u0, int* u1, int* u2){
  const int* cnt; int* offs; int* cur; int n;
  if(blockIdx.x==0){ cnt=c0; offs=o0; cur=u0; n=2000; }
  else if(blockIdx.x==1){ cnt=c1; offs=o1; cur=u1; n=1000; }
  else { cnt=c2; offs=o2; cur=u2; n=500; }
  __shared__ int l[2048];
  __shared__ int cs[256];
  int t = threadIdx.x;
  for(int i=t;i<2048;i+=256) l[i] = (i<n) ? cnt[i] : 0;
  __syncthreads();
  int s = 0;
  #pragma unroll
  for(int j=0;j<8;j++) s += l[t*8+j];
  cs[t] = s;
  __syncthreads();
  for(int d=1; d<256; d<<=1){
    int v = (t>=d) ? cs[t-d] : 0;
    __syncthreads();
    cs[t] += v;
    __syncthreads();
  }
  int run = cs[t] - s;
  for(int j=0;j<8;j++){
    int idx = t*8+j;
    int o = run;
    run += l[idx];
    if(idx < n){ offs[idx] = o; cur[idx] = o; }
  }
}

__global__ void k_fill(const int* __restrict__ s0, const int* __restrict__ s1, const int* __restrict__ s2,
                       int* u0, int* u1, int* u2, int* L0, int* L1, int* L2){
  int p = blockIdx.x*256 + threadIdx.x;
  if(p < N_PIX){
    int a = atomicAdd(&u0[s0[p]],1); L0[a] = p;
    int b = atomicAdd(&u1[s1[p]],1); L1[b] = p;
    int c = atomicAdd(&u2[s2[p]],1); L2[c] = p;
  }
}

// ---------- fused segment mean over all 3 scales: 192 thr, 2 pixel-groups of 78 lanes ----------
__global__ __launch_bounds__(192) void k_segmean3(const float* __restrict__ Y,
    const int* __restrict__ o0, const int* __restrict__ c0, const int* __restrict__ l0, float* __restrict__ X0,
    const int* __restrict__ o1, const int* __restrict__ c1, const int* __restrict__ l1, float* __restrict__ X1,
    const int* __restrict__ o2, const int* __restrict__ c2, const int* __restrict__ l2, float* __restrict__ X2){
  int b = blockIdx.x;
  const int *offs, *cnt, *list; float* X; int s;
  if(b < 2000){ s=b;      offs=o0; cnt=c0; list=l0; X=X0; }
  else if(b < 3000){ s=b-2000; offs=o1; cnt=c1; list=l1; X=X1; }
  else { s=b-3000; offs=o2; cnt=c2; list=l2; X=X2; }
  __shared__ float part[156];
  int t = threadIdx.x;
  int grp = t / 96, tb = t - grp*96;
  int n = cnt[s], st = offs[s];
  float ax=0.f, ay=0.f;
  if(tb < 78){
    int q = grp;
    for(; q+6<n; q+=8){
      int p0 = list[st+q], p1 = list[st+q+2], p2 = list[st+q+4], p3 = list[st+q+6];
      float2 v0 = *(const float2*)(Y + (size_t)p0*NB + tb*2);
      float2 v1 = *(const float2*)(Y + (size_t)p1*NB + tb*2);
      float2 v2 = *(const float2*)(Y + (size_t)p2*NB + tb*2);
      float2 v3 = *(const float2*)(Y + (size_t)p3*NB + tb*2);
      ax += (v0.x + v1.x) + (v2.x + v3.x);
      ay += (v0.y + v1.y) + (v2.y + v3.y);
    }
    for(; q<n; q+=2){
      int p0 = list[st+q];
      float2 v0 = *(const float2*)(Y + (size_t)p0*NB + tb*2);
      ax += v0.x; ay += v0.y;
    }
  }
  if(grp==1 && tb<78){ part[tb*2]=ax; part[tb*2+1]=ay; }
  __syncthreads();
  if(grp==0 && tb<78){
    float inv = 1.f / fmaxf((float)n, 1.f);
    float2 r; r.x = (ax + part[tb*2])*inv; r.y = (ay + part[tb*2+1])*inv;
    *(float2*)(X + (size_t)s*NB + tb*2) = r;
  }
}

// ---------- batched small linear over all 3 scales (rows 0..3499) ----------
__global__ void k_linearB(const float* __restrict__ X, int K, int D,
                          const float* __restrict__ W0, const float* __restrict__ bb0,
                          const float* __restrict__ W1, const float* __restrict__ bb1,
                          const float* __restrict__ W2, const float* __restrict__ bb2,
                          float* __restrict__ out){
  int gid = blockIdx.x*256 + threadIdx.x;
  if(gid >= 3500*D) return;
  int r = gid / D, c = gid - r*D;
  const float* W; const float* bb;
  if(r < 2000){ W=W0; bb=bb0; }
  else if(r < 3000){ W=W1; bb=bb1; }
  else { W=W2; bb=bb2; }
  const float* xr = X + (size_t)r*K;
  float acc = bb[c];
  for(int k=0;k<K;k++) acc = fmaf(xr[k], W[(size_t)k*D + c], acc);
  out[gid] = acc;
}

// ---------- batched GAT masked attention, 4 rows per block, all 3 scales ----------
// D==GH score pass: quad-cooperative (4 lanes per key row, coalesced 64B/quad)
template<int D, bool FINAL>
__global__ __launch_bounds__(256) void k_attn4B(const float* __restrict__ HnAll,
                                                const int* __restrict__ A0, const int* __restrict__ A1, const int* __restrict__ A2,
                                                float* __restrict__ outAll){
  __shared__ float sc[4][2048];
  __shared__ float hr[4][GH];
  __shared__ float redm[4][4];
  __shared__ float outp[4][4][GH];   // part, r, c (D==64)
  __shared__ float out3[4][4][4];    // wave, r, c (D==3)
  const int t = threadIdx.x, w = t>>6, lane = t&63;
  int b = blockIdx.x;
  int n, r0; size_t base; const int* A;
  if(b < 500){ n=2000; base=0;    r0=b*4;        A=A0; }
  else if(b < 750){ n=1000; base=2000; r0=(b-500)*4; A=A1; }
  else { n=500;  base=3000; r0=(b-750)*4; A=A2; }
  const int OD = FINAL ? 3 : (D==GH ? GH : 3);
  const float* Hn = HnAll + base*D;
  float* out = outAll + base*OD;
  if(D==GH){
    hr[w][lane] = Hn[(size_t)(r0 + w)*GH + lane];
  } else {
    if(t < 12) hr[t/3][t%3] = Hn[(size_t)(r0 + t/3)*3 + (t%3)];
  }
  __syncthreads();
  float lm0=-INFINITY, lm1=-INFINITY, lm2=-INFINITY, lm3=-INFINITY;
  if(D==GH){
    const int p = t & 3;
    for(int j = t>>2; j < n; j += 64){
      const float* hj = Hn + (size_t)j*GH;
      float s0=0.f,s1=0.f,s2=0.f,s3=0.f;
      #pragma unroll
      for(int k4=0;k4<4;k4++){
        float4 h  = *(const float4*)(hj + k4*16 + p*4);
        float4 a0 = *(const float4*)&hr[0][k4*16 + p*4];
        float4 a1 = *(const float4*)&hr[1][k4*16 + p*4];
        float4 a2 = *(const float4*)&hr[2][k4*16 + p*4];
        float4 a3 = *(const float4*)&hr[3][k4*16 + p*4];
        s0 = fmaf(a0.x,h.x, fmaf(a0.y,h.y, fmaf(a0.z,h.z, fmaf(a0.w,h.w, s0))));
        s1 = fmaf(a1.x,h.x, fmaf(a1.y,h.y, fmaf(a1.z,h.z, fmaf(a1.w,h.w, s1))));
        s2 = fmaf(a2.x,h.x, fmaf(a2.y,h.y, fmaf(a2.z,h.z, fmaf(a2.w,h.w, s2))));
        s3 = fmaf(a3.x,h.x, fmaf(a3.y,h.y, fmaf(a3.z,h.z, fmaf(a3.w,h.w, s3))));
      }
      s0 += __shfl_xor(s0,1,64); s0 += __shfl_xor(s0,2,64);
      s1 += __shfl_xor(s1,1,64); s1 += __shfl_xor(s1,2,64);
      s2 += __shfl_xor(s2,1,64); s2 += __shfl_xor(s2,2,64);
      s3 += __shfl_xor(s3,1,64); s3 += __shfl_xor(s3,2,64);
      if(p==0){
        int m0 = A[(size_t)(r0+0)*n + j];
        int m1 = A[(size_t)(r0+1)*n + j];
        int m2 = A[(size_t)(r0+2)*n + j];
        int m3 = A[(size_t)(r0+3)*n + j];
        s0 = (m0>0) ? s0 : -1e9f;
        s1 = (m1>0) ? s1 : -1e9f;
        s2 = (m2>0) ? s2 : -1e9f;
        s3 = (m3>0) ? s3 : -1e9f;
        sc[0][j]=s0; sc[1][j]=s1; sc[2][j]=s2; sc[3][j]=s3;
        lm0=fmaxf(lm0,s0); lm1=fmaxf(lm1,s1); lm2=fmaxf(lm2,s2); lm3=fmaxf(lm3,s3);
      }
    }
  } else {
    for(int j=t; j<n; j+=256){
      float h0=Hn[(size_t)j*3+0], h1=Hn[(size_t)j*3+1], h2=Hn[(size_t)j*3+2];
      float s0 = hr[0][0]*h0 + hr[0][1]*h1 + hr[0][2]*h2;
      float s1 = hr[1][0]*h0 + hr[1][1]*h1 + hr[1][2]*h2;
      float s2 = hr[2][0]*h0 + hr[2][1]*h1 + hr[2][2]*h2;
      float s3 = hr[3][0]*h0 + hr[3][1]*h1 + hr[3][2]*h2;
      int m0 = A[(size_t)(r0+0)*n + j];
      int m1 = A[(size_t)(r0+1)*n + j];
      int m2 = A[(size_t)(r0+2)*n + j];
      int m3 = A[(size_t)(r0+3)*n + j];
      s0 = (m0>0) ? s0 : -1e9f;
      s1 = (m1>0) ? s1 : -1e9f;
      s2 = (m2>0) ? s2 : -1e9f;
      s3 = (m3>0) ? s3 : -1e9f;
      sc[0][j]=s0; sc[1][j]=s1; sc[2][j]=s2; sc[3][j]=s3;
      lm0=fmaxf(lm0,s0); lm1=fmaxf(lm1,s1); lm2=fmaxf(lm2,s2); lm3=fmaxf(lm3,s3);
    }
  }
  {
    float w0=waveReduceMax(lm0), w1=waveReduceMax(lm1), w2=waveReduceMax(lm2), w3=waveReduceMax(lm3);
    if(lane==0){ redm[0][w]=w0; redm[1][w]=w1; redm[2][w]=w2; redm[3][w]=w3; }
  }
  __syncthreads();
  float m[4];
  #pragma unroll
  for(int r=0;r<4;r++) m[r] = fmaxf(fmaxf(redm[r][0],redm[r][1]), fmaxf(redm[r][2],redm[r][3]));
  __syncthreads();
  float ls0=0.f, ls1=0.f, ls2=0.f, ls3=0.f;
  for(int j=t; j<n; j+=256){
    float e0=__expf(sc[0][j]-m[0]); sc[0][j]=e0; ls0+=e0;
    float e1=__expf(sc[1][j]-m[1]); sc[1][j]=e1; ls1+=e1;
    float e2=__expf(sc[2][j]-m[2]); sc[2][j]=e2; ls2+=e2;
    float e3=__expf(sc[3][j]-m[3]); sc[3][j]=e3; ls3+=e3;
  }
  {
    float w0=waveReduceSum(ls0), w1=waveReduceSum(ls1), w2=waveReduceSum(ls2), w3=waveReduceSum(ls3);
    if(lane==0){ redm[0][w]=w0; redm[1][w]=w1; redm[2][w]=w2; redm[3][w]=w3; }
  }
  __syncthreads();
  float S[4];
  #pragma unroll
  for(int r=0;r<4;r++) S[r] = redm[r][0]+redm[r][1]+redm[r][2]+redm[r][3];
  if(D==GH){
    float acc0=0.f, acc1=0.f, acc2=0.f, acc3=0.f;
    const int c = lane, part = w;
    #pragma unroll 2
    for(int j=part; j<n; j+=4){
      float hv = Hn[(size_t)j*GH + c];
      acc0 = fmaf(sc[0][j], hv, acc0);
      acc1 = fmaf(sc[1][j], hv, acc1);
      acc2 = fmaf(sc[2][j], hv, acc2);
      acc3 = fmaf(sc[3][j], hv, acc3);
    }
    outp[part][0][c]=acc0; outp[part][1][c]=acc1; outp[part][2][c]=acc2; outp[part][3][c]=acc3;
    __syncthreads();
    int r = w;
    float tot = outp[0][r][lane]+outp[1][r][lane]+outp[2][r][lane]+outp[3][r][lane];
    out[(size_t)(r0+r)*GH + lane] = fmaxf(tot/S[r], 0.f);
  } else {
    float a00=0,a01=0,a02=0, a10=0,a11=0,a12=0, a20=0,a21=0,a22=0, a30=0,a31=0,a32=0;
    for(int j=t; j<n; j+=256){
      float h0=Hn[(size_t)j*3+0], h1=Hn[(size_t)j*3+1], h2=Hn[(size_t)j*3+2];
      float e0=sc[0][j], e1=sc[1][j], e2=sc[2][j], e3=sc[3][j];
      a00=fmaf(e0,h0,a00); a01=fmaf(e0,h1,a01); a02=fmaf(e0,h2,a02);
      a10=fmaf(e1,h0,a10); a11=fmaf(e1,h1,a11); a12=fmaf(e1,h2,a12);
      a20=fmaf(e2,h0,a20); a21=fmaf(e2,h1,a21); a22=fmaf(e2,h2,a22);
      a30=fmaf(e3,h0,a30); a31=fmaf(e3,h1,a31); a32=fmaf(e3,h2,a32);
    }
    float v[12] = {a00,a01,a02,a10,a11,a12,a20,a21,a22,a30,a31,a32};
    #pragma unroll
    for(int i=0;i<12;i++){
      float ws = waveReduceSum(v[i]);
      if(lane==0) out3[w][i/3][i%3] = ws;
    }
    __syncthreads();
    if(t < 4){
      int r = t;
      float t0 = out3[0][r][0]+out3[1][r][0]+out3[2][r][0]+out3[3][r][0];
      float t1 = out3[0][r][1]+out3[1][r][1]+out3[2][r][1]+out3[3][r][1];
      float t2 = out3[0][r][2]+out3[1][r][2]+out3[2][r][2]+out3[3][r][2];
      float v0 = fmaxf(t0/S[r], 0.f);
      float v1 = fmaxf(t1/S[r], 0.f);
      float v2 = fmaxf(t2/S[r], 0.f);
      if(FINAL){
        float mm = fmaxf(v0, fmaxf(v1,v2));
        float e0=__expf(v0-mm), e1=__expf(v1-mm), e2=__expf(v2-mm);
        float ss = e0+e1+e2;
        out[(size_t)(r0+r)*3+0]=e0/ss; out[(size_t)(r0+r)*3+1]=e1/ss; out[(size_t)(r0+r)*3+2]=e2/ss;
      } else {
        out[(size_t)(r0+r)*3+0]=v0; out[(size_t)(r0+r)*3+1]=v1; out[(size_t)(r0+r)*3+2]=v2;
      }
    }
  }
}

// ---------- superpixel sums of fused (computed inline) via CSR gather ----------
__global__ __launch_bounds__(128) void k_spsum0(const int* __restrict__ seg1, const int* __restrict__ seg2,
                                                const float* __restrict__ S0, const float* __restrict__ S1, const float* __restrict__ S2,
                                                const float* __restrict__ cst,
                                                const int* __restrict__ offs, const int* __restrict__ cnt,
                                                const int* __restrict__ list, float* __restrict__ spsum){
  __shared__ float r[2][3];
  int s = blockIdx.x;
  int t = threadIdx.x, w = t>>6, lane = t&63;
  int n = cnt[s], st = offs[s];
  float w0=cst[0], w1=cst[1], w2=cst[2];
  float s00=w0*S0[s*3+0], s01=w0*S0[s*3+1], s02=w0*S0[s*3+2];
  float a0=0.f, a1=0.f, a2=0.f;
  for(int q=t; q<n; q+=128){
    int p = list[st+q];
    int b = seg1[p], c = seg2[p];
    a0 += s00 + w1*S1[b*3+0] + w2*S2[c*3+0];
    a1 += s01 + w1*S1[b*3+1] + w2*S2[c*3+1];
    a2 += s02 + w1*S1[b*3+2] + w2*S2[c*3+2];
  }
  a0 = waveReduceSum(a0); a1 = waveReduceSum(a1); a2 = waveReduceSum(a2);
  if(lane==0){ r[w][0]=a0; r[w][1]=a1; r[w][2]=a2; }
  __syncthreads();
  if(t==0){
    spsum[s*3+0]=r[0][0]+r[1][0];
    spsum[s*3+1]=r[0][1]+r[1][1];
    spsum[s*3+2]=r[0][2]+r[1][2];
  }
}

// ---------- PCR: smoothed_sp[r] = softmax(attn[r]) @ (spsum/cnt) ----------
__global__ __launch_bounds__(256) void k_pcr(const float* __restrict__ attn, const float* __restrict__ spsum,
                                             const int* __restrict__ cnt0, float* __restrict__ sm){
  __shared__ float buf[2048];
  __shared__ float red[4];
  __shared__ float r3[256][3];
  int r=blockIdx.x, t=threadIdx.x;
  float lmax=-INFINITY;
  for(int j=t;j<2000;j+=256){ float v=attn[(size_t)r*2000+j]; buf[j]=v; lmax=fmaxf(lmax,v); }
  float wm=waveReduceMax(lmax);
  if((t&63)==0) red[t>>6]=wm;
  __syncthreads();
  float m = fmaxf(fmaxf(red[0],red[1]),fmaxf(red[2],red[3]));
  __syncthreads();
  float lsum=0.f;
  for(int j=t;j<2000;j+=256){ float e=__expf(buf[j]-m); buf[j]=e; lsum+=e; }
  float wsu=waveReduceSum(lsum);
  if((t&63)==0) red[t>>6]=wsu;
  __syncthreads();
  float S=red[0]+red[1]+red[2]+red[3];
  float a0=0.f,a1=0.f,a2=0.f;
  for(int j=t;j<2000;j+=256){
    float e=buf[j];
    float inv = 1.f / fmaxf((float)cnt0[j], 1.f);
    a0=fmaf(e, spsum[j*3+0]*inv, a0);
    a1=fmaf(e, spsum[j*3+1]*inv, a1);
    a2=fmaf(e, spsum[j*3+2]*inv, a2);
  }
  r3[t][0]=a0; r3[t][1]=a1; r3[t][2]=a2;
  __syncthreads();
  for(int st=128;st>0;st>>=1){
    if(t<st){ r3[t][0]+=r3[t+st][0]; r3[t][1]+=r3[t+st][1]; r3[t][2]+=r3[t+st][2]; }
    __syncthreads();
  }
  if(t==0){ sm[r*3+0]=r3[0][0]/S; sm[r*3+1]=r3[0][1]/S; sm[r*3+2]=r3[0][2]/S; }
}

// ---------- S_flat (fused computed inline) + argmax class index ----------
__global__ void k_sflat(const int* __restrict__ s0g, const int* __restrict__ s1g, const int* __restrict__ s2g,
                        const float* __restrict__ S0, const float* __restrict__ S1, const float* __restrict__ S2,
                        const float* __restrict__ sm, const float* __restrict__ cst,
                        float* __restrict__ Sf, int* __restrict__ ci){
  int p = blockIdx.x*256 + threadIdx.x;
  if(p >= N_PIX) return;
  float a = cst[3];
  float w0=cst[0], w1=cst[1], w2=cst[2];
  int sa=s0g[p], sb=s1g[p], sc_=s2g[p];
  float f0 = w0*S0[sa*3+0] + w1*S1[sb*3+0] + w2*S2[sc_*3+0];
  float f1 = w0*S0[sa*3+1] + w1*S1[sb*3+1] + w2*S2[sc_*3+1];
  float f2 = w0*S0[sa*3+2] + w1*S1[sb*3+2] + w2*S2[sc_*3+2];
  float x0 = a*sm[sa*3+0] + (1.f-a)*f0;
  float x1 = a*sm[sa*3+1] + (1.f-a)*f1;
  float x2 = a*sm[sa*3+2] + (1.f-a)*f2;
  Sf[(size_t)p*3+0]=x0; Sf[(size_t)p*3+1]=x1; Sf[(size_t)p*3+2]=x2;
  int c=0; float b=x0;
  if(x1>b){c=1;b=x1;}
  if(x2>b){c=2;}
  ci[p]=c;
}

// ---------- weight pre-pack into MFMA B-fragment order, bf16 hi/lo ----------
__global__ void k_packw(const float* __restrict__ W, int Kreal, int Nreal, int nkt, int nnt,
                        u16* __restrict__ dhi, u16* __restrict__ dlo){
  int gid = blockIdx.x*256 + threadIdx.x;
  int total = nnt*nkt*512;
  if(gid >= total) return;
  int j = gid & 7, l = (gid>>3)&63;
  int rem = gid >> 9;               // nt*nkt + ks
  int ks = rem % nkt;
  int nt = rem / nkt;
  int k = ks*32 + (l>>4)*8 + j;
  int n = nt*16 + (l&15);
  float w = (k < Kreal && n < Nreal) ? W[(size_t)k*Nreal + n] : 0.f;
  u16 hi = f2bf(w);
  dhi[gid] = hi;
  dlo[gid] = f2bf(w - bf2f(hi));
}

// ---------- MFMA MLP (156->128->128->156): 64 px/block, 512 threads (8 waves) ----------
// Wave w owns ONE output ntile per layer -> unique epilogue writers, plain LDS stores.
#define MFMA(a,b,c) __builtin_amdgcn_mfma_f32_16x16x32_bf16((a),(b),(c),0,0,0)

__global__ __launch_bounds__(512, 4) void k_mlp_mfma(
    const float* __restrict__ Y, const int* __restrict__ ci,
    const u16* __restrict__ P1h, const u16* __restrict__ P1l,
    const u16* __restrict__ P2h, const u16* __restrict__ P2l,
    const u16* __restrict__ P3h, const u16* __restrict__ P3l,
    const float* __restrict__ b1, const float* __restrict__ b2, const float* __restrict__ b3,
    float* __restrict__ gsum, float* __restrict__ gwsum){
  __shared__ u16 SH[64*168];                 // X-hi [64][168]  ->  A-hi [64][136]
  __shared__ u16 SL[64*168];                 // X-lo            ->  A-lo
  __shared__ float csum[480], cwsum[480];    // per-class sums [3][160]; unique writers
  __shared__ int cis[64];
  const int t = threadIdx.x;
  const int lane = t & 63, w = t >> 6;       // 8 waves
  const int g = lane >> 4, r16 = lane & 15;
  const size_t p0 = (size_t)blockIdx.x * 64;

  if(t<64) cis[t] = ci[p0+t];
  // stage Y tile: 64 rows x 39 float4, packed bf16 hi/lo split
  for(int i=t;i<2496;i+=512){
    int row = i/39, q = i - row*39, c0 = q*4;
    float4 v = *(const float4*)(Y + (p0+row)*NB + c0);
    unsigned h01 = pkbf(v.x, v.y), h23 = pkbf(v.z, v.w);
    float l0 = v.x - __uint_as_float(h01 << 16);
    float l1 = v.y - __uint_as_float(h01 & 0xFFFF0000u);
    float l2 = v.z - __uint_as_float(h23 << 16);
    float l3 = v.w - __uint_as_float(h23 & 0xFFFF0000u);
    *(unsigned*)&SH[row*168+c0]   = h01;
    *(unsigned*)&SH[row*168+c0+2] = h23;
    *(unsigned*)&SL[row*168+c0]   = pkbf(l0, l1);
    *(unsigned*)&SL[row*168+c0+2] = pkbf(l2, l3);
  }
  if(t<128){ int row=t>>1, o=156+(t&1)*2;
    *(unsigned*)&SH[row*168+o]=0u; *(unsigned*)&SL[row*168+o]=0u; }
  __syncthreads();

  const int c12 = w*16 + r16;                // this wave's output column, layers 1/2

  // ---- layer 1: K=160 (5 ks), wave w -> ntile w, 4 m-tiles ----
  {
    f32x4 acc[4];
    #pragma unroll
    for(int mt=0;mt<4;mt++) acc[mt] = (f32x4){0.f,0.f,0.f,0.f};
    #pragma unroll
    for(int ks=0;ks<5;ks++){
      bfrag8 bh = *(const bfrag8*)(P1h + ((size_t)(w*5+ks))*512 + lane*8);
      bfrag8 bl = *(const bfrag8*)(P1l + ((size_t)(w*5+ks))*512 + lane*8);
      #pragma unroll
      for(int mt=0;mt<4;mt++){
        bfrag8 ah = *(const bfrag8*)(SH + (mt*16+r16)*168 + g*8 + ks*32);
        bfrag8 al = *(const bfrag8*)(SL + (mt*16+r16)*168 + g*8 + ks*32);
        acc[mt]=MFMA(ah,bh,acc[mt]); acc[mt]=MFMA(ah,bl,acc[mt]); acc[mt]=MFMA(al,bh,acc[mt]);
      }
    }
    __syncthreads();   // all waves done reading X
    float bv = b1[c12];
    #pragma unroll
    for(int mt=0;mt<4;mt++){
      float v0 = fmaxf(acc[mt][0] + bv, 0.f);
      float v1 = fmaxf(acc[mt][1] + bv, 0.f);
      float v2 = fmaxf(acc[mt][2] + bv, 0.f);
      float v3 = fmaxf(acc[mt][3] + bv, 0.f);
      unsigned h01 = pkbf(v0,v1), h23 = pkbf(v2,v3);
      float l0 = v0 - __uint_as_float(h01<<16);
      float l1 = v1 - __uint_as_float(h01 & 0xFFFF0000u);
      float l2 = v2 - __uint_as_float(h23<<16);
      float l3 = v3 - __uint_as_float(h23 & 0xFFFF0000u);
      unsigned q01 = pkbf(l0,l1), q23 = pkbf(l2,l3);
      int rb = (mt*16 + g*4)*136 + c12;
      SH[rb      ] = (u16)h01; SH[rb+136 ] = (u16)(h01>>16);
      SH[rb+272  ] = (u16)h23; SH[rb+408 ] = (u16)(h23>>16);
      SL[rb      ] = (u16)q01; SL[rb+136 ] = (u16)(q01>>16);
      SL[rb+272  ] = (u16)q23; SL[rb+408 ] = (u16)(q23>>16);
    }
  }
  __syncthreads();

  // ---- layer 2: K=128 (4 ks); regs across barrier, overwrite A ----
  {
    f32x4 acc[4];
    #pragma unroll
    for(int mt=0;mt<4;mt++) acc[mt] = (f32x4){0.f,0.f,0.f,0.f};
    #pragma unroll
    for(int ks=0;ks<4;ks++){
      bfrag8 bh = *(const bfrag8*)(P2h + ((size_t)(w*4+ks))*512 + lane*8);
      bfrag8 bl = *(const bfrag8*)(P2l + ((size_t)(w*4+ks))*512 + lane*8);
      #pragma unroll
      for(int mt=0;mt<4;mt++){
        bfrag8 ah = *(const bfrag8*)(SH + (mt*16+r16)*136 + g*8 + ks*32);
        bfrag8 al = *(const bfrag8*)(SL + (mt*16+r16)*136 + g*8 + ks*32);
        acc[mt]=MFMA(ah,bh,acc[mt]); acc[mt]=MFMA(ah,bl,acc[mt]); acc[mt]=MFMA(al,bh,acc[mt]);
      }
    }
    __syncthreads();   // all waves done reading A(layer1)
    float bv = b2[c12];
    #pragma unroll
    for(int mt=0;mt<4;mt++){
      float v0 = fmaxf(acc[mt][0] + bv, 0.f);
      float v1 = fmaxf(acc[mt][1] + bv, 0.f);
      float v2 = fmaxf(acc[mt][2] + bv, 0.f);
      float v3 = fmaxf(acc[mt][3] + bv, 0.f);
      unsigned h01 = pkbf(v0,v1), h23 = pkbf(v2,v3);
      float l0 = v0 - __uint_as_float(h01<<16);
      float l1 = v1 - __uint_as_float(h01 & 0xFFFF0000u);
      float l2 = v2 - __uint_as_float(h23<<16);
      float l3 = v3 - __uint_as_float(h23 & 0xFFFF0000u);
      unsigned q01 = pkbf(l0,l1), q23 = pkbf(l2,l3);
      int rb = (mt*16 + g*4)*136 + c12;
      SH[rb      ] = (u16)h01; SH[rb+136 ] = (u16)(h01>>16);
      SH[rb+272  ] = (u16)h23; SH[rb+408 ] = (u16)(h23>>16);
      SL[rb      ] = (u16)q01; SL[rb+136 ] = (u16)(q01>>16);
      SL[rb+272  ] = (u16)q23; SL[rb+408 ] = (u16)(q23>>16);
    }
  }
  __syncthreads();

  // ---- layer 3: K=128; wave w -> ntile w; waves 0,1 also ntile 8+w ----
  {
    f32x4 acc[4], acc2[4];
    #pragma unroll
    for(int mt=0;mt<4;mt++){ acc[mt] = (f32x4){0.f,0.f,0.f,0.f}; acc2[mt] = (f32x4){0.f,0.f,0.f,0.f}; }
    #pragma unroll
    for(int ks=0;ks<4;ks++){
      bfrag8 bh = *(const bfrag8*)(P3h + ((size_t)(w*4+ks))*512 + lane*8);
      bfrag8 bl = *(const bfrag8*)(P3l + ((size_t)(w*4+ks))*512 + lane*8);
      #pragma unroll
      for(int mt=0;mt<4;mt++){
        bfrag8 ah = *(const bfrag8*)(SH + (mt*16+r16)*136 + g*8 + ks*32);
        bfrag8 al = *(const bfrag8*)(SL + (mt*16+r16)*136 + g*8 + ks*32);
        acc[mt]=MFMA(ah,bh,acc[mt]); acc[mt]=MFMA(ah,bl,acc[mt]); acc[mt]=MFMA(al,bh,acc[mt]);
      }
    }
    if(w < 2){
      #pragma unroll
      for(int ks=0;ks<4;ks++){
        bfrag8 bh = *(const bfrag8*)(P3h + ((size_t)((8+w)*4+ks))*512 + lane*8);
        bfrag8 bl = *(const bfrag8*)(P3l + ((size_t)((8+w)*4+ks))*512 + lane*8);
        #pragma unroll
        for(int mt=0;mt<4;mt++){
          bfrag8 ah = *(const bfrag8*)(SH + (mt*16+r16)*136 + g*8 + ks*32);
          bfrag8 al = *(const bfrag8*)(SL + (mt*16+r16)*136 + g*8 + ks*32);
          acc2[mt]=MFMA(ah,bh,acc2[mt]); acc2[mt]=MFMA(ah,bl,acc2[mt]); acc2[mt]=MFMA(al,bh,acc2[mt]);
        }
      }
    }

    // ---- epilogue: per-lane class partials, g-group shuffle reduce, unique-writer stores ----
    const int c = w*16 + r16;        // primary column, < 128
    float bv = b3[c];
    float cs0=0,cs1=0,cs2=0, cw0=0,cw1=0,cw2=0;
    #pragma unroll
    for(int mt=0;mt<4;mt++){
      #pragma unroll
      for(int r=0;r<4;r++){
        int p = mt*16 + g*4 + r;
        float e = __expf(acc[mt][r] + bv);
        float y = Y[(p0+p)*NB + c];
        float ey = e*y;
        int k = cis[p];
        cs0 += (k==0)?e:0.f;  cs1 += (k==1)?e:0.f;  cs2 += (k==2)?e:0.f;
        cw0 += (k==0)?ey:0.f; cw1 += (k==1)?ey:0.f; cw2 += (k==2)?ey:0.f;
      }
    }
    #define GRED(v) { v += __shfl_xor(v,16,64); v += __shfl_xor(v,32,64); }
    GRED(cs0) GRED(cs1) GRED(cs2) GRED(cw0) GRED(cw1) GRED(cw2)
    float ds0=0,ds1=0,ds2=0, dw0=0,dw1=0,dw2=0;
    const int c2 = 128 + w*16 + r16;
    if(w < 2){
      if(c2 < 156){
        float bv2 = b3[c2];
        #pragma unroll
        for(int mt=0;mt<4;mt++){
          #pragma unroll
          for(int r=0;r<4;r++){
            int p = mt*16 + g*4 + r;
            float e = __expf(acc2[mt][r] + bv2);
            float y = Y[(p0+p)*NB + c2];
            float ey = e*y;
            int k = cis[p];
            ds0 += (k==0)?e:0.f;  ds1 += (k==1)?e:0.f;  ds2 += (k==2)?e:0.f;
            dw0 += (k==0)?ey:0.f; dw1 += (k==1)?ey:0.f; dw2 += (k==2)?ey:0.f;
          }
        }
      }
      GRED(ds0) GRED(ds1) GRED(ds2) GRED(dw0) GRED(dw1) GRED(dw2)
    }
    #undef GRED
    if(g==0){
      csum[c]       = cs0; csum[160+c]  = cs1; csum[320+c]  = cs2;
      cwsum[c]      = cw0; cwsum[160+c] = cw1; cwsum[320+c] = cw2;
      if(w < 2 && c2 < 156){
        csum[c2]       = ds0; csum[160+c2]  = ds1; csum[320+c2]  = ds2;
        cwsum[c2]      = dw0; cwsum[160+c2] = dw1; cwsum[320+c2] = dw2;
      }
    }
  }
  __syncthreads();
  // flush to 256 rotation slots (skip unwritten cols 156..159 of each class)
  float* gs = gsum  + (size_t)(blockIdx.x & 255)*480;
  float* gw = gwsum + (size_t)(blockIdx.x & 255)*480;
  for(int i=t;i<480;i+=512){
    if((i % 160) < 156){
      atomicAdd(&gs[i], csum[i]);
      atomicAdd(&gw[i], cwsum[i]);
    }
  }
}

// ---------- final M: reduce 256 slots ----------
__global__ void k_finalM(const float* __restrict__ gsump, const float* __restrict__ gwsump, float* __restrict__ M){
  int e = blockIdx.x*256 + threadIdx.x;
  if(e < 468){
    int cls = e/156, c = e - cls*156;
    int off = cls*160 + c;
    float s=0.f, wv=0.f;
    for(int k=0;k<256;k++){ s += gsump[(size_t)k*480 + off]; wv += gwsump[(size_t)k*480 + off]; }
    M[e] = (s > 0.f) ? (wv / fmaxf(s, 1e-30f)) : 0.f;
  }
}

// ---------- Y_hat = S_flat @ M, float4 stores ----------
__global__ void k_yhat4(const float* __restrict__ Sf, const float* __restrict__ M, float4* __restrict__ out){
  unsigned idx = blockIdx.x*256u + threadIdx.x;   // N_PIX*39 float4s, grid exact
  unsigned p = idx / 39u, q = idx - p*39u;
  unsigned c0 = q*4u;
  float4 m0 = *(const float4*)(M + c0);
  float4 m1 = *(const float4*)(M + 156 + c0);
  float4 m2 = *(const float4*)(M + 312 + c0);
  float s0 = Sf[(size_t)p*3+0], s1 = Sf[(size_t)p*3+1], s2 = Sf[(size_t)p*3+2];
  float4 r;
  r.x = s0*m0.x + s1*m1.x + s2*m2.x;
  r.y = s0*m0.y + s1*m1.y + s2*m2.y;
  r.z = s0*m0.z + s1*m1.z + s2*m2.z;
  r.w = s0*m0.w + s1*m1.w + s2*m2.w;
  out[idx] = r;
}

extern "C" void kernel_launch(void* const* d_in, const int* in_sizes, int n_in,
                              void* d_out, int out_size, void* d_ws, size_t ws_size,
                              hipStream_t stream){
  const float* Y    = (const float*)d_in[0];
  const int*   seg0 = (const int*)d_in[1];
  const int*   A0   = (const int*)d_in[2];
  const int*   seg1 = (const int*)d_in[3];
  const int*   A1   = (const int*)d_in[4];
  const int*   seg2 = (const int*)d_in[5];
  const int*   A2   = (const int*)d_in[6];
  const float* attn = (const float*)d_in[7];
  const float* alpha= (const float*)d_in[8];
  const float* sw   = (const float*)d_in[9];
  const float* W1a[3] = {(const float*)d_in[10], (const float*)d_in[14], (const float*)d_in[18]};
  const float* b1a[3] = {(const float*)d_in[11], (const float*)d_in[15], (const float*)d_in[19]};
  const float* W2a[3] = {(const float*)d_in[12], (const float*)d_in[16], (const float*)d_in[20]};
  const float* b2a[3] = {(const float*)d_in[13], (const float*)d_in[17], (const float*)d_in[21]};
  const float* Wm1=(const float*)d_in[22]; const float* bm1=(const float*)d_in[23];
  const float* Wm2=(const float*)d_in[24]; const float* bm2=(const float*)d_in[25];
  const float* Wm3=(const float*)d_in[26]; const float* bm3=(const float*)d_in[27];
  float* out = (float*)d_out;

  char* base = (char*)d_ws;
  size_t off = 0;
  auto alloc = [&](size_t bytes)->char*{
    char* r = base + off;
    off += (bytes + 255) & ~(size_t)255;
    return r;
  };
  int* cntAll = (int*)alloc((size_t)3500*4);
  int* cnt[3] = {cntAll, cntAll+2000, cntAll+3000};
  int* offs[3]; int* cur[3]; int* lst[3];
  for(int i=0;i<3;i++) offs[i] = (int*)alloc((size_t)(i==0?2000:(i==1?1000:500))*4);
  for(int i=0;i<3;i++) cur[i]  = (int*)alloc((size_t)(i==0?2000:(i==1?1000:500))*4);
  for(int i=0;i<3;i++) lst[i]  = (int*)alloc((size_t)N_PIX*4);
  float* X_all   = (float*)alloc((size_t)3500*NB*4);
  float* Hn_all  = (float*)alloc((size_t)3500*64*4);
  float* x1b_all = (float*)alloc((size_t)3500*64*4);
  float* Hn2_all = (float*)alloc((size_t)3500*3*4);
  float* Ss_all  = (float*)alloc((size_t)3500*3*4);
  float* cst   = (float*)alloc(64);
  float* spsum = (float*)alloc((size_t)2000*3*4);
  float* smth  = (float*)alloc((size_t)2000*3*4);
  float* Sf    = (float*)alloc((size_t)N_PIX*3*4);
  int*   ci    = (int*)alloc((size_t)N_PIX*4);
  u16* P1h = (u16*)alloc((size_t)20480*2); u16* P1l = (u16*)alloc((size_t)20480*2);
  u16* P2h = (u16*)alloc((size_t)16384*2); u16* P2l = (u16*)alloc((size_t)16384*2);
  u16* P3h = (u16*)alloc((size_t)20480*2); u16* P3l = (u16*)alloc((size_t)20480*2);
  float* gsump  = (float*)alloc((size_t)256*480*4);
  float* gwsump = (float*)alloc((size_t)256*480*4);
  float* Mbuf   = (float*)alloc((size_t)480*4);

  float* X0 = X_all;            float* X1 = X_all + (size_t)2000*NB;   float* X2 = X_all + (size_t)3000*NB;
  const float* Ss0 = Ss_all;    const float* Ss1 = Ss_all + 2000*3;    const float* Ss2 = Ss_all + 3000*3;

  // per-call re-init (replay/poison safe)
  hipMemsetAsync(cntAll, 0, (size_t)3500*4, stream);
  hipMemsetAsync(gsump, 0, (size_t)256*480*4, stream);
  hipMemsetAsync(gwsump, 0, (size_t)256*480*4, stream);
  k_prep<<<1,64,0,stream>>>(sw, alpha, cst);

  // weight pre-pack
  k_packw<<<(8*5*512+255)/256,256,0,stream>>>(Wm1, 156, 128, 5, 8, P1h, P1l);
  k_packw<<<(8*4*512+255)/256,256,0,stream>>>(Wm2, 128, 128, 4, 8, P2h, P2l);
  k_packw<<<(10*4*512+255)/256,256,0,stream>>>(Wm3, 128, 156, 4, 10, P3h, P3l);

  // CSR + segment means
  k_count<<<N_PIX/256,256,0,stream>>>(seg0,seg1,seg2,cnt[0],cnt[1],cnt[2]);
  k_scan<<<3,256,0,stream>>>(cnt[0],cnt[1],cnt[2],offs[0],offs[1],offs[2],cur[0],cur[1],cur[2]);
  k_fill<<<N_PIX/256,256,0,stream>>>(seg0,seg1,seg2,cur[0],cur[1],cur[2],lst[0],lst[1],lst[2]);
  k_segmean3<<<3500,192,0,stream>>>(Y,
      offs[0],cnt[0],lst[0],X0,
      offs[1],cnt[1],lst[1],X1,
      offs[2],cnt[2],lst[2],X2);

  // Multi-scale GAT encoder (batched: 4 launches total)
  k_linearB<<<(3500*64+255)/256,256,0,stream>>>(X_all, NB, 64,
      W1a[0],b1a[0],W1a[1],b1a[1],W1a[2],b1a[2], Hn_all);
  k_attn4B<64,false><<<875,256,0,stream>>>(Hn_all, A0,A1,A2, x1b_all);
  k_linearB<<<(3500*3+255)/256,256,0,stream>>>(x1b_all, 64, 3,
      W2a[0],b2a[0],W2a[1],b2a[1],W2a[2],b2a[2], Hn2_all);
  k_attn4B<3,true><<<875,256,0,stream>>>(Hn2_all, A0,A1,A2, Ss_all);

  // spsum (fused inline) + PCR + sflat (fused inline)
  k_spsum0<<<2000,128,0,stream>>>(seg1, seg2, Ss0, Ss1, Ss2, cst, offs[0], cnt[0], lst[0], spsum);
  k_pcr<<<2000,256,0,stream>>>(attn, spsum, cnt[0], smth);
  k_sflat<<<N_PIX/256,256,0,stream>>>(seg0, seg1, seg2, Ss0, Ss1, Ss2, smth, cst, Sf, ci);

  // ACDE: MFMA MLP (64 px/block) + unique-writer epilogue, 256-slot atomic flush
  k_mlp_mfma<<<N_PIX/64,512,0,stream>>>(Y, ci, P1h,P1l,P2h,P2l,P3h,P3l, bm1,bm2,bm3, gsump, gwsump);
  k_finalM<<<2,256,0,stream>>>(gsump, gwsump, Mbuf);
  k_yhat4<<<(N_PIX/256)*39,256,0,stream>>>(Sf, Mbuf, (float4*)out);
  (void)in_sizes; (void)n_in; (void)out_size;
}

// Round 14
// 741.956 us; speedup vs baseline: 1.9946x; 1.1335x over previous
//
#include <hip/hip_runtime.h>
#include <hip/hip_bf16.h>
#include <math.h>

#define N_PIX (512*512)
#define NB 156
#define GH 64

typedef unsigned short u16;
typedef __attribute__((ext_vector_type(8))) short bfrag8;   // 8 bf16 = 4 VGPRs
typedef __attribute__((ext_vector_type(4))) float f32x4;    // MFMA accumulator

// ---------- bf16 helpers ----------
__device__ __forceinline__ u16 f2bf(float x){
  unsigned u = __float_as_uint(x);
  unsigned r = (u + 0x7FFFu + ((u >> 16) & 1u)) >> 16;
  return (u16)r;
}
__device__ __forceinline__ float bf2f(u16 h){
  return __uint_as_float(((unsigned)h) << 16);
}
// packed RNE: low 16 = bf16(a), high 16 = bf16(b)  (v_cvt_pk_bf16_f32)
__device__ __forceinline__ unsigned pkbf(float a, float b){
  __hip_bfloat162 h = __float22bfloat162_rn(make_float2(a,b));
  unsigned u; __builtin_memcpy(&u,&h,4); return u;
}

__device__ __forceinline__ float waveReduceMax(float v){
  #pragma unroll
  for(int o=32;o>0;o>>=1) v = fmaxf(v, __shfl_down(v, o, 64));
  return v;
}
__device__ __forceinline__ float waveReduceSum(float v){
  #pragma unroll
  for(int o=32;o>0;o>>=1) v += __shfl_down(v, o, 64);
  return v;
}

// ---------- derived constants: softmax(scale_weights), clip(alpha) ----------
__global__ void k_prep(const float* __restrict__ sw, const float* __restrict__ alpha, float* __restrict__ cst){
  if(threadIdx.x==0 && blockIdx.x==0){
    float m = fmaxf(sw[0], fmaxf(sw[1], sw[2]));
    float e0=expf(sw[0]-m), e1=expf(sw[1]-m), e2=expf(sw[2]-m);
    float s = e0+e1+e2;
    cst[0]=e0/s; cst[1]=e1/s; cst[2]=e2/s;
    cst[3]=fminf(fmaxf(alpha[0],0.f),1.f);
  }
}

// ---------- CSR build ----------
__global__ void k_count(const int* __restrict__ s0, const int* __restrict__ s1, const int* __restrict__ s2,
                        int* c0, int* c1, int* c2){
  int p = blockIdx.x*256 + threadIdx.x;
  if(p < N_PIX){
    atomicAdd(&c0[s0[p]],1);
    atomicAdd(&c1[s1[p]],1);
    atomicAdd(&c2[s2[p]],1);
  }
}

__global__ __launch_bounds__(256) void k_scan(const int* __restrict__ c0, const int* __restrict__ c1, const int* __restrict__ c2,
                       int* o0, int* o1, int* o2, int* u0, int* u1, int* u2){
  const int* cnt; int* offs; int* cur; int n;
  if(blockIdx.x==0){ cnt=c0; offs=o0; cur=u0; n=2000; }
  else if(blockIdx.x==1){ cnt=c1; offs=o1; cur=u1; n=1000; }
  else { cnt=c2; offs=o2; cur=u2; n=500; }
  __shared__ int l[2048];
  __shared__ int cs[256];
  int t = threadIdx.x;
  for(int i=t;i<2048;i+=256) l[i] = (i<n) ? cnt[i] : 0;
  __syncthreads();
  int s = 0;
  #pragma unroll
  for(int j=0;j<8;j++) s += l[t*8+j];
  cs[t] = s;
  __syncthreads();
  for(int d=1; d<256; d<<=1){
    int v = (t>=d) ? cs[t-d] : 0;
    __syncthreads();
    cs[t] += v;
    __syncthreads();
  }
  int run = cs[t] - s;
  for(int j=0;j<8;j++){
    int idx = t*8+j;
    int o = run;
    run += l[idx];
    if(idx < n){ offs[idx] = o; cur[idx] = o; }
  }
}

__global__ void k_fill(const int* __restrict__ s0, const int* __restrict__ s1, const int* __restrict__ s2,
                       int* u0, int* u1, int* u2, int* L0, int* L1, int* L2){
  int p = blockIdx.x*256 + threadIdx.x;
  if(p < N_PIX){
    int a = atomicAdd(&u0[s0[p]],1); L0[a] = p;
    int b = atomicAdd(&u1[s1[p]],1); L1[b] = p;
    int c = atomicAdd(&u2[s2[p]],1); L2[c] = p;
  }
}

// ---------- fused segment mean over all 3 scales: 192 thr, 2 pixel-groups of 78 lanes ----------
__global__ __launch_bounds__(192) void k_segmean3(const float* __restrict__ Y,
    const int* __restrict__ o0, const int* __restrict__ c0, const int* __restrict__ l0, float* __restrict__ X0,
    const int* __restrict__ o1, const int* __restrict__ c1, const int* __restrict__ l1, float* __restrict__ X1,
    const int* __restrict__ o2, const int* __restrict__ c2, const int* __restrict__ l2, float* __restrict__ X2){
  int b = blockIdx.x;
  const int *offs, *cnt, *list; float* X; int s;
  if(b < 2000){ s=b;      offs=o0; cnt=c0; list=l0; X=X0; }
  else if(b < 3000){ s=b-2000; offs=o1; cnt=c1; list=l1; X=X1; }
  else { s=b-3000; offs=o2; cnt=c2; list=l2; X=X2; }
  __shared__ float part[156];
  int t = threadIdx.x;
  int grp = t / 96, tb = t - grp*96;
  int n = cnt[s], st = offs[s];
  float ax=0.f, ay=0.f;
  if(tb < 78){
    int q = grp;
    for(; q+6<n; q+=8){
      int p0 = list[st+q], p1 = list[st+q+2], p2 = list[st+q+4], p3 = list[st+q+6];
      float2 v0 = *(const float2*)(Y + (size_t)p0*NB + tb*2);
      float2 v1 = *(const float2*)(Y + (size_t)p1*NB + tb*2);
      float2 v2 = *(const float2*)(Y + (size_t)p2*NB + tb*2);
      float2 v3 = *(const float2*)(Y + (size_t)p3*NB + tb*2);
      ax += (v0.x + v1.x) + (v2.x + v3.x);
      ay += (v0.y + v1.y) + (v2.y + v3.y);
    }
    for(; q<n; q+=2){
      int p0 = list[st+q];
      float2 v0 = *(const float2*)(Y + (size_t)p0*NB + tb*2);
      ax += v0.x; ay += v0.y;
    }
  }
  if(grp==1 && tb<78){ part[tb*2]=ax; part[tb*2+1]=ay; }
  __syncthreads();
  if(grp==0 && tb<78){
    float inv = 1.f / fmaxf((float)n, 1.f);
    float2 r; r.x = (ax + part[tb*2])*inv; r.y = (ay + part[tb*2+1])*inv;
    *(float2*)(X + (size_t)s*NB + tb*2) = r;
  }
}

// ---------- batched small linear over all 3 scales (rows 0..3499) ----------
__global__ void k_linearB(const float* __restrict__ X, int K, int D,
                          const float* __restrict__ W0, const float* __restrict__ bb0,
                          const float* __restrict__ W1, const float* __restrict__ bb1,
                          const float* __restrict__ W2, const float* __restrict__ bb2,
                          float* __restrict__ out){
  int gid = blockIdx.x*256 + threadIdx.x;
  if(gid >= 3500*D) return;
  int r = gid / D, c = gid - r*D;
  const float* W; const float* bb;
  if(r < 2000){ W=W0; bb=bb0; }
  else if(r < 3000){ W=W1; bb=bb1; }
  else { W=W2; bb=bb2; }
  const float* xr = X + (size_t)r*K;
  float acc = bb[c];
  for(int k=0;k<K;k++) acc = fmaf(xr[k], W[(size_t)k*D + c], acc);
  out[gid] = acc;
}

// ---------- batched GAT masked attention, 4 rows per block, all 3 scales ----------
// D==GH score pass: quad-cooperative (4 lanes per key row, coalesced 64B/quad)
template<int D, bool FINAL>
__global__ __launch_bounds__(256) void k_attn4B(const float* __restrict__ HnAll,
                                                const int* __restrict__ A0, const int* __restrict__ A1, const int* __restrict__ A2,
                                                float* __restrict__ outAll){
  __shared__ float sc[4][2048];
  __shared__ float hr[4][GH];
  __shared__ float redm[4][4];
  __shared__ float outp[4][4][GH];   // part, r, c (D==64)
  __shared__ float out3[4][4][4];    // wave, r, c (D==3)
  const int t = threadIdx.x, w = t>>6, lane = t&63;
  int b = blockIdx.x;
  int n, r0; size_t base; const int* A;
  if(b < 500){ n=2000; base=0;    r0=b*4;        A=A0; }
  else if(b < 750){ n=1000; base=2000; r0=(b-500)*4; A=A1; }
  else { n=500;  base=3000; r0=(b-750)*4; A=A2; }
  const int OD = FINAL ? 3 : (D==GH ? GH : 3);
  const float* Hn = HnAll + base*D;
  float* out = outAll + base*OD;
  if(D==GH){
    hr[w][lane] = Hn[(size_t)(r0 + w)*GH + lane];
  } else {
    if(t < 12) hr[t/3][t%3] = Hn[(size_t)(r0 + t/3)*3 + (t%3)];
  }
  __syncthreads();
  float lm0=-INFINITY, lm1=-INFINITY, lm2=-INFINITY, lm3=-INFINITY;
  if(D==GH){
    const int p = t & 3;
    for(int j = t>>2; j < n; j += 64){
      const float* hj = Hn + (size_t)j*GH;
      float s0=0.f,s1=0.f,s2=0.f,s3=0.f;
      #pragma unroll
      for(int k4=0;k4<4;k4++){
        float4 h  = *(const float4*)(hj + k4*16 + p*4);
        float4 a0 = *(const float4*)&hr[0][k4*16 + p*4];
        float4 a1 = *(const float4*)&hr[1][k4*16 + p*4];
        float4 a2 = *(const float4*)&hr[2][k4*16 + p*4];
        float4 a3 = *(const float4*)&hr[3][k4*16 + p*4];
        s0 = fmaf(a0.x,h.x, fmaf(a0.y,h.y, fmaf(a0.z,h.z, fmaf(a0.w,h.w, s0))));
        s1 = fmaf(a1.x,h.x, fmaf(a1.y,h.y, fmaf(a1.z,h.z, fmaf(a1.w,h.w, s1))));
        s2 = fmaf(a2.x,h.x, fmaf(a2.y,h.y, fmaf(a2.z,h.z, fmaf(a2.w,h.w, s2))));
        s3 = fmaf(a3.x,h.x, fmaf(a3.y,h.y, fmaf(a3.z,h.z, fmaf(a3.w,h.w, s3))));
      }
      s0 += __shfl_xor(s0,1,64); s0 += __shfl_xor(s0,2,64);
      s1 += __shfl_xor(s1,1,64); s1 += __shfl_xor(s1,2,64);
      s2 += __shfl_xor(s2,1,64); s2 += __shfl_xor(s2,2,64);
      s3 += __shfl_xor(s3,1,64); s3 += __shfl_xor(s3,2,64);
      if(p==0){
        int m0 = A[(size_t)(r0+0)*n + j];
        int m1 = A[(size_t)(r0+1)*n + j];
        int m2 = A[(size_t)(r0+2)*n + j];
        int m3 = A[(size_t)(r0+3)*n + j];
        s0 = (m0>0) ? s0 : -1e9f;
        s1 = (m1>0) ? s1 : -1e9f;
        s2 = (m2>0) ? s2 : -1e9f;
        s3 = (m3>0) ? s3 : -1e9f;
        sc[0][j]=s0; sc[1][j]=s1; sc[2][j]=s2; sc[3][j]=s3;
        lm0=fmaxf(lm0,s0); lm1=fmaxf(lm1,s1); lm2=fmaxf(lm2,s2); lm3=fmaxf(lm3,s3);
      }
    }
  } else {
    for(int j=t; j<n; j+=256){
      float h0=Hn[(size_t)j*3+0], h1=Hn[(size_t)j*3+1], h2=Hn[(size_t)j*3+2];
      float s0 = hr[0][0]*h0 + hr[0][1]*h1 + hr[0][2]*h2;
      float s1 = hr[1][0]*h0 + hr[1][1]*h1 + hr[1][2]*h2;
      float s2 = hr[2][0]*h0 + hr[2][1]*h1 + hr[2][2]*h2;
      float s3 = hr[3][0]*h0 + hr[3][1]*h1 + hr[3][2]*h2;
      int m0 = A[(size_t)(r0+0)*n + j];
      int m1 = A[(size_t)(r0+1)*n + j];
      int m2 = A[(size_t)(r0+2)*n + j];
      int m3 = A[(size_t)(r0+3)*n + j];
      s0 = (m0>0) ? s0 : -1e9f;
      s1 = (m1>0) ? s1 : -1e9f;
      s2 = (m2>0) ? s2 : -1e9f;
      s3 = (m3>0) ? s3 : -1e9f;
      sc[0][j]=s0; sc[1][j]=s1; sc[2][j]=s2; sc[3][j]=s3;
      lm0=fmaxf(lm0,s0); lm1=fmaxf(lm1,s1); lm2=fmaxf(lm2,s2); lm3=fmaxf(lm3,s3);
    }
  }
  {
    float w0=waveReduceMax(lm0), w1=waveReduceMax(lm1), w2=waveReduceMax(lm2), w3=waveReduceMax(lm3);
    if(lane==0){ redm[0][w]=w0; redm[1][w]=w1; redm[2][w]=w2; redm[3][w]=w3; }
  }
  __syncthreads();
  float m[4];
  #pragma unroll
  for(int r=0;r<4;r++) m[r] = fmaxf(fmaxf(redm[r][0],redm[r][1]), fmaxf(redm[r][2],redm[r][3]));
  __syncthreads();
  float ls0=0.f, ls1=0.f, ls2=0.f, ls3=0.f;
  for(int j=t; j<n; j+=256){
    float e0=__expf(sc[0][j]-m[0]); sc[0][j]=e0; ls0+=e0;
    float e1=__expf(sc[1][j]-m[1]); sc[1][j]=e1; ls1+=e1;
    float e2=__expf(sc[2][j]-m[2]); sc[2][j]=e2; ls2+=e2;
    float e3=__expf(sc[3][j]-m[3]); sc[3][j]=e3; ls3+=e3;
  }
  {
    float w0=waveReduceSum(ls0), w1=waveReduceSum(ls1), w2=waveReduceSum(ls2), w3=waveReduceSum(ls3);
    if(lane==0){ redm[0][w]=w0; redm[1][w]=w1; redm[2][w]=w2; redm[3][w]=w3; }
  }
  __syncthreads();
  float S[4];
  #pragma unroll
  for(int r=0;r<4;r++) S[r] = redm[r][0]+redm[r][1]+redm[r][2]+redm[r][3];
  if(D==GH){
    float acc0=0.f, acc1=0.f, acc2=0.f, acc3=0.f;
    const int c = lane, part = w;
    #pragma unroll 2
    for(int j=part; j<n; j+=4){
      float hv = Hn[(size_t)j*GH + c];
      acc0 = fmaf(sc[0][j], hv, acc0);
      acc1 = fmaf(sc[1][j], hv, acc1);
      acc2 = fmaf(sc[2][j], hv, acc2);
      acc3 = fmaf(sc[3][j], hv, acc3);
    }
    outp[part][0][c]=acc0; outp[part][1][c]=acc1; outp[part][2][c]=acc2; outp[part][3][c]=acc3;
    __syncthreads();
    int r = w;
    float tot = outp[0][r][lane]+outp[1][r][lane]+outp[2][r][lane]+outp[3][r][lane];
    out[(size_t)(r0+r)*GH + lane] = fmaxf(tot/S[r], 0.f);
  } else {
    float a00=0,a01=0,a02=0, a10=0,a11=0,a12=0, a20=0,a21=0,a22=0, a30=0,a31=0,a32=0;
    for(int j=t; j<n; j+=256){
      float h0=Hn[(size_t)j*3+0], h1=Hn[(size_t)j*3+1], h2=Hn[(size_t)j*3+2];
      float e0=sc[0][j], e1=sc[1][j], e2=sc[2][j], e3=sc[3][j];
      a00=fmaf(e0,h0,a00); a01=fmaf(e0,h1,a01); a02=fmaf(e0,h2,a02);
      a10=fmaf(e1,h0,a10); a11=fmaf(e1,h1,a11); a12=fmaf(e1,h2,a12);
      a20=fmaf(e2,h0,a20); a21=fmaf(e2,h1,a21); a22=fmaf(e2,h2,a22);
      a30=fmaf(e3,h0,a30); a31=fmaf(e3,h1,a31); a32=fmaf(e3,h2,a32);
    }
    float v[12] = {a00,a01,a02,a10,a11,a12,a20,a21,a22,a30,a31,a32};
    #pragma unroll
    for(int i=0;i<12;i++){
      float ws = waveReduceSum(v[i]);
      if(lane==0) out3[w][i/3][i%3] = ws;
    }
    __syncthreads();
    if(t < 4){
      int r = t;
      float t0 = out3[0][r][0]+out3[1][r][0]+out3[2][r][0]+out3[3][r][0];
      float t1 = out3[0][r][1]+out3[1][r][1]+out3[2][r][1]+out3[3][r][1];
      float t2 = out3[0][r][2]+out3[1][r][2]+out3[2][r][2]+out3[3][r][2];
      float v0 = fmaxf(t0/S[r], 0.f);
      float v1 = fmaxf(t1/S[r], 0.f);
      float v2 = fmaxf(t2/S[r], 0.f);
      if(FINAL){
        float mm = fmaxf(v0, fmaxf(v1,v2));
        float e0=__expf(v0-mm), e1=__expf(v1-mm), e2=__expf(v2-mm);
        float ss = e0+e1+e2;
        out[(size_t)(r0+r)*3+0]=e0/ss; out[(size_t)(r0+r)*3+1]=e1/ss; out[(size_t)(r0+r)*3+2]=e2/ss;
      } else {
        out[(size_t)(r0+r)*3+0]=v0; out[(size_t)(r0+r)*3+1]=v1; out[(size_t)(r0+r)*3+2]=v2;
      }
    }
  }
}

// ---------- superpixel sums of fused (computed inline) via CSR gather ----------
__global__ __launch_bounds__(128) void k_spsum0(const int* __restrict__ seg1, const int* __restrict__ seg2,
                                                const float* __restrict__ S0, const float* __restrict__ S1, const float* __restrict__ S2,
                                                const float* __restrict__ cst,
                                                const int* __restrict__ offs, const int* __restrict__ cnt,
                                                const int* __restrict__ list, float* __restrict__ spsum){
  __shared__ float r[2][3];
  int s = blockIdx.x;
  int t = threadIdx.x, w = t>>6, lane = t&63;
  int n = cnt[s], st = offs[s];
  float w0=cst[0], w1=cst[1], w2=cst[2];
  float s00=w0*S0[s*3+0], s01=w0*S0[s*3+1], s02=w0*S0[s*3+2];
  float a0=0.f, a1=0.f, a2=0.f;
  for(int q=t; q<n; q+=128){
    int p = list[st+q];
    int b = seg1[p], c = seg2[p];
    a0 += s00 + w1*S1[b*3+0] + w2*S2[c*3+0];
    a1 += s01 + w1*S1[b*3+1] + w2*S2[c*3+1];
    a2 += s02 + w1*S1[b*3+2] + w2*S2[c*3+2];
  }
  a0 = waveReduceSum(a0); a1 = waveReduceSum(a1); a2 = waveReduceSum(a2);
  if(lane==0){ r[w][0]=a0; r[w][1]=a1; r[w][2]=a2; }
  __syncthreads();
  if(t==0){
    spsum[s*3+0]=r[0][0]+r[1][0];
    spsum[s*3+1]=r[0][1]+r[1][1];
    spsum[s*3+2]=r[0][2]+r[1][2];
  }
}

// ---------- PCR: smoothed_sp[r] = softmax(attn[r]) @ (spsum/cnt) ----------
__global__ __launch_bounds__(256) void k_pcr(const float* __restrict__ attn, const float* __restrict__ spsum,
                                             const int* __restrict__ cnt0, float* __restrict__ sm){
  __shared__ float buf[2048];
  __shared__ float red[4];
  __shared__ float r3[256][3];
  int r=blockIdx.x, t=threadIdx.x;
  float lmax=-INFINITY;
  for(int j=t;j<2000;j+=256){ float v=attn[(size_t)r*2000+j]; buf[j]=v; lmax=fmaxf(lmax,v); }
  float wm=waveReduceMax(lmax);
  if((t&63)==0) red[t>>6]=wm;
  __syncthreads();
  float m = fmaxf(fmaxf(red[0],red[1]),fmaxf(red[2],red[3]));
  __syncthreads();
  float lsum=0.f;
  for(int j=t;j<2000;j+=256){ float e=__expf(buf[j]-m); buf[j]=e; lsum+=e; }
  float wsu=waveReduceSum(lsum);
  if((t&63)==0) red[t>>6]=wsu;
  __syncthreads();
  float S=red[0]+red[1]+red[2]+red[3];
  float a0=0.f,a1=0.f,a2=0.f;
  for(int j=t;j<2000;j+=256){
    float e=buf[j];
    float inv = 1.f / fmaxf((float)cnt0[j], 1.f);
    a0=fmaf(e, spsum[j*3+0]*inv, a0);
    a1=fmaf(e, spsum[j*3+1]*inv, a1);
    a2=fmaf(e, spsum[j*3+2]*inv, a2);
  }
  r3[t][0]=a0; r3[t][1]=a1; r3[t][2]=a2;
  __syncthreads();
  for(int st=128;st>0;st>>=1){
    if(t<st){ r3[t][0]+=r3[t+st][0]; r3[t][1]+=r3[t+st][1]; r3[t][2]+=r3[t+st][2]; }
    __syncthreads();
  }
  if(t==0){ sm[r*3+0]=r3[0][0]/S; sm[r*3+1]=r3[0][1]/S; sm[r*3+2]=r3[0][2]/S; }
}

// ---------- S_flat (fused computed inline) + argmax class index ----------
__global__ void k_sflat(const int* __restrict__ s0g, const int* __restrict__ s1g, const int* __restrict__ s2g,
                        const float* __restrict__ S0, const float* __restrict__ S1, const float* __restrict__ S2,
                        const float* __restrict__ sm, const float* __restrict__ cst,
                        float* __restrict__ Sf, int* __restrict__ ci){
  int p = blockIdx.x*256 + threadIdx.x;
  if(p >= N_PIX) return;
  float a = cst[3];
  float w0=cst[0], w1=cst[1], w2=cst[2];
  int sa=s0g[p], sb=s1g[p], sc_=s2g[p];
  float f0 = w0*S0[sa*3+0] + w1*S1[sb*3+0] + w2*S2[sc_*3+0];
  float f1 = w0*S0[sa*3+1] + w1*S1[sb*3+1] + w2*S2[sc_*3+1];
  float f2 = w0*S0[sa*3+2] + w1*S1[sb*3+2] + w2*S2[sc_*3+2];
  float x0 = a*sm[sa*3+0] + (1.f-a)*f0;
  float x1 = a*sm[sa*3+1] + (1.f-a)*f1;
  float x2 = a*sm[sa*3+2] + (1.f-a)*f2;
  Sf[(size_t)p*3+0]=x0; Sf[(size_t)p*3+1]=x1; Sf[(size_t)p*3+2]=x2;
  int c=0; float b=x0;
  if(x1>b){c=1;b=x1;}
  if(x2>b){c=2;}
  ci[p]=c;
}

// ---------- weight pre-pack into MFMA B-fragment order, bf16 hi/lo ----------
__global__ void k_packw(const float* __restrict__ W, int Kreal, int Nreal, int nkt, int nnt,
                        u16* __restrict__ dhi, u16* __restrict__ dlo){
  int gid = blockIdx.x*256 + threadIdx.x;
  int total = nnt*nkt*512;
  if(gid >= total) return;
  int j = gid & 7, l = (gid>>3)&63;
  int rem = gid >> 9;               // nt*nkt + ks
  int ks = rem % nkt;
  int nt = rem / nkt;
  int k = ks*32 + (l>>4)*8 + j;
  int n = nt*16 + (l&15);
  float w = (k < Kreal && n < Nreal) ? W[(size_t)k*Nreal + n] : 0.f;
  u16 hi = f2bf(w);
  dhi[gid] = hi;
  dlo[gid] = f2bf(w - bf2f(hi));
}

// ---------- MFMA MLP (156->128->128->156): 64 px/block, 512 threads (8 waves) ----------
// Layer-3 strictly sequential (primary compute+epilogue, THEN secondary) to kill spills.
#define MFMA(a,b,c) __builtin_amdgcn_mfma_f32_16x16x32_bf16((a),(b),(c),0,0,0)

__global__ __launch_bounds__(512, 4) void k_mlp_mfma(
    const float* __restrict__ Y, const int* __restrict__ ci,
    const u16* __restrict__ P1h, const u16* __restrict__ P1l,
    const u16* __restrict__ P2h, const u16* __restrict__ P2l,
    const u16* __restrict__ P3h, const u16* __restrict__ P3l,
    const float* __restrict__ b1, const float* __restrict__ b2, const float* __restrict__ b3,
    float* __restrict__ gsum, float* __restrict__ gwsum){
  __shared__ u16 SH[64*168];                 // X-hi [64][168]  ->  A-hi [64][136]
  __shared__ u16 SL[64*168];                 // X-lo            ->  A-lo
  __shared__ float csum[480], cwsum[480];    // per-class sums [3][160]; unique writers
  __shared__ int cis[64];
  const int t = threadIdx.x;
  const int lane = t & 63, w = t >> 6;       // 8 waves
  const int g = lane >> 4, r16 = lane & 15;
  const size_t p0 = (size_t)blockIdx.x * 64;

  if(t<64) cis[t] = ci[p0+t];
  // stage Y tile: 64 rows x 39 float4, packed bf16 hi/lo split
  for(int i=t;i<2496;i+=512){
    int row = i/39, q = i - row*39, c0 = q*4;
    float4 v = *(const float4*)(Y + (p0+row)*NB + c0);
    unsigned h01 = pkbf(v.x, v.y), h23 = pkbf(v.z, v.w);
    float l0 = v.x - __uint_as_float(h01 << 16);
    float l1 = v.y - __uint_as_float(h01 & 0xFFFF0000u);
    float l2 = v.z - __uint_as_float(h23 << 16);
    float l3 = v.w - __uint_as_float(h23 & 0xFFFF0000u);
    *(unsigned*)&SH[row*168+c0]   = h01;
    *(unsigned*)&SH[row*168+c0+2] = h23;
    *(unsigned*)&SL[row*168+c0]   = pkbf(l0, l1);
    *(unsigned*)&SL[row*168+c0+2] = pkbf(l2, l3);
  }
  if(t<128){ int row=t>>1, o=156+(t&1)*2;
    *(unsigned*)&SH[row*168+o]=0u; *(unsigned*)&SL[row*168+o]=0u; }
  __syncthreads();

  const int c12 = w*16 + r16;                // this wave's output column, layers 1/2

  // ---- layer 1: K=160 (5 ks), wave w -> ntile w, 4 m-tiles ----
  {
    f32x4 acc[4];
    #pragma unroll
    for(int mt=0;mt<4;mt++) acc[mt] = (f32x4){0.f,0.f,0.f,0.f};
    #pragma unroll
    for(int ks=0;ks<5;ks++){
      bfrag8 bh = *(const bfrag8*)(P1h + ((size_t)(w*5+ks))*512 + lane*8);
      bfrag8 bl = *(const bfrag8*)(P1l + ((size_t)(w*5+ks))*512 + lane*8);
      #pragma unroll
      for(int mt=0;mt<4;mt++){
        bfrag8 ah = *(const bfrag8*)(SH + (mt*16+r16)*168 + g*8 + ks*32);
        bfrag8 al = *(const bfrag8*)(SL + (mt*16+r16)*168 + g*8 + ks*32);
        acc[mt]=MFMA(ah,bh,acc[mt]); acc[mt]=MFMA(ah,bl,acc[mt]); acc[mt]=MFMA(al,bh,acc[mt]);
      }
    }
    __syncthreads();   // all waves done reading X
    float bv = b1[c12];
    #pragma unroll
    for(int mt=0;mt<4;mt++){
      float v0 = fmaxf(acc[mt][0] + bv, 0.f);
      float v1 = fmaxf(acc[mt][1] + bv, 0.f);
      float v2 = fmaxf(acc[mt][2] + bv, 0.f);
      float v3 = fmaxf(acc[mt][3] + bv, 0.f);
      unsigned h01 = pkbf(v0,v1), h23 = pkbf(v2,v3);
      float l0 = v0 - __uint_as_float(h01<<16);
      float l1 = v1 - __uint_as_float(h01 & 0xFFFF0000u);
      float l2 = v2 - __uint_as_float(h23<<16);
      float l3 = v3 - __uint_as_float(h23 & 0xFFFF0000u);
      unsigned q01 = pkbf(l0,l1), q23 = pkbf(l2,l3);
      int rb = (mt*16 + g*4)*136 + c12;
      SH[rb      ] = (u16)h01; SH[rb+136 ] = (u16)(h01>>16);
      SH[rb+272  ] = (u16)h23; SH[rb+408 ] = (u16)(h23>>16);
      SL[rb      ] = (u16)q01; SL[rb+136 ] = (u16)(q01>>16);
      SL[rb+272  ] = (u16)q23; SL[rb+408 ] = (u16)(q23>>16);
    }
  }
  __syncthreads();

  // ---- layer 2: K=128 (4 ks); regs across barrier, overwrite A ----
  {
    f32x4 acc[4];
    #pragma unroll
    for(int mt=0;mt<4;mt++) acc[mt] = (f32x4){0.f,0.f,0.f,0.f};
    #pragma unroll
    for(int ks=0;ks<4;ks++){
      bfrag8 bh = *(const bfrag8*)(P2h + ((size_t)(w*4+ks))*512 + lane*8);
      bfrag8 bl = *(const bfrag8*)(P2l + ((size_t)(w*4+ks))*512 + lane*8);
      #pragma unroll
      for(int mt=0;mt<4;mt++){
        bfrag8 ah = *(const bfrag8*)(SH + (mt*16+r16)*136 + g*8 + ks*32);
        bfrag8 al = *(const bfrag8*)(SL + (mt*16+r16)*136 + g*8 + ks*32);
        acc[mt]=MFMA(ah,bh,acc[mt]); acc[mt]=MFMA(ah,bl,acc[mt]); acc[mt]=MFMA(al,bh,acc[mt]);
      }
    }
    __syncthreads();   // all waves done reading A(layer1)
    float bv = b2[c12];
    #pragma unroll
    for(int mt=0;mt<4;mt++){
      float v0 = fmaxf(acc[mt][0] + bv, 0.f);
      float v1 = fmaxf(acc[mt][1] + bv, 0.f);
      float v2 = fmaxf(acc[mt][2] + bv, 0.f);
      float v3 = fmaxf(acc[mt][3] + bv, 0.f);
      unsigned h01 = pkbf(v0,v1), h23 = pkbf(v2,v3);
      float l0 = v0 - __uint_as_float(h01<<16);
      float l1 = v1 - __uint_as_float(h01 & 0xFFFF0000u);
      float l2 = v2 - __uint_as_float(h23<<16);
      float l3 = v3 - __uint_as_float(h23 & 0xFFFF0000u);
      unsigned q01 = pkbf(l0,l1), q23 = pkbf(l2,l3);
      int rb = (mt*16 + g*4)*136 + c12;
      SH[rb      ] = (u16)h01; SH[rb+136 ] = (u16)(h01>>16);
      SH[rb+272  ] = (u16)h23; SH[rb+408 ] = (u16)(h23>>16);
      SL[rb      ] = (u16)q01; SL[rb+136 ] = (u16)(q01>>16);
      SL[rb+272  ] = (u16)q23; SL[rb+408 ] = (u16)(q23>>16);
    }
  }
  __syncthreads();

  // ---- layer 3, phase A: primary ntile w (compute -> epilogue, acc fully consumed) ----
  {
    f32x4 acc[4];
    #pragma unroll
    for(int mt=0;mt<4;mt++) acc[mt] = (f32x4){0.f,0.f,0.f,0.f};
    #pragma unroll
    for(int ks=0;ks<4;ks++){
      bfrag8 bh = *(const bfrag8*)(P3h + ((size_t)(w*4+ks))*512 + lane*8);
      bfrag8 bl = *(const bfrag8*)(P3l + ((size_t)(w*4+ks))*512 + lane*8);
      #pragma unroll
      for(int mt=0;mt<4;mt++){
        bfrag8 ah = *(const bfrag8*)(SH + (mt*16+r16)*136 + g*8 + ks*32);
        bfrag8 al = *(const bfrag8*)(SL + (mt*16+r16)*136 + g*8 + ks*32);
        acc[mt]=MFMA(ah,bh,acc[mt]); acc[mt]=MFMA(ah,bl,acc[mt]); acc[mt]=MFMA(al,bh,acc[mt]);
      }
    }
    const int c = w*16 + r16;        // primary column, < 128
    float bv = b3[c];
    float cs0=0,cs1=0,cs2=0, cw0=0,cw1=0,cw2=0;
    #pragma unroll
    for(int mt=0;mt<4;mt++){
      #pragma unroll
      for(int r=0;r<4;r++){
        int p = mt*16 + g*4 + r;
        float e = __expf(acc[mt][r] + bv);
        float y = Y[(p0+p)*NB + c];
        float ey = e*y;
        int k = cis[p];
        cs0 += (k==0)?e:0.f;  cs1 += (k==1)?e:0.f;  cs2 += (k==2)?e:0.f;
        cw0 += (k==0)?ey:0.f; cw1 += (k==1)?ey:0.f; cw2 += (k==2)?ey:0.f;
      }
    }
    #define GRED(v) { v += __shfl_xor(v,16,64); v += __shfl_xor(v,32,64); }
    GRED(cs0) GRED(cs1) GRED(cs2) GRED(cw0) GRED(cw1) GRED(cw2)
    if(g==0){
      csum[c]       = cs0; csum[160+c]  = cs1; csum[320+c]  = cs2;
      cwsum[c]      = cw0; cwsum[160+c] = cw1; cwsum[320+c] = cw2;
    }
  }
  // ---- layer 3, phase B: secondary ntile 8+w (waves 0,1 only), fully after phase A ----
  if(w < 2){
    const int c2 = 128 + w*16 + r16;
    f32x4 acc2[4];
    #pragma unroll
    for(int mt=0;mt<4;mt++) acc2[mt] = (f32x4){0.f,0.f,0.f,0.f};
    #pragma unroll
    for(int ks=0;ks<4;ks++){
      bfrag8 bh = *(const bfrag8*)(P3h + ((size_t)((8+w)*4+ks))*512 + lane*8);
      bfrag8 bl = *(const bfrag8*)(P3l + ((size_t)((8+w)*4+ks))*512 + lane*8);
      #pragma unroll
      for(int mt=0;mt<4;mt++){
        bfrag8 ah = *(const bfrag8*)(SH + (mt*16+r16)*136 + g*8 + ks*32);
        bfrag8 al = *(const bfrag8*)(SL + (mt*16+r16)*136 + g*8 + ks*32);
        acc2[mt]=MFMA(ah,bh,acc2[mt]); acc2[mt]=MFMA(ah,bl,acc2[mt]); acc2[mt]=MFMA(al,bh,acc2[mt]);
      }
    }
    float ds0=0,ds1=0,ds2=0, dw0=0,dw1=0,dw2=0;
    if(c2 < 156){
      float bv2 = b3[c2];
      #pragma unroll
      for(int mt=0;mt<4;mt++){
        #pragma unroll
        for(int r=0;r<4;r++){
          int p = mt*16 + g*4 + r;
          float e = __expf(acc2[mt][r] + bv2);
          float y = Y[(p0+p)*NB + c2];
          float ey = e*y;
          int k = cis[p];
          ds0 += (k==0)?e:0.f;  ds1 += (k==1)?e:0.f;  ds2 += (k==2)?e:0.f;
          dw0 += (k==0)?ey:0.f; dw1 += (k==1)?ey:0.f; dw2 += (k==2)?ey:0.f;
        }
      }
    }
    GRED(ds0) GRED(ds1) GRED(ds2) GRED(dw0) GRED(dw1) GRED(dw2)
    #undef GRED
    if(g==0 && c2 < 156){
      csum[c2]       = ds0; csum[160+c2]  = ds1; csum[320+c2]  = ds2;
      cwsum[c2]      = dw0; cwsum[160+c2] = dw1; cwsum[320+c2] = dw2;
    }
  }
  __syncthreads();
  // flush to 256 rotation slots (skip unwritten cols 156..159 of each class)
  float* gs = gsum  + (size_t)(blockIdx.x & 255)*480;
  float* gw = gwsum + (size_t)(blockIdx.x & 255)*480;
  for(int i=t;i<480;i+=512){
    if((i % 160) < 156){
      atomicAdd(&gs[i], csum[i]);
      atomicAdd(&gw[i], cwsum[i]);
    }
  }
}

// ---------- final M: reduce 256 slots ----------
__global__ void k_finalM(const float* __restrict__ gsump, const float* __restrict__ gwsump, float* __restrict__ M){
  int e = blockIdx.x*256 + threadIdx.x;
  if(e < 468){
    int cls = e/156, c = e - cls*156;
    int off = cls*160 + c;
    float s=0.f, wv=0.f;
    for(int k=0;k<256;k++){ s += gsump[(size_t)k*480 + off]; wv += gwsump[(size_t)k*480 + off]; }
    M[e] = (s > 0.f) ? (wv / fmaxf(s, 1e-30f)) : 0.f;
  }
}

// ---------- Y_hat = S_flat @ M, float4 stores ----------
__global__ void k_yhat4(const float* __restrict__ Sf, const float* __restrict__ M, float4* __restrict__ out){
  unsigned idx = blockIdx.x*256u + threadIdx.x;   // N_PIX*39 float4s, grid exact
  unsigned p = idx / 39u, q = idx - p*39u;
  unsigned c0 = q*4u;
  float4 m0 = *(const float4*)(M + c0);
  float4 m1 = *(const float4*)(M + 156 + c0);
  float4 m2 = *(const float4*)(M + 312 + c0);
  float s0 = Sf[(size_t)p*3+0], s1 = Sf[(size_t)p*3+1], s2 = Sf[(size_t)p*3+2];
  float4 r;
  r.x = s0*m0.x + s1*m1.x + s2*m2.x;
  r.y = s0*m0.y + s1*m1.y + s2*m2.y;
  r.z = s0*m0.z + s1*m1.z + s2*m2.z;
  r.w = s0*m0.w + s1*m1.w + s2*m2.w;
  out[idx] = r;
}

extern "C" void kernel_launch(void* const* d_in, const int* in_sizes, int n_in,
                              void* d_out, int out_size, void* d_ws, size_t ws_size,
                              hipStream_t stream){
  const float* Y    = (const float*)d_in[0];
  const int*   seg0 = (const int*)d_in[1];
  const int*   A0   = (const int*)d_in[2];
  const int*   seg1 = (const int*)d_in[3];
  const int*   A1   = (const int*)d_in[4];
  const int*   seg2 = (const int*)d_in[5];
  const int*   A2   = (const int*)d_in[6];
  const float* attn = (const float*)d_in[7];
  const float* alpha= (const float*)d_in[8];
  const float* sw   = (const float*)d_in[9];
  const float* W1a[3] = {(const float*)d_in[10], (const float*)d_in[14], (const float*)d_in[18]};
  const float* b1a[3] = {(const float*)d_in[11], (const float*)d_in[15], (const float*)d_in[19]};
  const float* W2a[3] = {(const float*)d_in[12], (const float*)d_in[16], (const float*)d_in[20]};
  const float* b2a[3] = {(const float*)d_in[13], (const float*)d_in[17], (const float*)d_in[21]};
  const float* Wm1=(const float*)d_in[22]; const float* bm1=(const float*)d_in[23];
  const float* Wm2=(const float*)d_in[24]; const float* bm2=(const float*)d_in[25];
  const float* Wm3=(const float*)d_in[26]; const float* bm3=(const float*)d_in[27];
  float* out = (float*)d_out;

  char* base = (char*)d_ws;
  size_t off = 0;
  auto alloc = [&](size_t bytes)->char*{
    char* r = base + off;
    off += (bytes + 255) & ~(size_t)255;
    return r;
  };
  int* cntAll = (int*)alloc((size_t)3500*4);
  int* cnt[3] = {cntAll, cntAll+2000, cntAll+3000};
  int* offs[3]; int* cur[3]; int* lst[3];
  for(int i=0;i<3;i++) offs[i] = (int*)alloc((size_t)(i==0?2000:(i==1?1000:500))*4);
  for(int i=0;i<3;i++) cur[i]  = (int*)alloc((size_t)(i==0?2000:(i==1?1000:500))*4);
  for(int i=0;i<3;i++) lst[i]  = (int*)alloc((size_t)N_PIX*4);
  float* X_all   = (float*)alloc((size_t)3500*NB*4);
  float* Hn_all  = (float*)alloc((size_t)3500*64*4);
  float* x1b_all = (float*)alloc((size_t)3500*64*4);
  float* Hn2_all = (float*)alloc((size_t)3500*3*4);
  float* Ss_all  = (float*)alloc((size_t)3500*3*4);
  float* cst   = (float*)alloc(64);
  float* spsum = (float*)alloc((size_t)2000*3*4);
  float* smth  = (float*)alloc((size_t)2000*3*4);
  float* Sf    = (float*)alloc((size_t)N_PIX*3*4);
  int*   ci    = (int*)alloc((size_t)N_PIX*4);
  u16* P1h = (u16*)alloc((size_t)20480*2); u16* P1l = (u16*)alloc((size_t)20480*2);
  u16* P2h = (u16*)alloc((size_t)16384*2); u16* P2l = (u16*)alloc((size_t)16384*2);
  u16* P3h = (u16*)alloc((size_t)20480*2); u16* P3l = (u16*)alloc((size_t)20480*2);
  float* gsump  = (float*)alloc((size_t)256*480*4);
  float* gwsump = (float*)alloc((size_t)256*480*4);
  float* Mbuf   = (float*)alloc((size_t)480*4);

  float* X0 = X_all;            float* X1 = X_all + (size_t)2000*NB;   float* X2 = X_all + (size_t)3000*NB;
  const float* Ss0 = Ss_all;    const float* Ss1 = Ss_all + 2000*3;    const float* Ss2 = Ss_all + 3000*3;

  // per-call re-init (replay/poison safe)
  hipMemsetAsync(cntAll, 0, (size_t)3500*4, stream);
  hipMemsetAsync(gsump, 0, (size_t)256*480*4, stream);
  hipMemsetAsync(gwsump, 0, (size_t)256*480*4, stream);
  k_prep<<<1,64,0,stream>>>(sw, alpha, cst);

  // weight pre-pack
  k_packw<<<(8*5*512+255)/256,256,0,stream>>>(Wm1, 156, 128, 5, 8, P1h, P1l);
  k_packw<<<(8*4*512+255)/256,256,0,stream>>>(Wm2, 128, 128, 4, 8, P2h, P2l);
  k_packw<<<(10*4*512+255)/256,256,0,stream>>>(Wm3, 128, 156, 4, 10, P3h, P3l);

  // CSR + segment means
  k_count<<<N_PIX/256,256,0,stream>>>(seg0,seg1,seg2,cnt[0],cnt[1],cnt[2]);
  k_scan<<<3,256,0,stream>>>(cnt[0],cnt[1],cnt[2],offs[0],offs[1],offs[2],cur[0],cur[1],cur[2]);
  k_fill<<<N_PIX/256,256,0,stream>>>(seg0,seg1,seg2,cur[0],cur[1],cur[2],lst[0],lst[1],lst[2]);
  k_segmean3<<<3500,192,0,stream>>>(Y,
      offs[0],cnt[0],lst[0],X0,
      offs[1],cnt[1],lst[1],X1,
      offs[2],cnt[2],lst[2],X2);

  // Multi-scale GAT encoder (batched: 4 launches total)
  k_linearB<<<(3500*64+255)/256,256,0,stream>>>(X_all, NB, 64,
      W1a[0],b1a[0],W1a[1],b1a[1],W1a[2],b1a[2], Hn_all);
  k_attn4B<64,false><<<875,256,0,stream>>>(Hn_all, A0,A1,A2, x1b_all);
  k_linearB<<<(3500*3+255)/256,256,0,stream>>>(x1b_all, 64, 3,
      W2a[0],b2a[0],W2a[1],b2a[1],W2a[2],b2a[2], Hn2_all);
  k_attn4B<3,true><<<875,256,0,stream>>>(Hn2_all, A0,A1,A2, Ss_all);

  // spsum (fused inline) + PCR + sflat (fused inline)
  k_spsum0<<<2000,128,0,stream>>>(seg1, seg2, Ss0, Ss1, Ss2, cst, offs[0], cnt[0], lst[0], spsum);
  k_pcr<<<2000,256,0,stream>>>(attn, spsum, cnt[0], smth);
  k_sflat<<<N_PIX/256,256,0,stream>>>(seg0, seg1, seg2, Ss0, Ss1, Ss2, smth, cst, Sf, ci);

  // ACDE: MFMA MLP (64 px/block, sequential L3 phases) + unique-writer epilogue
  k_mlp_mfma<<<N_PIX/64,512,0,stream>>>(Y, ci, P1h,P1l,P2h,P2l,P3h,P3l, bm1,bm2,bm3, gsump, gwsump);
  k_finalM<<<2,256,0,stream>>>(gsump, gwsump, Mbuf);
  k_yhat4<<<(N_PIX/256)*39,256,0,stream>>>(Sf, Mbuf, (float4*)out);
  (void)in_sizes; (void)n_in; (void)out_size;
}

// Round 15
// 699.504 us; speedup vs baseline: 2.1157x; 1.0607x over previous
//
#include <hip/hip_runtime.h>
#include <hip/hip_bf16.h>
#include <math.h>

#define N_PIX (512*512)
#define NB 156
#define GH 64

typedef unsigned short u16;
typedef __attribute__((ext_vector_type(8))) short bfrag8;   // 8 bf16 = 4 VGPRs
typedef __attribute__((ext_vector_type(4))) float f32x4;    // MFMA accumulator

// ---------- bf16 helpers ----------
__device__ __forceinline__ u16 f2bf(float x){
  unsigned u = __float_as_uint(x);
  unsigned r = (u + 0x7FFFu + ((u >> 16) & 1u)) >> 16;
  return (u16)r;
}
__device__ __forceinline__ float bf2f(u16 h){
  return __uint_as_float(((unsigned)h) << 16);
}
// packed RNE: low 16 = bf16(a), high 16 = bf16(b)  (v_cvt_pk_bf16_f32)
__device__ __forceinline__ unsigned pkbf(float a, float b){
  __hip_bfloat162 h = __float22bfloat162_rn(make_float2(a,b));
  unsigned u; __builtin_memcpy(&u,&h,4); return u;
}

__device__ __forceinline__ float waveReduceMax(float v){
  #pragma unroll
  for(int o=32;o>0;o>>=1) v = fmaxf(v, __shfl_down(v, o, 64));
  return v;
}
__device__ __forceinline__ float waveReduceSum(float v){
  #pragma unroll
  for(int o=32;o>0;o>>=1) v += __shfl_down(v, o, 64);
  return v;
}

// ---------- merged: derived constants + weight pre-pack (bf16 hi/lo, B-fragment order) ----------
__global__ void k_prep_pack(const float* __restrict__ sw, const float* __restrict__ alpha, float* __restrict__ cst,
                            const float* __restrict__ Wm1, const float* __restrict__ Wm2, const float* __restrict__ Wm3,
                            u16* __restrict__ P1h, u16* __restrict__ P1l,
                            u16* __restrict__ P2h, u16* __restrict__ P2l,
                            u16* __restrict__ P3h, u16* __restrict__ P3l){
  int b = blockIdx.x;
  if(b == 0){
    if(threadIdx.x == 0){
      float m = fmaxf(sw[0], fmaxf(sw[1], sw[2]));
      float e0=expf(sw[0]-m), e1=expf(sw[1]-m), e2=expf(sw[2]-m);
      float s = e0+e1+e2;
      cst[0]=e0/s; cst[1]=e1/s; cst[2]=e2/s;
      cst[3]=fminf(fmaxf(alpha[0],0.f),1.f);
    }
    return;
  }
  int pb = b - 1;
  const float* W; u16 *dh, *dl; int Kr, Nr, nkt, base;
  if(pb < 80){      W=Wm1; dh=P1h; dl=P1l; Kr=156; Nr=128; nkt=5; base=pb; }
  else if(pb<144){  W=Wm2; dh=P2h; dl=P2l; Kr=128; Nr=128; nkt=4; base=pb-80; }
  else {            W=Wm3; dh=P3h; dl=P3l; Kr=128; Nr=156; nkt=4; base=pb-144; }
  int gid = base*256 + threadIdx.x;
  int j = gid & 7, l = (gid>>3)&63;
  int rem = gid >> 9;               // nt*nkt + ks
  int ks = rem % nkt;
  int nt = rem / nkt;
  int k = ks*32 + (l>>4)*8 + j;
  int n = nt*16 + (l&15);
  float w = (k < Kr && n < Nr) ? W[(size_t)k*Nr + n] : 0.f;
  u16 hi = f2bf(w);
  dh[gid] = hi;
  dl[gid] = f2bf(w - bf2f(hi));
}

// ---------- CSR build ----------
__global__ void k_count(const int* __restrict__ s0, const int* __restrict__ s1, const int* __restrict__ s2,
                        int* c0, int* c1, int* c2){
  int p = blockIdx.x*256 + threadIdx.x;
  if(p < N_PIX){
    atomicAdd(&c0[s0[p]],1);
    atomicAdd(&c1[s1[p]],1);
    atomicAdd(&c2[s2[p]],1);
  }
}

__global__ __launch_bounds__(256) void k_scan(const int* __restrict__ c0, const int* __restrict__ c1, const int* __restrict__ c2,
                       int* o0, int* o1, int* o2, int* u0, int* u1, int* u2){
  const int* cnt; int* offs; int* cur; int n;
  if(blockIdx.x==0){ cnt=c0; offs=o0; cur=u0; n=2000; }
  else if(blockIdx.x==1){ cnt=c1; offs=o1; cur=u1; n=1000; }
  else { cnt=c2; offs=o2; cur=u2; n=500; }
  __shared__ int l[2048];
  __shared__ int cs[256];
  int t = threadIdx.x;
  for(int i=t;i<2048;i+=256) l[i] = (i<n) ? cnt[i] : 0;
  __syncthreads();
  int s = 0;
  #pragma unroll
  for(int j=0;j<8;j++) s += l[t*8+j];
  cs[t] = s;
  __syncthreads();
  for(int d=1; d<256; d<<=1){
    int v = (t>=d) ? cs[t-d] : 0;
    __syncthreads();
    cs[t] += v;
    __syncthreads();
  }
  int run = cs[t] - s;
  for(int j=0;j<8;j++){
    int idx = t*8+j;
    int o = run;
    run += l[idx];
    if(idx < n){ offs[idx] = o; cur[idx] = o; }
  }
}

__global__ void k_fill(const int* __restrict__ s0, const int* __restrict__ s1, const int* __restrict__ s2,
                       int* u0, int* u1, int* u2, int* L0, int* L1, int* L2){
  int p = blockIdx.x*256 + threadIdx.x;
  if(p < N_PIX){
    int a = atomicAdd(&u0[s0[p]],1); L0[a] = p;
    int b = atomicAdd(&u1[s1[p]],1); L1[b] = p;
    int c = atomicAdd(&u2[s2[p]],1); L2[c] = p;
  }
}

// ---------- fused segment mean over all 3 scales: 192 thr, 2 pixel-groups of 78 lanes ----------
__global__ __launch_bounds__(192) void k_segmean3(const float* __restrict__ Y,
    const int* __restrict__ o0, const int* __restrict__ c0, const int* __restrict__ l0, float* __restrict__ X0,
    const int* __restrict__ o1, const int* __restrict__ c1, const int* __restrict__ l1, float* __restrict__ X1,
    const int* __restrict__ o2, const int* __restrict__ c2, const int* __restrict__ l2, float* __restrict__ X2){
  int b = blockIdx.x;
  const int *offs, *cnt, *list; float* X; int s;
  if(b < 2000){ s=b;      offs=o0; cnt=c0; list=l0; X=X0; }
  else if(b < 3000){ s=b-2000; offs=o1; cnt=c1; list=l1; X=X1; }
  else { s=b-3000; offs=o2; cnt=c2; list=l2; X=X2; }
  __shared__ float part[156];
  int t = threadIdx.x;
  int grp = t / 96, tb = t - grp*96;
  int n = cnt[s], st = offs[s];
  float ax=0.f, ay=0.f;
  if(tb < 78){
    int q = grp;
    for(; q+6<n; q+=8){
      int p0 = list[st+q], p1 = list[st+q+2], p2 = list[st+q+4], p3 = list[st+q+6];
      float2 v0 = *(const float2*)(Y + (size_t)p0*NB + tb*2);
      float2 v1 = *(const float2*)(Y + (size_t)p1*NB + tb*2);
      float2 v2 = *(const float2*)(Y + (size_t)p2*NB + tb*2);
      float2 v3 = *(const float2*)(Y + (size_t)p3*NB + tb*2);
      ax += (v0.x + v1.x) + (v2.x + v3.x);
      ay += (v0.y + v1.y) + (v2.y + v3.y);
    }
    for(; q<n; q+=2){
      int p0 = list[st+q];
      float2 v0 = *(const float2*)(Y + (size_t)p0*NB + tb*2);
      ax += v0.x; ay += v0.y;
    }
  }
  if(grp==1 && tb<78){ part[tb*2]=ax; part[tb*2+1]=ay; }
  __syncthreads();
  if(grp==0 && tb<78){
    float inv = 1.f / fmaxf((float)n, 1.f);
    float2 r; r.x = (ax + part[tb*2])*inv; r.y = (ay + part[tb*2+1])*inv;
    *(float2*)(X + (size_t)s*NB + tb*2) = r;
  }
}

// ---------- batched small linear over all 3 scales (rows 0..3499) ----------
__global__ void k_linearB(const float* __restrict__ X, int K, int D,
                          const float* __restrict__ W0, const float* __restrict__ bb0,
                          const float* __restrict__ W1, const float* __restrict__ bb1,
                          const float* __restrict__ W2, const float* __restrict__ bb2,
                          float* __restrict__ out){
  int gid = blockIdx.x*256 + threadIdx.x;
  if(gid >= 3500*D) return;
  int r = gid / D, c = gid - r*D;
  const float* W; const float* bb;
  if(r < 2000){ W=W0; bb=bb0; }
  else if(r < 3000){ W=W1; bb=bb1; }
  else { W=W2; bb=bb2; }
  const float* xr = X + (size_t)r*K;
  float acc = bb[c];
  for(int k=0;k<K;k++) acc = fmaf(xr[k], W[(size_t)k*D + c], acc);
  out[gid] = acc;
}

// ---------- batched GAT masked attention, 4 rows per block, all 3 scales ----------
// D==GH score pass: quad-cooperative (4 lanes per key row, coalesced 64B/quad)
template<int D, bool FINAL>
__global__ __launch_bounds__(256) void k_attn4B(const float* __restrict__ HnAll,
                                                const int* __restrict__ A0, const int* __restrict__ A1, const int* __restrict__ A2,
                                                float* __restrict__ outAll){
  __shared__ float sc[4][2048];
  __shared__ float hr[4][GH];
  __shared__ float redm[4][4];
  __shared__ float outp[4][4][GH];   // part, r, c (D==64)
  __shared__ float out3[4][4][4];    // wave, r, c (D==3)
  const int t = threadIdx.x, w = t>>6, lane = t&63;
  int b = blockIdx.x;
  int n, r0; size_t base; const int* A;
  if(b < 500){ n=2000; base=0;    r0=b*4;        A=A0; }
  else if(b < 750){ n=1000; base=2000; r0=(b-500)*4; A=A1; }
  else { n=500;  base=3000; r0=(b-750)*4; A=A2; }
  const int OD = FINAL ? 3 : (D==GH ? GH : 3);
  const float* Hn = HnAll + base*D;
  float* out = outAll + base*OD;
  if(D==GH){
    hr[w][lane] = Hn[(size_t)(r0 + w)*GH + lane];
  } else {
    if(t < 12) hr[t/3][t%3] = Hn[(size_t)(r0 + t/3)*3 + (t%3)];
  }
  __syncthreads();
  float lm0=-INFINITY, lm1=-INFINITY, lm2=-INFINITY, lm3=-INFINITY;
  if(D==GH){
    const int p = t & 3;
    for(int j = t>>2; j < n; j += 64){
      const float* hj = Hn + (size_t)j*GH;
      float s0=0.f,s1=0.f,s2=0.f,s3=0.f;
      #pragma unroll
      for(int k4=0;k4<4;k4++){
        float4 h  = *(const float4*)(hj + k4*16 + p*4);
        float4 a0 = *(const float4*)&hr[0][k4*16 + p*4];
        float4 a1 = *(const float4*)&hr[1][k4*16 + p*4];
        float4 a2 = *(const float4*)&hr[2][k4*16 + p*4];
        float4 a3 = *(const float4*)&hr[3][k4*16 + p*4];
        s0 = fmaf(a0.x,h.x, fmaf(a0.y,h.y, fmaf(a0.z,h.z, fmaf(a0.w,h.w, s0))));
        s1 = fmaf(a1.x,h.x, fmaf(a1.y,h.y, fmaf(a1.z,h.z, fmaf(a1.w,h.w, s1))));
        s2 = fmaf(a2.x,h.x, fmaf(a2.y,h.y, fmaf(a2.z,h.z, fmaf(a2.w,h.w, s2))));
        s3 = fmaf(a3.x,h.x, fmaf(a3.y,h.y, fmaf(a3.z,h.z, fmaf(a3.w,h.w, s3))));
      }
      s0 += __shfl_xor(s0,1,64); s0 += __shfl_xor(s0,2,64);
      s1 += __shfl_xor(s1,1,64); s1 += __shfl_xor(s1,2,64);
      s2 += __shfl_xor(s2,1,64); s2 += __shfl_xor(s2,2,64);
      s3 += __shfl_xor(s3,1,64); s3 += __shfl_xor(s3,2,64);
      if(p==0){
        int m0 = A[(size_t)(r0+0)*n + j];
        int m1 = A[(size_t)(r0+1)*n + j];
        int m2 = A[(size_t)(r0+2)*n + j];
        int m3 = A[(size_t)(r0+3)*n + j];
        s0 = (m0>0) ? s0 : -1e9f;
        s1 = (m1>0) ? s1 : -1e9f;
        s2 = (m2>0) ? s2 : -1e9f;
        s3 = (m3>0) ? s3 : -1e9f;
        sc[0][j]=s0; sc[1][j]=s1; sc[2][j]=s2; sc[3][j]=s3;
        lm0=fmaxf(lm0,s0); lm1=fmaxf(lm1,s1); lm2=fmaxf(lm2,s2); lm3=fmaxf(lm3,s3);
      }
    }
  } else {
    for(int j=t; j<n; j+=256){
      float h0=Hn[(size_t)j*3+0], h1=Hn[(size_t)j*3+1], h2=Hn[(size_t)j*3+2];
      float s0 = hr[0][0]*h0 + hr[0][1]*h1 + hr[0][2]*h2;
      float s1 = hr[1][0]*h0 + hr[1][1]*h1 + hr[1][2]*h2;
      float s2 = hr[2][0]*h0 + hr[2][1]*h1 + hr[2][2]*h2;
      float s3 = hr[3][0]*h0 + hr[3][1]*h1 + hr[3][2]*h2;
      int m0 = A[(size_t)(r0+0)*n + j];
      int m1 = A[(size_t)(r0+1)*n + j];
      int m2 = A[(size_t)(r0+2)*n + j];
      int m3 = A[(size_t)(r0+3)*n + j];
      s0 = (m0>0) ? s0 : -1e9f;
      s1 = (m1>0) ? s1 : -1e9f;
      s2 = (m2>0) ? s2 : -1e9f;
      s3 = (m3>0) ? s3 : -1e9f;
      sc[0][j]=s0; sc[1][j]=s1; sc[2][j]=s2; sc[3][j]=s3;
      lm0=fmaxf(lm0,s0); lm1=fmaxf(lm1,s1); lm2=fmaxf(lm2,s2); lm3=fmaxf(lm3,s3);
    }
  }
  {
    float w0=waveReduceMax(lm0), w1=waveReduceMax(lm1), w2=waveReduceMax(lm2), w3=waveReduceMax(lm3);
    if(lane==0){ redm[0][w]=w0; redm[1][w]=w1; redm[2][w]=w2; redm[3][w]=w3; }
  }
  __syncthreads();
  float m[4];
  #pragma unroll
  for(int r=0;r<4;r++) m[r] = fmaxf(fmaxf(redm[r][0],redm[r][1]), fmaxf(redm[r][2],redm[r][3]));
  __syncthreads();
  float ls0=0.f, ls1=0.f, ls2=0.f, ls3=0.f;
  for(int j=t; j<n; j+=256){
    float e0=__expf(sc[0][j]-m[0]); sc[0][j]=e0; ls0+=e0;
    float e1=__expf(sc[1][j]-m[1]); sc[1][j]=e1; ls1+=e1;
    float e2=__expf(sc[2][j]-m[2]); sc[2][j]=e2; ls2+=e2;
    float e3=__expf(sc[3][j]-m[3]); sc[3][j]=e3; ls3+=e3;
  }
  {
    float w0=waveReduceSum(ls0), w1=waveReduceSum(ls1), w2=waveReduceSum(ls2), w3=waveReduceSum(ls3);
    if(lane==0){ redm[0][w]=w0; redm[1][w]=w1; redm[2][w]=w2; redm[3][w]=w3; }
  }
  __syncthreads();
  float S[4];
  #pragma unroll
  for(int r=0;r<4;r++) S[r] = redm[r][0]+redm[r][1]+redm[r][2]+redm[r][3];
  if(D==GH){
    float acc0=0.f, acc1=0.f, acc2=0.f, acc3=0.f;
    const int c = lane, part = w;
    #pragma unroll 2
    for(int j=part; j<n; j+=4){
      float hv = Hn[(size_t)j*GH + c];
      acc0 = fmaf(sc[0][j], hv, acc0);
      acc1 = fmaf(sc[1][j], hv, acc1);
      acc2 = fmaf(sc[2][j], hv, acc2);
      acc3 = fmaf(sc[3][j], hv, acc3);
    }
    outp[part][0][c]=acc0; outp[part][1][c]=acc1; outp[part][2][c]=acc2; outp[part][3][c]=acc3;
    __syncthreads();
    int r = w;
    float tot = outp[0][r][lane]+outp[1][r][lane]+outp[2][r][lane]+outp[3][r][lane];
    out[(size_t)(r0+r)*GH + lane] = fmaxf(tot/S[r], 0.f);
  } else {
    float a00=0,a01=0,a02=0, a10=0,a11=0,a12=0, a20=0,a21=0,a22=0, a30=0,a31=0,a32=0;
    for(int j=t; j<n; j+=256){
      float h0=Hn[(size_t)j*3+0], h1=Hn[(size_t)j*3+1], h2=Hn[(size_t)j*3+2];
      float e0=sc[0][j], e1=sc[1][j], e2=sc[2][j], e3=sc[3][j];
      a00=fmaf(e0,h0,a00); a01=fmaf(e0,h1,a01); a02=fmaf(e0,h2,a02);
      a10=fmaf(e1,h0,a10); a11=fmaf(e1,h1,a11); a12=fmaf(e1,h2,a12);
      a20=fmaf(e2,h0,a20); a21=fmaf(e2,h1,a21); a22=fmaf(e2,h2,a22);
      a30=fmaf(e3,h0,a30); a31=fmaf(e3,h1,a31); a32=fmaf(e3,h2,a32);
    }
    float v[12] = {a00,a01,a02,a10,a11,a12,a20,a21,a22,a30,a31,a32};
    #pragma unroll
    for(int i=0;i<12;i++){
      float ws = waveReduceSum(v[i]);
      if(lane==0) out3[w][i/3][i%3] = ws;
    }
    __syncthreads();
    if(t < 4){
      int r = t;
      float t0 = out3[0][r][0]+out3[1][r][0]+out3[2][r][0]+out3[3][r][0];
      float t1 = out3[0][r][1]+out3[1][r][1]+out3[2][r][1]+out3[3][r][1];
      float t2 = out3[0][r][2]+out3[1][r][2]+out3[2][r][2]+out3[3][r][2];
      float v0 = fmaxf(t0/S[r], 0.f);
      float v1 = fmaxf(t1/S[r], 0.f);
      float v2 = fmaxf(t2/S[r], 0.f);
      if(FINAL){
        float mm = fmaxf(v0, fmaxf(v1,v2));
        float e0=__expf(v0-mm), e1=__expf(v1-mm), e2=__expf(v2-mm);
        float ss = e0+e1+e2;
        out[(size_t)(r0+r)*3+0]=e0/ss; out[(size_t)(r0+r)*3+1]=e1/ss; out[(size_t)(r0+r)*3+2]=e2/ss;
      } else {
        out[(size_t)(r0+r)*3+0]=v0; out[(size_t)(r0+r)*3+1]=v1; out[(size_t)(r0+r)*3+2]=v2;
      }
    }
  }
}

// ---------- superpixel sums of fused (computed inline) via CSR gather ----------
__global__ __launch_bounds__(128) void k_spsum0(const int* __restrict__ seg1, const int* __restrict__ seg2,
                                                const float* __restrict__ S0, const float* __restrict__ S1, const float* __restrict__ S2,
                                                const float* __restrict__ cst,
                                                const int* __restrict__ offs, const int* __restrict__ cnt,
                                                const int* __restrict__ list, float* __restrict__ spsum){
  __shared__ float r[2][3];
  int s = blockIdx.x;
  int t = threadIdx.x, w = t>>6, lane = t&63;
  int n = cnt[s], st = offs[s];
  float w0=cst[0], w1=cst[1], w2=cst[2];
  float s00=w0*S0[s*3+0], s01=w0*S0[s*3+1], s02=w0*S0[s*3+2];
  float a0=0.f, a1=0.f, a2=0.f;
  for(int q=t; q<n; q+=128){
    int p = list[st+q];
    int b = seg1[p], c = seg2[p];
    a0 += s00 + w1*S1[b*3+0] + w2*S2[c*3+0];
    a1 += s01 + w1*S1[b*3+1] + w2*S2[c*3+1];
    a2 += s02 + w1*S1[b*3+2] + w2*S2[c*3+2];
  }
  a0 = waveReduceSum(a0); a1 = waveReduceSum(a1); a2 = waveReduceSum(a2);
  if(lane==0){ r[w][0]=a0; r[w][1]=a1; r[w][2]=a2; }
  __syncthreads();
  if(t==0){
    spsum[s*3+0]=r[0][0]+r[1][0];
    spsum[s*3+1]=r[0][1]+r[1][1];
    spsum[s*3+2]=r[0][2]+r[1][2];
  }
}

// ---------- PCR: smoothed_sp[r] = softmax(attn[r]) @ (spsum/cnt) ----------
__global__ __launch_bounds__(256) void k_pcr(const float* __restrict__ attn, const float* __restrict__ spsum,
                                             const int* __restrict__ cnt0, float* __restrict__ sm){
  __shared__ float buf[2048];
  __shared__ float red[4];
  __shared__ float r3[256][3];
  int r=blockIdx.x, t=threadIdx.x;
  float lmax=-INFINITY;
  for(int j=t;j<2000;j+=256){ float v=attn[(size_t)r*2000+j]; buf[j]=v; lmax=fmaxf(lmax,v); }
  float wm=waveReduceMax(lmax);
  if((t&63)==0) red[t>>6]=wm;
  __syncthreads();
  float m = fmaxf(fmaxf(red[0],red[1]),fmaxf(red[2],red[3]));
  __syncthreads();
  float lsum=0.f;
  for(int j=t;j<2000;j+=256){ float e=__expf(buf[j]-m); buf[j]=e; lsum+=e; }
  float wsu=waveReduceSum(lsum);
  if((t&63)==0) red[t>>6]=wsu;
  __syncthreads();
  float S=red[0]+red[1]+red[2]+red[3];
  float a0=0.f,a1=0.f,a2=0.f;
  for(int j=t;j<2000;j+=256){
    float e=buf[j];
    float inv = 1.f / fmaxf((float)cnt0[j], 1.f);
    a0=fmaf(e, spsum[j*3+0]*inv, a0);
    a1=fmaf(e, spsum[j*3+1]*inv, a1);
    a2=fmaf(e, spsum[j*3+2]*inv, a2);
  }
  r3[t][0]=a0; r3[t][1]=a1; r3[t][2]=a2;
  __syncthreads();
  for(int st=128;st>0;st>>=1){
    if(t<st){ r3[t][0]+=r3[t+st][0]; r3[t][1]+=r3[t+st][1]; r3[t][2]+=r3[t+st][2]; }
    __syncthreads();
  }
  if(t==0){ sm[r*3+0]=r3[0][0]/S; sm[r*3+1]=r3[0][1]/S; sm[r*3+2]=r3[0][2]/S; }
}

// ---------- MFMA MLP (156->128->128->156): 64 px/block, 512 threads (8 waves) ----------
// sflat fused into staging: computes Sf + ci in-kernel (no ci buffer).
#define MFMA(a,b,c) __builtin_amdgcn_mfma_f32_16x16x32_bf16((a),(b),(c),0,0,0)

__global__ __launch_bounds__(512, 4) void k_mlp_mfma(
    const float* __restrict__ Y,
    const int* __restrict__ seg0, const int* __restrict__ seg1, const int* __restrict__ seg2,
    const float* __restrict__ S0, const float* __restrict__ S1, const float* __restrict__ S2,
    const float* __restrict__ sm, const float* __restrict__ cst, float* __restrict__ Sf,
    const u16* __restrict__ P1h, const u16* __restrict__ P1l,
    const u16* __restrict__ P2h, const u16* __restrict__ P2l,
    const u16* __restrict__ P3h, const u16* __restrict__ P3l,
    const float* __restrict__ b1, const float* __restrict__ b2, const float* __restrict__ b3,
    float* __restrict__ gsum, float* __restrict__ gwsum){
  __shared__ u16 SH[64*168];                 // X-hi [64][168]  ->  A-hi [64][136]
  __shared__ u16 SL[64*168];                 // X-lo            ->  A-lo
  __shared__ float csum[480], cwsum[480];    // per-class sums [3][160]; unique writers
  __shared__ int cis[64];
  const int t = threadIdx.x;
  const int lane = t & 63, w = t >> 6;       // 8 waves
  const int g = lane >> 4, r16 = lane & 15;
  const size_t p0 = (size_t)blockIdx.x * 64;

  // inline sflat for this block's 64 pixels: Sf write + class index
  if(t < 64){
    size_t p = p0 + t;
    float a = cst[3];
    float w0=cst[0], w1=cst[1], w2=cst[2];
    int sa=seg0[p], sb=seg1[p], sc_=seg2[p];
    float f0 = w0*S0[sa*3+0] + w1*S1[sb*3+0] + w2*S2[sc_*3+0];
    float f1 = w0*S0[sa*3+1] + w1*S1[sb*3+1] + w2*S2[sc_*3+1];
    float f2 = w0*S0[sa*3+2] + w1*S1[sb*3+2] + w2*S2[sc_*3+2];
    float x0 = a*sm[sa*3+0] + (1.f-a)*f0;
    float x1 = a*sm[sa*3+1] + (1.f-a)*f1;
    float x2 = a*sm[sa*3+2] + (1.f-a)*f2;
    Sf[p*3+0]=x0; Sf[p*3+1]=x1; Sf[p*3+2]=x2;
    int c=0; float b=x0;
    if(x1>b){c=1;b=x1;}
    if(x2>b){c=2;}
    cis[t]=c;
  }
  // stage Y tile: 64 rows x 39 float4, packed bf16 hi/lo split
  for(int i=t;i<2496;i+=512){
    int row = i/39, q = i - row*39, c0 = q*4;
    float4 v = *(const float4*)(Y + (p0+row)*NB + c0);
    unsigned h01 = pkbf(v.x, v.y), h23 = pkbf(v.z, v.w);
    float l0 = v.x - __uint_as_float(h01 << 16);
    float l1 = v.y - __uint_as_float(h01 & 0xFFFF0000u);
    float l2 = v.z - __uint_as_float(h23 << 16);
    float l3 = v.w - __uint_as_float(h23 & 0xFFFF0000u);
    *(unsigned*)&SH[row*168+c0]   = h01;
    *(unsigned*)&SH[row*168+c0+2] = h23;
    *(unsigned*)&SL[row*168+c0]   = pkbf(l0, l1);
    *(unsigned*)&SL[row*168+c0+2] = pkbf(l2, l3);
  }
  if(t<128){ int row=t>>1, o=156+(t&1)*2;
    *(unsigned*)&SH[row*168+o]=0u; *(unsigned*)&SL[row*168+o]=0u; }
  __syncthreads();

  const int c12 = w*16 + r16;                // this wave's output column, layers 1/2

  // ---- layer 1: K=160 (5 ks), wave w -> ntile w, 4 m-tiles ----
  {
    f32x4 acc[4];
    #pragma unroll
    for(int mt=0;mt<4;mt++) acc[mt] = (f32x4){0.f,0.f,0.f,0.f};
    #pragma unroll
    for(int ks=0;ks<5;ks++){
      bfrag8 bh = *(const bfrag8*)(P1h + ((size_t)(w*5+ks))*512 + lane*8);
      bfrag8 bl = *(const bfrag8*)(P1l + ((size_t)(w*5+ks))*512 + lane*8);
      #pragma unroll
      for(int mt=0;mt<4;mt++){
        bfrag8 ah = *(const bfrag8*)(SH + (mt*16+r16)*168 + g*8 + ks*32);
        bfrag8 al = *(const bfrag8*)(SL + (mt*16+r16)*168 + g*8 + ks*32);
        acc[mt]=MFMA(ah,bh,acc[mt]); acc[mt]=MFMA(ah,bl,acc[mt]); acc[mt]=MFMA(al,bh,acc[mt]);
      }
    }
    __syncthreads();   // all waves done reading X
    float bv = b1[c12];
    #pragma unroll
    for(int mt=0;mt<4;mt++){
      float v0 = fmaxf(acc[mt][0] + bv, 0.f);
      float v1 = fmaxf(acc[mt][1] + bv, 0.f);
      float v2 = fmaxf(acc[mt][2] + bv, 0.f);
      float v3 = fmaxf(acc[mt][3] + bv, 0.f);
      unsigned h01 = pkbf(v0,v1), h23 = pkbf(v2,v3);
      float l0 = v0 - __uint_as_float(h01<<16);
      float l1 = v1 - __uint_as_float(h01 & 0xFFFF0000u);
      float l2 = v2 - __uint_as_float(h23<<16);
      float l3 = v3 - __uint_as_float(h23 & 0xFFFF0000u);
      unsigned q01 = pkbf(l0,l1), q23 = pkbf(l2,l3);
      int rb = (mt*16 + g*4)*136 + c12;
      SH[rb      ] = (u16)h01; SH[rb+136 ] = (u16)(h01>>16);
      SH[rb+272  ] = (u16)h23; SH[rb+408 ] = (u16)(h23>>16);
      SL[rb      ] = (u16)q01; SL[rb+136 ] = (u16)(q01>>16);
      SL[rb+272  ] = (u16)q23; SL[rb+408 ] = (u16)(q23>>16);
    }
  }
  __syncthreads();

  // ---- layer 2: K=128 (4 ks); regs across barrier, overwrite A ----
  {
    f32x4 acc[4];
    #pragma unroll
    for(int mt=0;mt<4;mt++) acc[mt] = (f32x4){0.f,0.f,0.f,0.f};
    #pragma unroll
    for(int ks=0;ks<4;ks++){
      bfrag8 bh = *(const bfrag8*)(P2h + ((size_t)(w*4+ks))*512 + lane*8);
      bfrag8 bl = *(const bfrag8*)(P2l + ((size_t)(w*4+ks))*512 + lane*8);
      #pragma unroll
      for(int mt=0;mt<4;mt++){
        bfrag8 ah = *(const bfrag8*)(SH + (mt*16+r16)*136 + g*8 + ks*32);
        bfrag8 al = *(const bfrag8*)(SL + (mt*16+r16)*136 + g*8 + ks*32);
        acc[mt]=MFMA(ah,bh,acc[mt]); acc[mt]=MFMA(ah,bl,acc[mt]); acc[mt]=MFMA(al,bh,acc[mt]);
      }
    }
    __syncthreads();   // all waves done reading A(layer1)
    float bv = b2[c12];
    #pragma unroll
    for(int mt=0;mt<4;mt++){
      float v0 = fmaxf(acc[mt][0] + bv, 0.f);
      float v1 = fmaxf(acc[mt][1] + bv, 0.f);
      float v2 = fmaxf(acc[mt][2] + bv, 0.f);
      float v3 = fmaxf(acc[mt][3] + bv, 0.f);
      unsigned h01 = pkbf(v0,v1), h23 = pkbf(v2,v3);
      float l0 = v0 - __uint_as_float(h01<<16);
      float l1 = v1 - __uint_as_float(h01 & 0xFFFF0000u);
      float l2 = v2 - __uint_as_float(h23<<16);
      float l3 = v3 - __uint_as_float(h23 & 0xFFFF0000u);
      unsigned q01 = pkbf(l0,l1), q23 = pkbf(l2,l3);
      int rb = (mt*16 + g*4)*136 + c12;
      SH[rb      ] = (u16)h01; SH[rb+136 ] = (u16)(h01>>16);
      SH[rb+272  ] = (u16)h23; SH[rb+408 ] = (u16)(h23>>16);
      SL[rb      ] = (u16)q01; SL[rb+136 ] = (u16)(q01>>16);
      SL[rb+272  ] = (u16)q23; SL[rb+408 ] = (u16)(q23>>16);
    }
  }
  __syncthreads();

  // ---- layer 3, phase A: primary ntile w (compute -> epilogue, acc fully consumed) ----
  {
    f32x4 acc[4];
    #pragma unroll
    for(int mt=0;mt<4;mt++) acc[mt] = (f32x4){0.f,0.f,0.f,0.f};
    #pragma unroll
    for(int ks=0;ks<4;ks++){
      bfrag8 bh = *(const bfrag8*)(P3h + ((size_t)(w*4+ks))*512 + lane*8);
      bfrag8 bl = *(const bfrag8*)(P3l + ((size_t)(w*4+ks))*512 + lane*8);
      #pragma unroll
      for(int mt=0;mt<4;mt++){
        bfrag8 ah = *(const bfrag8*)(SH + (mt*16+r16)*136 + g*8 + ks*32);
        bfrag8 al = *(const bfrag8*)(SL + (mt*16+r16)*136 + g*8 + ks*32);
        acc[mt]=MFMA(ah,bh,acc[mt]); acc[mt]=MFMA(ah,bl,acc[mt]); acc[mt]=MFMA(al,bh,acc[mt]);
      }
    }
    const int c = w*16 + r16;        // primary column, < 128
    float bv = b3[c];
    float cs0=0,cs1=0,cs2=0, cw0=0,cw1=0,cw2=0;
    #pragma unroll
    for(int mt=0;mt<4;mt++){
      #pragma unroll
      for(int r=0;r<4;r++){
        int p = mt*16 + g*4 + r;
        float e = __expf(acc[mt][r] + bv);
        float y = Y[(p0+p)*NB + c];
        float ey = e*y;
        int k = cis[p];
        cs0 += (k==0)?e:0.f;  cs1 += (k==1)?e:0.f;  cs2 += (k==2)?e:0.f;
        cw0 += (k==0)?ey:0.f; cw1 += (k==1)?ey:0.f; cw2 += (k==2)?ey:0.f;
      }
    }
    #define GRED(v) { v += __shfl_xor(v,16,64); v += __shfl_xor(v,32,64); }
    GRED(cs0) GRED(cs1) GRED(cs2) GRED(cw0) GRED(cw1) GRED(cw2)
    if(g==0){
      csum[c]       = cs0; csum[160+c]  = cs1; csum[320+c]  = cs2;
      cwsum[c]      = cw0; cwsum[160+c] = cw1; cwsum[320+c] = cw2;
    }
  }
  // ---- layer 3, phase B: secondary ntile 8+w (waves 0,1 only), fully after phase A ----
  if(w < 2){
    const int c2 = 128 + w*16 + r16;
    f32x4 acc2[4];
    #pragma unroll
    for(int mt=0;mt<4;mt++) acc2[mt] = (f32x4){0.f,0.f,0.f,0.f};
    #pragma unroll
    for(int ks=0;ks<4;ks++){
      bfrag8 bh = *(const bfrag8*)(P3h + ((size_t)((8+w)*4+ks))*512 + lane*8);
      bfrag8 bl = *(const bfrag8*)(P3l + ((size_t)((8+w)*4+ks))*512 + lane*8);
      #pragma unroll
      for(int mt=0;mt<4;mt++){
        bfrag8 ah = *(const bfrag8*)(SH + (mt*16+r16)*136 + g*8 + ks*32);
        bfrag8 al = *(const bfrag8*)(SL + (mt*16+r16)*136 + g*8 + ks*32);
        acc2[mt]=MFMA(ah,bh,acc2[mt]); acc2[mt]=MFMA(ah,bl,acc2[mt]); acc2[mt]=MFMA(al,bh,acc2[mt]);
      }
    }
    float ds0=0,ds1=0,ds2=0, dw0=0,dw1=0,dw2=0;
    if(c2 < 156){
      float bv2 = b3[c2];
      #pragma unroll
      for(int mt=0;mt<4;mt++){
        #pragma unroll
        for(int r=0;r<4;r++){
          int p = mt*16 + g*4 + r;
          float e = __expf(acc2[mt][r] + bv2);
          float y = Y[(p0+p)*NB + c2];
          float ey = e*y;
          int k = cis[p];
          ds0 += (k==0)?e:0.f;  ds1 += (k==1)?e:0.f;  ds2 += (k==2)?e:0.f;
          dw0 += (k==0)?ey:0.f; dw1 += (k==1)?ey:0.f; dw2 += (k==2)?ey:0.f;
        }
      }
    }
    GRED(ds0) GRED(ds1) GRED(ds2) GRED(dw0) GRED(dw1) GRED(dw2)
    #undef GRED
    if(g==0 && c2 < 156){
      csum[c2]       = ds0; csum[160+c2]  = ds1; csum[320+c2]  = ds2;
      cwsum[c2]      = dw0; cwsum[160+c2] = dw1; cwsum[320+c2] = dw2;
    }
  }
  __syncthreads();
  // flush to 256 rotation slots (skip unwritten cols 156..159 of each class)
  float* gs = gsum  + (size_t)(blockIdx.x & 255)*480;
  float* gw = gwsum + (size_t)(blockIdx.x & 255)*480;
  for(int i=t;i<480;i+=512){
    if((i % 160) < 156){
      atomicAdd(&gs[i], csum[i]);
      atomicAdd(&gw[i], cwsum[i]);
    }
  }
}

// ---------- final M: one block per (cls,c), 256 threads = 256 slots ----------
__global__ __launch_bounds__(256) void k_finalM(const float* __restrict__ gsump, const float* __restrict__ gwsump,
                                                float* __restrict__ M){
  __shared__ float rs[4], rw[4];
  int e = blockIdx.x;                 // 0..467
  int cls = e/156, c = e - cls*156;
  int off = cls*160 + c;
  int t = threadIdx.x, w = t>>6, lane = t&63;
  float s  = gsump[(size_t)t*480 + off];
  float wv = gwsump[(size_t)t*480 + off];
  s = waveReduceSum(s); wv = waveReduceSum(wv);
  if(lane==0){ rs[w]=s; rw[w]=wv; }
  __syncthreads();
  if(t==0){
    float S = rs[0]+rs[1]+rs[2]+rs[3];
    float W = rw[0]+rw[1]+rw[2]+rw[3];
    M[e] = (S > 0.f) ? (W / fmaxf(S, 1e-30f)) : 0.f;
  }
}

// ---------- Y_hat = S_flat @ M, float4 stores ----------
__global__ void k_yhat4(const float* __restrict__ Sf, const float* __restrict__ M, float4* __restrict__ out){
  unsigned idx = blockIdx.x*256u + threadIdx.x;   // N_PIX*39 float4s, grid exact
  unsigned p = idx / 39u, q = idx - p*39u;
  unsigned c0 = q*4u;
  float4 m0 = *(const float4*)(M + c0);
  float4 m1 = *(const float4*)(M + 156 + c0);
  float4 m2 = *(const float4*)(M + 312 + c0);
  float s0 = Sf[(size_t)p*3+0], s1 = Sf[(size_t)p*3+1], s2 = Sf[(size_t)p*3+2];
  float4 r;
  r.x = s0*m0.x + s1*m1.x + s2*m2.x;
  r.y = s0*m0.y + s1*m1.y + s2*m2.y;
  r.z = s0*m0.z + s1*m1.z + s2*m2.z;
  r.w = s0*m0.w + s1*m1.w + s2*m2.w;
  out[idx] = r;
}

extern "C" void kernel_launch(void* const* d_in, const int* in_sizes, int n_in,
                              void* d_out, int out_size, void* d_ws, size_t ws_size,
                              hipStream_t stream){
  const float* Y    = (const float*)d_in[0];
  const int*   seg0 = (const int*)d_in[1];
  const int*   A0   = (const int*)d_in[2];
  const int*   seg1 = (const int*)d_in[3];
  const int*   A1   = (const int*)d_in[4];
  const int*   seg2 = (const int*)d_in[5];
  const int*   A2   = (const int*)d_in[6];
  const float* attn = (const float*)d_in[7];
  const float* alpha= (const float*)d_in[8];
  const float* sw   = (const float*)d_in[9];
  const float* W1a[3] = {(const float*)d_in[10], (const float*)d_in[14], (const float*)d_in[18]};
  const float* b1a[3] = {(const float*)d_in[11], (const float*)d_in[15], (const float*)d_in[19]};
  const float* W2a[3] = {(const float*)d_in[12], (const float*)d_in[16], (const float*)d_in[20]};
  const float* b2a[3] = {(const float*)d_in[13], (const float*)d_in[17], (const float*)d_in[21]};
  const float* Wm1=(const float*)d_in[22]; const float* bm1=(const float*)d_in[23];
  const float* Wm2=(const float*)d_in[24]; const float* bm2=(const float*)d_in[25];
  const float* Wm3=(const float*)d_in[26]; const float* bm3=(const float*)d_in[27];
  float* out = (float*)d_out;

  char* base = (char*)d_ws;
  size_t off = 0;
  auto alloc = [&](size_t bytes)->char*{
    char* r = base + off;
    off += (bytes + 255) & ~(size_t)255;
    return r;
  };
  int* cntAll = (int*)alloc((size_t)3500*4);
  int* cnt[3] = {cntAll, cntAll+2000, cntAll+3000};
  int* offs[3]; int* cur[3]; int* lst[3];
  for(int i=0;i<3;i++) offs[i] = (int*)alloc((size_t)(i==0?2000:(i==1?1000:500))*4);
  for(int i=0;i<3;i++) cur[i]  = (int*)alloc((size_t)(i==0?2000:(i==1?1000:500))*4);
  for(int i=0;i<3;i++) lst[i]  = (int*)alloc((size_t)N_PIX*4);
  float* X_all   = (float*)alloc((size_t)3500*NB*4);
  float* Hn_all  = (float*)alloc((size_t)3500*64*4);
  float* x1b_all = (float*)alloc((size_t)3500*64*4);
  float* Hn2_all = (float*)alloc((size_t)3500*3*4);
  float* Ss_all  = (float*)alloc((size_t)3500*3*4);
  float* cst   = (float*)alloc(64);
  float* spsum = (float*)alloc((size_t)2000*3*4);
  float* smth  = (float*)alloc((size_t)2000*3*4);
  float* Sf    = (float*)alloc((size_t)N_PIX*3*4);
  u16* P1h = (u16*)alloc((size_t)20480*2); u16* P1l = (u16*)alloc((size_t)20480*2);
  u16* P2h = (u16*)alloc((size_t)16384*2); u16* P2l = (u16*)alloc((size_t)16384*2);
  u16* P3h = (u16*)alloc((size_t)20480*2); u16* P3l = (u16*)alloc((size_t)20480*2);
  float* gsump  = (float*)alloc((size_t)256*480*4);
  float* gwsump = (float*)alloc((size_t)256*480*4);
  float* Mbuf   = (float*)alloc((size_t)480*4);

  float* X0 = X_all;            float* X1 = X_all + (size_t)2000*NB;   float* X2 = X_all + (size_t)3000*NB;
  const float* Ss0 = Ss_all;    const float* Ss1 = Ss_all + 2000*3;    const float* Ss2 = Ss_all + 3000*3;

  // per-call re-init (replay/poison safe)
  hipMemsetAsync(cntAll, 0, (size_t)3500*4, stream);
  hipMemsetAsync(gsump, 0, (size_t)256*480*4, stream);
  hipMemsetAsync(gwsump, 0, (size_t)256*480*4, stream);

  // merged prep + weight pre-pack (1 + 80 + 64 + 80 = 225 blocks)
  k_prep_pack<<<225,256,0,stream>>>(sw, alpha, cst, Wm1, Wm2, Wm3, P1h,P1l,P2h,P2l,P3h,P3l);

  // CSR + segment means
  k_count<<<N_PIX/256,256,0,stream>>>(seg0,seg1,seg2,cnt[0],cnt[1],cnt[2]);
  k_scan<<<3,256,0,stream>>>(cnt[0],cnt[1],cnt[2],offs[0],offs[1],offs[2],cur[0],cur[1],cur[2]);
  k_fill<<<N_PIX/256,256,0,stream>>>(seg0,seg1,seg2,cur[0],cur[1],cur[2],lst[0],lst[1],lst[2]);
  k_segmean3<<<3500,192,0,stream>>>(Y,
      offs[0],cnt[0],lst[0],X0,
      offs[1],cnt[1],lst[1],X1,
      offs[2],cnt[2],lst[2],X2);

  // Multi-scale GAT encoder (batched: 4 launches total)
  k_linearB<<<(3500*64+255)/256,256,0,stream>>>(X_all, NB, 64,
      W1a[0],b1a[0],W1a[1],b1a[1],W1a[2],b1a[2], Hn_all);
  k_attn4B<64,false><<<875,256,0,stream>>>(Hn_all, A0,A1,A2, x1b_all);
  k_linearB<<<(3500*3+255)/256,256,0,stream>>>(x1b_all, 64, 3,
      W2a[0],b2a[0],W2a[1],b2a[1],W2a[2],b2a[2], Hn2_all);
  k_attn4B<3,true><<<875,256,0,stream>>>(Hn2_all, A0,A1,A2, Ss_all);

  // spsum (fused inline) + PCR
  k_spsum0<<<2000,128,0,stream>>>(seg1, seg2, Ss0, Ss1, Ss2, cst, offs[0], cnt[0], lst[0], spsum);
  k_pcr<<<2000,256,0,stream>>>(attn, spsum, cnt[0], smth);

  // ACDE: MFMA MLP (64 px/block) with sflat fused into staging
  k_mlp_mfma<<<N_PIX/64,512,0,stream>>>(Y, seg0, seg1, seg2, Ss0, Ss1, Ss2, smth, cst, Sf,
                                        P1h,P1l,P2h,P2l,P3h,P3l, bm1,bm2,bm3, gsump, gwsump);
  k_finalM<<<468,256,0,stream>>>(gsump, gwsump, Mbuf);
  k_yhat4<<<(N_PIX/256)*39,256,0,stream>>>(Sf, Mbuf, (float4*)out);
  (void)in_sizes; (void)n_in; (void)out_size;
}

// Round 16
// 690.665 us; speedup vs baseline: 2.1427x; 1.0128x over previous
//
#include <hip/hip_runtime.h>
#include <hip/hip_bf16.h>
#include <math.h>

#define N_PIX (512*512)
#define NB 156
#define GH 64
#define XS 172          // X staging row stride (u16) — 16-bank pattern
#define AS 140          // A (hidden) row stride (u16) — 16-bank pattern

typedef unsigned short u16;
typedef __attribute__((ext_vector_type(8))) short bfrag8;   // 8 bf16 = 4 VGPRs
typedef __attribute__((ext_vector_type(4))) float f32x4;    // MFMA accumulator

// ---------- bf16 helpers ----------
__device__ __forceinline__ u16 f2bf(float x){
  unsigned u = __float_as_uint(x);
  unsigned r = (u + 0x7FFFu + ((u >> 16) & 1u)) >> 16;
  return (u16)r;
}
__device__ __forceinline__ float bf2f(u16 h){
  return __uint_as_float(((unsigned)h) << 16);
}
// packed RNE: low 16 = bf16(a), high 16 = bf16(b)  (v_cvt_pk_bf16_f32)
__device__ __forceinline__ unsigned pkbf(float a, float b){
  __hip_bfloat162 h = __float22bfloat162_rn(make_float2(a,b));
  unsigned u; __builtin_memcpy(&u,&h,4); return u;
}

__device__ __forceinline__ float waveReduceMax(float v){
  #pragma unroll
  for(int o=32;o>0;o>>=1) v = fmaxf(v, __shfl_down(v, o, 64));
  return v;
}
__device__ __forceinline__ float waveReduceSum(float v){
  #pragma unroll
  for(int o=32;o>0;o>>=1) v += __shfl_down(v, o, 64);
  return v;
}

// ---------- merged: constants + weight pre-pack + buffer zeroing ----------
// blocks 0..224: prep+pack; 225..1184: zero gsump/gwsump; 1185..1198: zero cntAll
__global__ void k_prep_pack(const float* __restrict__ sw, const float* __restrict__ alpha, float* __restrict__ cst,
                            const float* __restrict__ Wm1, const float* __restrict__ Wm2, const float* __restrict__ Wm3,
                            u16* __restrict__ P1h, u16* __restrict__ P1l,
                            u16* __restrict__ P2h, u16* __restrict__ P2l,
                            u16* __restrict__ P3h, u16* __restrict__ P3l,
                            float* __restrict__ gsump, float* __restrict__ gwsump, int* __restrict__ cntAll){
  int b = blockIdx.x;
  if(b >= 1185){
    int i = (b-1185)*256 + threadIdx.x;
    if(i < 3500) cntAll[i] = 0;
    return;
  }
  if(b >= 225){
    int i = (b-225)*256 + threadIdx.x;   // 0 .. 245759
    gsump[i] = 0.f;
    gwsump[i] = 0.f;
    return;
  }
  if(b == 0){
    if(threadIdx.x == 0){
      float m = fmaxf(sw[0], fmaxf(sw[1], sw[2]));
      float e0=expf(sw[0]-m), e1=expf(sw[1]-m), e2=expf(sw[2]-m);
      float s = e0+e1+e2;
      cst[0]=e0/s; cst[1]=e1/s; cst[2]=e2/s;
      cst[3]=fminf(fmaxf(alpha[0],0.f),1.f);
    }
    return;
  }
  int pb = b - 1;
  const float* W; u16 *dh, *dl; int Kr, Nr, nkt, base;
  if(pb < 80){      W=Wm1; dh=P1h; dl=P1l; Kr=156; Nr=128; nkt=5; base=pb; }
  else if(pb<144){  W=Wm2; dh=P2h; dl=P2l; Kr=128; Nr=128; nkt=4; base=pb-80; }
  else {            W=Wm3; dh=P3h; dl=P3l; Kr=128; Nr=156; nkt=4; base=pb-144; }
  int gid = base*256 + threadIdx.x;
  int j = gid & 7, l = (gid>>3)&63;
  int rem = gid >> 9;               // nt*nkt + ks
  int ks = rem % nkt;
  int nt = rem / nkt;
  int k = ks*32 + (l>>4)*8 + j;
  int n = nt*16 + (l&15);
  float w = (k < Kr && n < Nr) ? W[(size_t)k*Nr + n] : 0.f;
  u16 hi = f2bf(w);
  dh[gid] = hi;
  dl[gid] = f2bf(w - bf2f(hi));
}

// ---------- CSR build ----------
__global__ void k_count(const int* __restrict__ s0, const int* __restrict__ s1, const int* __restrict__ s2,
                        int* c0, int* c1, int* c2){
  int p = blockIdx.x*256 + threadIdx.x;
  if(p < N_PIX){
    atomicAdd(&c0[s0[p]],1);
    atomicAdd(&c1[s1[p]],1);
    atomicAdd(&c2[s2[p]],1);
  }
}

__global__ __launch_bounds__(256) void k_scan(const int* __restrict__ c0, const int* __restrict__ c1, const int* __restrict__ c2,
                       int* o0, int* o1, int* o2, int* u0, int* u1, int* u2){
  const int* cnt; int* offs; int* cur; int n;
  if(blockIdx.x==0){ cnt=c0; offs=o0; cur=u0; n=2000; }
  else if(blockIdx.x==1){ cnt=c1; offs=o1; cur=u1; n=1000; }
  else { cnt=c2; offs=o2; cur=u2; n=500; }
  __shared__ int l[2048];
  __shared__ int cs[256];
  int t = threadIdx.x;
  for(int i=t;i<2048;i+=256) l[i] = (i<n) ? cnt[i] : 0;
  __syncthreads();
  int s = 0;
  #pragma unroll
  for(int j=0;j<8;j++) s += l[t*8+j];
  cs[t] = s;
  __syncthreads();
  for(int d=1; d<256; d<<=1){
    int v = (t>=d) ? cs[t-d] : 0;
    __syncthreads();
    cs[t] += v;
    __syncthreads();
  }
  int run = cs[t] - s;
  for(int j=0;j<8;j++){
    int idx = t*8+j;
    int o = run;
    run += l[idx];
    if(idx < n){ offs[idx] = o; cur[idx] = o; }
  }
}

__global__ void k_fill(const int* __restrict__ s0, const int* __restrict__ s1, const int* __restrict__ s2,
                       int* u0, int* u1, int* u2, int* L0, int* L1, int* L2){
  int p = blockIdx.x*256 + threadIdx.x;
  if(p < N_PIX){
    int a = atomicAdd(&u0[s0[p]],1); L0[a] = p;
    int b = atomicAdd(&u1[s1[p]],1); L1[b] = p;
    int c = atomicAdd(&u2[s2[p]],1); L2[c] = p;
  }
}

// ---------- fused segment mean over all 3 scales: 192 thr, 2 pixel-groups of 78 lanes ----------
__global__ __launch_bounds__(192) void k_segmean3(const float* __restrict__ Y,
    const int* __restrict__ o0, const int* __restrict__ c0, const int* __restrict__ l0, float* __restrict__ X0,
    const int* __restrict__ o1, const int* __restrict__ c1, const int* __restrict__ l1, float* __restrict__ X1,
    const int* __restrict__ o2, const int* __restrict__ c2, const int* __restrict__ l2, float* __restrict__ X2){
  int b = blockIdx.x;
  const int *offs, *cnt, *list; float* X; int s;
  if(b < 2000){ s=b;      offs=o0; cnt=c0; list=l0; X=X0; }
  else if(b < 3000){ s=b-2000; offs=o1; cnt=c1; list=l1; X=X1; }
  else { s=b-3000; offs=o2; cnt=c2; list=l2; X=X2; }
  __shared__ float part[156];
  int t = threadIdx.x;
  int grp = t / 96, tb = t - grp*96;
  int n = cnt[s], st = offs[s];
  float ax=0.f, ay=0.f;
  if(tb < 78){
    int q = grp;
    for(; q+6<n; q+=8){
      int p0 = list[st+q], p1 = list[st+q+2], p2 = list[st+q+4], p3 = list[st+q+6];
      float2 v0 = *(const float2*)(Y + (size_t)p0*NB + tb*2);
      float2 v1 = *(const float2*)(Y + (size_t)p1*NB + tb*2);
      float2 v2 = *(const float2*)(Y + (size_t)p2*NB + tb*2);
      float2 v3 = *(const float2*)(Y + (size_t)p3*NB + tb*2);
      ax += (v0.x + v1.x) + (v2.x + v3.x);
      ay += (v0.y + v1.y) + (v2.y + v3.y);
    }
    for(; q<n; q+=2){
      int p0 = list[st+q];
      float2 v0 = *(const float2*)(Y + (size_t)p0*NB + tb*2);
      ax += v0.x; ay += v0.y;
    }
  }
  if(grp==1 && tb<78){ part[tb*2]=ax; part[tb*2+1]=ay; }
  __syncthreads();
  if(grp==0 && tb<78){
    float inv = 1.f / fmaxf((float)n, 1.f);
    float2 r; r.x = (ax + part[tb*2])*inv; r.y = (ay + part[tb*2+1])*inv;
    *(float2*)(X + (size_t)s*NB + tb*2) = r;
  }
}

// ---------- batched small linear over all 3 scales (rows 0..3499) ----------
__global__ void k_linearB(const float* __restrict__ X, int K, int D,
                          const float* __restrict__ W0, const float* __restrict__ bb0,
                          const float* __restrict__ W1, const float* __restrict__ bb1,
                          const float* __restrict__ W2, const float* __restrict__ bb2,
                          float* __restrict__ out){
  int gid = blockIdx.x*256 + threadIdx.x;
  if(gid >= 3500*D) return;
  int r = gid / D, c = gid - r*D;
  const float* W; const float* bb;
  if(r < 2000){ W=W0; bb=bb0; }
  else if(r < 3000){ W=W1; bb=bb1; }
  else { W=W2; bb=bb2; }
  const float* xr = X + (size_t)r*K;
  float acc = bb[c];
  for(int k=0;k<K;k++) acc = fmaf(xr[k], W[(size_t)k*D + c], acc);
  out[gid] = acc;
}

// ---------- batched GAT masked attention, 4 rows per block, all 3 scales ----------
template<int D, bool FINAL>
__global__ __launch_bounds__(256) void k_attn4B(const float* __restrict__ HnAll,
                                                const int* __restrict__ A0, const int* __restrict__ A1, const int* __restrict__ A2,
                                                float* __restrict__ outAll){
  __shared__ float sc[4][2048];
  __shared__ float hr[4][GH];
  __shared__ float redm[4][4];
  __shared__ float outp[4][4][GH];   // part, r, c (D==64)
  __shared__ float out3[4][4][4];    // wave, r, c (D==3)
  const int t = threadIdx.x, w = t>>6, lane = t&63;
  int b = blockIdx.x;
  int n, r0; size_t base; const int* A;
  if(b < 500){ n=2000; base=0;    r0=b*4;        A=A0; }
  else if(b < 750){ n=1000; base=2000; r0=(b-500)*4; A=A1; }
  else { n=500;  base=3000; r0=(b-750)*4; A=A2; }
  const int OD = FINAL ? 3 : (D==GH ? GH : 3);
  const float* Hn = HnAll + base*D;
  float* out = outAll + base*OD;
  if(D==GH){
    hr[w][lane] = Hn[(size_t)(r0 + w)*GH + lane];
  } else {
    if(t < 12) hr[t/3][t%3] = Hn[(size_t)(r0 + t/3)*3 + (t%3)];
  }
  __syncthreads();
  float lm0=-INFINITY, lm1=-INFINITY, lm2=-INFINITY, lm3=-INFINITY;
  if(D==GH){
    const int p = t & 3;
    for(int j = t>>2; j < n; j += 64){
      const float* hj = Hn + (size_t)j*GH;
      float s0=0.f,s1=0.f,s2=0.f,s3=0.f;
      #pragma unroll
      for(int k4=0;k4<4;k4++){
        float4 h  = *(const float4*)(hj + k4*16 + p*4);
        float4 a0 = *(const float4*)&hr[0][k4*16 + p*4];
        float4 a1 = *(const float4*)&hr[1][k4*16 + p*4];
        float4 a2 = *(const float4*)&hr[2][k4*16 + p*4];
        float4 a3 = *(const float4*)&hr[3][k4*16 + p*4];
        s0 = fmaf(a0.x,h.x, fmaf(a0.y,h.y, fmaf(a0.z,h.z, fmaf(a0.w,h.w, s0))));
        s1 = fmaf(a1.x,h.x, fmaf(a1.y,h.y, fmaf(a1.z,h.z, fmaf(a1.w,h.w, s1))));
        s2 = fmaf(a2.x,h.x, fmaf(a2.y,h.y, fmaf(a2.z,h.z, fmaf(a2.w,h.w, s2))));
        s3 = fmaf(a3.x,h.x, fmaf(a3.y,h.y, fmaf(a3.z,h.z, fmaf(a3.w,h.w, s3))));
      }
      s0 += __shfl_xor(s0,1,64); s0 += __shfl_xor(s0,2,64);
      s1 += __shfl_xor(s1,1,64); s1 += __shfl_xor(s1,2,64);
      s2 += __shfl_xor(s2,1,64); s2 += __shfl_xor(s2,2,64);
      s3 += __shfl_xor(s3,1,64); s3 += __shfl_xor(s3,2,64);
      if(p==0){
        int m0 = A[(size_t)(r0+0)*n + j];
        int m1 = A[(size_t)(r0+1)*n + j];
        int m2 = A[(size_t)(r0+2)*n + j];
        int m3 = A[(size_t)(r0+3)*n + j];
        s0 = (m0>0) ? s0 : -1e9f;
        s1 = (m1>0) ? s1 : -1e9f;
        s2 = (m2>0) ? s2 : -1e9f;
        s3 = (m3>0) ? s3 : -1e9f;
        sc[0][j]=s0; sc[1][j]=s1; sc[2][j]=s2; sc[3][j]=s3;
        lm0=fmaxf(lm0,s0); lm1=fmaxf(lm1,s1); lm2=fmaxf(lm2,s2); lm3=fmaxf(lm3,s3);
      }
    }
  } else {
    for(int j=t; j<n; j+=256){
      float h0=Hn[(size_t)j*3+0], h1=Hn[(size_t)j*3+1], h2=Hn[(size_t)j*3+2];
      float s0 = hr[0][0]*h0 + hr[0][1]*h1 + hr[0][2]*h2;
      float s1 = hr[1][0]*h0 + hr[1][1]*h1 + hr[1][2]*h2;
      float s2 = hr[2][0]*h0 + hr[2][1]*h1 + hr[2][2]*h2;
      float s3 = hr[3][0]*h0 + hr[3][1]*h1 + hr[3][2]*h2;
      int m0 = A[(size_t)(r0+0)*n + j];
      int m1 = A[(size_t)(r0+1)*n + j];
      int m2 = A[(size_t)(r0+2)*n + j];
      int m3 = A[(size_t)(r0+3)*n + j];
      s0 = (m0>0) ? s0 : -1e9f;
      s1 = (m1>0) ? s1 : -1e9f;
      s2 = (m2>0) ? s2 : -1e9f;
      s3 = (m3>0) ? s3 : -1e9f;
      sc[0][j]=s0; sc[1][j]=s1; sc[2][j]=s2; sc[3][j]=s3;
      lm0=fmaxf(lm0,s0); lm1=fmaxf(lm1,s1); lm2=fmaxf(lm2,s2); lm3=fmaxf(lm3,s3);
    }
  }
  {
    float w0=waveReduceMax(lm0), w1=waveReduceMax(lm1), w2=waveReduceMax(lm2), w3=waveReduceMax(lm3);
    if(lane==0){ redm[0][w]=w0; redm[1][w]=w1; redm[2][w]=w2; redm[3][w]=w3; }
  }
  __syncthreads();
  float m[4];
  #pragma unroll
  for(int r=0;r<4;r++) m[r] = fmaxf(fmaxf(redm[r][0],redm[r][1]), fmaxf(redm[r][2],redm[r][3]));
  __syncthreads();
  float ls0=0.f, ls1=0.f, ls2=0.f, ls3=0.f;
  for(int j=t; j<n; j+=256){
    float e0=__expf(sc[0][j]-m[0]); sc[0][j]=e0; ls0+=e0;
    float e1=__expf(sc[1][j]-m[1]); sc[1][j]=e1; ls1+=e1;
    float e2=__expf(sc[2][j]-m[2]); sc[2][j]=e2; ls2+=e2;
    float e3=__expf(sc[3][j]-m[3]); sc[3][j]=e3; ls3+=e3;
  }
  {
    float w0=waveReduceSum(ls0), w1=waveReduceSum(ls1), w2=waveReduceSum(ls2), w3=waveReduceSum(ls3);
    if(lane==0){ redm[0][w]=w0; redm[1][w]=w1; redm[2][w]=w2; redm[3][w]=w3; }
  }
  __syncthreads();
  float S[4];
  #pragma unroll
  for(int r=0;r<4;r++) S[r] = redm[r][0]+redm[r][1]+redm[r][2]+redm[r][3];
  if(D==GH){
    float acc0=0.f, acc1=0.f, acc2=0.f, acc3=0.f;
    const int c = lane, part = w;
    #pragma unroll 2
    for(int j=part; j<n; j+=4){
      float hv = Hn[(size_t)j*GH + c];
      acc0 = fmaf(sc[0][j], hv, acc0);
      acc1 = fmaf(sc[1][j], hv, acc1);
      acc2 = fmaf(sc[2][j], hv, acc2);
      acc3 = fmaf(sc[3][j], hv, acc3);
    }
    outp[part][0][c]=acc0; outp[part][1][c]=acc1; outp[part][2][c]=acc2; outp[part][3][c]=acc3;
    __syncthreads();
    int r = w;
    float tot = outp[0][r][lane]+outp[1][r][lane]+outp[2][r][lane]+outp[3][r][lane];
    out[(size_t)(r0+r)*GH + lane] = fmaxf(tot/S[r], 0.f);
  } else {
    float a00=0,a01=0,a02=0, a10=0,a11=0,a12=0, a20=0,a21=0,a22=0, a30=0,a31=0,a32=0;
    for(int j=t; j<n; j+=256){
      float h0=Hn[(size_t)j*3+0], h1=Hn[(size_t)j*3+1], h2=Hn[(size_t)j*3+2];
      float e0=sc[0][j], e1=sc[1][j], e2=sc[2][j], e3=sc[3][j];
      a00=fmaf(e0,h0,a00); a01=fmaf(e0,h1,a01); a02=fmaf(e0,h2,a02);
      a10=fmaf(e1,h0,a10); a11=fmaf(e1,h1,a11); a12=fmaf(e1,h2,a12);
      a20=fmaf(e2,h0,a20); a21=fmaf(e2,h1,a21); a22=fmaf(e2,h2,a22);
      a30=fmaf(e3,h0,a30); a31=fmaf(e3,h1,a31); a32=fmaf(e3,h2,a32);
    }
    float v[12] = {a00,a01,a02,a10,a11,a12,a20,a21,a22,a30,a31,a32};
    #pragma unroll
    for(int i=0;i<12;i++){
      float ws = waveReduceSum(v[i]);
      if(lane==0) out3[w][i/3][i%3] = ws;
    }
    __syncthreads();
    if(t < 4){
      int r = t;
      float t0 = out3[0][r][0]+out3[1][r][0]+out3[2][r][0]+out3[3][r][0];
      float t1 = out3[0][r][1]+out3[1][r][1]+out3[2][r][1]+out3[3][r][1];
      float t2 = out3[0][r][2]+out3[1][r][2]+out3[2][r][2]+out3[3][r][2];
      float v0 = fmaxf(t0/S[r], 0.f);
      float v1 = fmaxf(t1/S[r], 0.f);
      float v2 = fmaxf(t2/S[r], 0.f);
      if(FINAL){
        float mm = fmaxf(v0, fmaxf(v1,v2));
        float e0=__expf(v0-mm), e1=__expf(v1-mm), e2=__expf(v2-mm);
        float ss = e0+e1+e2;
        out[(size_t)(r0+r)*3+0]=e0/ss; out[(size_t)(r0+r)*3+1]=e1/ss; out[(size_t)(r0+r)*3+2]=e2/ss;
      } else {
        out[(size_t)(r0+r)*3+0]=v0; out[(size_t)(r0+r)*3+1]=v1; out[(size_t)(r0+r)*3+2]=v2;
      }
    }
  }
}

// ---------- superpixel sums of fused (computed inline) via CSR gather ----------
__global__ __launch_bounds__(128) void k_spsum0(const int* __restrict__ seg1, const int* __restrict__ seg2,
                                                const float* __restrict__ S0, const float* __restrict__ S1, const float* __restrict__ S2,
                                                const float* __restrict__ cst,
                                                const int* __restrict__ offs, const int* __restrict__ cnt,
                                                const int* __restrict__ list, float* __restrict__ spsum){
  __shared__ float r[2][3];
  int s = blockIdx.x;
  int t = threadIdx.x, w = t>>6, lane = t&63;
  int n = cnt[s], st = offs[s];
  float w0=cst[0], w1=cst[1], w2=cst[2];
  float s00=w0*S0[s*3+0], s01=w0*S0[s*3+1], s02=w0*S0[s*3+2];
  float a0=0.f, a1=0.f, a2=0.f;
  for(int q=t; q<n; q+=128){
    int p = list[st+q];
    int b = seg1[p], c = seg2[p];
    a0 += s00 + w1*S1[b*3+0] + w2*S2[c*3+0];
    a1 += s01 + w1*S1[b*3+1] + w2*S2[c*3+1];
    a2 += s02 + w1*S1[b*3+2] + w2*S2[c*3+2];
  }
  a0 = waveReduceSum(a0); a1 = waveReduceSum(a1); a2 = waveReduceSum(a2);
  if(lane==0){ r[w][0]=a0; r[w][1]=a1; r[w][2]=a2; }
  __syncthreads();
  if(t==0){
    spsum[s*3+0]=r[0][0]+r[1][0];
    spsum[s*3+1]=r[0][1]+r[1][1];
    spsum[s*3+2]=r[0][2]+r[1][2];
  }
}

// ---------- PCR: smoothed_sp[r] = softmax(attn[r]) @ (spsum/cnt) ----------
__global__ __launch_bounds__(256) void k_pcr(const float* __restrict__ attn, const float* __restrict__ spsum,
                                             const int* __restrict__ cnt0, float* __restrict__ sm){
  __shared__ float buf[2048];
  __shared__ float red[4];
  __shared__ float r3[256][3];
  int r=blockIdx.x, t=threadIdx.x;
  float lmax=-INFINITY;
  for(int j=t;j<2000;j+=256){ float v=attn[(size_t)r*2000+j]; buf[j]=v; lmax=fmaxf(lmax,v); }
  float wm=waveReduceMax(lmax);
  if((t&63)==0) red[t>>6]=wm;
  __syncthreads();
  float m = fmaxf(fmaxf(red[0],red[1]),fmaxf(red[2],red[3]));
  __syncthreads();
  float lsum=0.f;
  for(int j=t;j<2000;j+=256){ float e=__expf(buf[j]-m); buf[j]=e; lsum+=e; }
  float wsu=waveReduceSum(lsum);
  if((t&63)==0) red[t>>6]=wsu;
  __syncthreads();
  float S=red[0]+red[1]+red[2]+red[3];
  float a0=0.f,a1=0.f,a2=0.f;
  for(int j=t;j<2000;j+=256){
    float e=buf[j];
    float inv = 1.f / fmaxf((float)cnt0[j], 1.f);
    a0=fmaf(e, spsum[j*3+0]*inv, a0);
    a1=fmaf(e, spsum[j*3+1]*inv, a1);
    a2=fmaf(e, spsum[j*3+2]*inv, a2);
  }
  r3[t][0]=a0; r3[t][1]=a1; r3[t][2]=a2;
  __syncthreads();
  for(int st=128;st>0;st>>=1){
    if(t<st){ r3[t][0]+=r3[t+st][0]; r3[t][1]+=r3[t+st][1]; r3[t][2]+=r3[t+st][2]; }
    __syncthreads();
  }
  if(t==0){ sm[r*3+0]=r3[0][0]/S; sm[r*3+1]=r3[0][1]/S; sm[r*3+2]=r3[0][2]/S; }
}

// ---------- MFMA MLP (156->128->128->156): 64 px/block, 512 threads (8 waves) ----------
// sflat fused into staging; padded LDS strides (XS=172, AS=140) for 16-bank ds_read patterns.
#define MFMA(a,b,c) __builtin_amdgcn_mfma_f32_16x16x32_bf16((a),(b),(c),0,0,0)

__global__ __launch_bounds__(512, 4) void k_mlp_mfma(
    const float* __restrict__ Y,
    const int* __restrict__ seg0, const int* __restrict__ seg1, const int* __restrict__ seg2,
    const float* __restrict__ S0, const float* __restrict__ S1, const float* __restrict__ S2,
    const float* __restrict__ sm, const float* __restrict__ cst, float* __restrict__ Sf,
    const u16* __restrict__ P1h, const u16* __restrict__ P1l,
    const u16* __restrict__ P2h, const u16* __restrict__ P2l,
    const u16* __restrict__ P3h, const u16* __restrict__ P3l,
    const float* __restrict__ b1, const float* __restrict__ b2, const float* __restrict__ b3,
    float* __restrict__ gsum, float* __restrict__ gwsum){
  __shared__ u16 SH[64*XS];                  // X-hi [64][XS]  ->  A-hi [64][AS]
  __shared__ u16 SL[64*XS];                  // X-lo           ->  A-lo
  __shared__ float csum[480], cwsum[480];    // per-class sums [3][160]; unique writers
  __shared__ int cis[64];
  const int t = threadIdx.x;
  const int lane = t & 63, w = t >> 6;       // 8 waves
  const int g = lane >> 4, r16 = lane & 15;
  const size_t p0 = (size_t)blockIdx.x * 64;

  // inline sflat for this block's 64 pixels: Sf write + class index
  if(t < 64){
    size_t p = p0 + t;
    float a = cst[3];
    float w0=cst[0], w1=cst[1], w2=cst[2];
    int sa=seg0[p], sb=seg1[p], sc_=seg2[p];
    float f0 = w0*S0[sa*3+0] + w1*S1[sb*3+0] + w2*S2[sc_*3+0];
    float f1 = w0*S0[sa*3+1] + w1*S1[sb*3+1] + w2*S2[sc_*3+1];
    float f2 = w0*S0[sa*3+2] + w1*S1[sb*3+2] + w2*S2[sc_*3+2];
    float x0 = a*sm[sa*3+0] + (1.f-a)*f0;
    float x1 = a*sm[sa*3+1] + (1.f-a)*f1;
    float x2 = a*sm[sa*3+2] + (1.f-a)*f2;
    Sf[p*3+0]=x0; Sf[p*3+1]=x1; Sf[p*3+2]=x2;
    int c=0; float b=x0;
    if(x1>b){c=1;b=x1;}
    if(x2>b){c=2;}
    cis[t]=c;
  }
  // stage Y tile: 64 rows x 39 float4, packed bf16 hi/lo split
  for(int i=t;i<2496;i+=512){
    int row = i/39, q = i - row*39, c0 = q*4;
    float4 v = *(const float4*)(Y + (p0+row)*NB + c0);
    unsigned h01 = pkbf(v.x, v.y), h23 = pkbf(v.z, v.w);
    float l0 = v.x - __uint_as_float(h01 << 16);
    float l1 = v.y - __uint_as_float(h01 & 0xFFFF0000u);
    float l2 = v.z - __uint_as_float(h23 << 16);
    float l3 = v.w - __uint_as_float(h23 & 0xFFFF0000u);
    *(unsigned*)&SH[row*XS+c0]   = h01;
    *(unsigned*)&SH[row*XS+c0+2] = h23;
    *(unsigned*)&SL[row*XS+c0]   = pkbf(l0, l1);
    *(unsigned*)&SL[row*XS+c0+2] = pkbf(l2, l3);
  }
  if(t<128){ int row=t>>1, o=156+(t&1)*2;
    *(unsigned*)&SH[row*XS+o]=0u; *(unsigned*)&SL[row*XS+o]=0u; }
  __syncthreads();

  const int c12 = w*16 + r16;                // this wave's output column, layers 1/2

  // ---- layer 1: K=160 (5 ks), wave w -> ntile w, 4 m-tiles ----
  {
    f32x4 acc[4];
    #pragma unroll
    for(int mt=0;mt<4;mt++) acc[mt] = (f32x4){0.f,0.f,0.f,0.f};
    #pragma unroll
    for(int ks=0;ks<5;ks++){
      bfrag8 bh = *(const bfrag8*)(P1h + ((size_t)(w*5+ks))*512 + lane*8);
      bfrag8 bl = *(const bfrag8*)(P1l + ((size_t)(w*5+ks))*512 + lane*8);
      #pragma unroll
      for(int mt=0;mt<4;mt++){
        bfrag8 ah = *(const bfrag8*)(SH + (mt*16+r16)*XS + g*8 + ks*32);
        bfrag8 al = *(const bfrag8*)(SL + (mt*16+r16)*XS + g*8 + ks*32);
        acc[mt]=MFMA(ah,bh,acc[mt]); acc[mt]=MFMA(ah,bl,acc[mt]); acc[mt]=MFMA(al,bh,acc[mt]);
      }
    }
    __syncthreads();   // all waves done reading X
    float bv = b1[c12];
    #pragma unroll
    for(int mt=0;mt<4;mt++){
      float v0 = fmaxf(acc[mt][0] + bv, 0.f);
      float v1 = fmaxf(acc[mt][1] + bv, 0.f);
      float v2 = fmaxf(acc[mt][2] + bv, 0.f);
      float v3 = fmaxf(acc[mt][3] + bv, 0.f);
      unsigned h01 = pkbf(v0,v1), h23 = pkbf(v2,v3);
      float l0 = v0 - __uint_as_float(h01<<16);
      float l1 = v1 - __uint_as_float(h01 & 0xFFFF0000u);
      float l2 = v2 - __uint_as_float(h23<<16);
      float l3 = v3 - __uint_as_float(h23 & 0xFFFF0000u);
      unsigned q01 = pkbf(l0,l1), q23 = pkbf(l2,l3);
      int rb = (mt*16 + g*4)*AS + c12;
      SH[rb       ] = (u16)h01; SH[rb+AS   ] = (u16)(h01>>16);
      SH[rb+2*AS  ] = (u16)h23; SH[rb+3*AS ] = (u16)(h23>>16);
      SL[rb       ] = (u16)q01; SL[rb+AS   ] = (u16)(q01>>16);
      SL[rb+2*AS  ] = (u16)q23; SL[rb+3*AS ] = (u16)(q23>>16);
    }
  }
  __syncthreads();

  // ---- layer 2: K=128 (4 ks); regs across barrier, overwrite A ----
  {
    f32x4 acc[4];
    #pragma unroll
    for(int mt=0;mt<4;mt++) acc[mt] = (f32x4){0.f,0.f,0.f,0.f};
    #pragma unroll
    for(int ks=0;ks<4;ks++){
      bfrag8 bh = *(const bfrag8*)(P2h + ((size_t)(w*4+ks))*512 + lane*8);
      bfrag8 bl = *(const bfrag8*)(P2l + ((size_t)(w*4+ks))*512 + lane*8);
      #pragma unroll
      for(int mt=0;mt<4;mt++){
        bfrag8 ah = *(const bfrag8*)(SH + (mt*16+r16)*AS + g*8 + ks*32);
        bfrag8 al = *(const bfrag8*)(SL + (mt*16+r16)*AS + g*8 + ks*32);
        acc[mt]=MFMA(ah,bh,acc[mt]); acc[mt]=MFMA(ah,bl,acc[mt]); acc[mt]=MFMA(al,bh,acc[mt]);
      }
    }
    __syncthreads();   // all waves done reading A(layer1)
    float bv = b2[c12];
    #pragma unroll
    for(int mt=0;mt<4;mt++){
      float v0 = fmaxf(acc[mt][0] + bv, 0.f);
      float v1 = fmaxf(acc[mt][1] + bv, 0.f);
      float v2 = fmaxf(acc[mt][2] + bv, 0.f);
      float v3 = fmaxf(acc[mt][3] + bv, 0.f);
      unsigned h01 = pkbf(v0,v1), h23 = pkbf(v2,v3);
      float l0 = v0 - __uint_as_float(h01<<16);
      float l1 = v1 - __uint_as_float(h01 & 0xFFFF0000u);
      float l2 = v2 - __uint_as_float(h23<<16);
      float l3 = v3 - __uint_as_float(h23 & 0xFFFF0000u);
      unsigned q01 = pkbf(l0,l1), q23 = pkbf(l2,l3);
      int rb = (mt*16 + g*4)*AS + c12;
      SH[rb       ] = (u16)h01; SH[rb+AS   ] = (u16)(h01>>16);
      SH[rb+2*AS  ] = (u16)h23; SH[rb+3*AS ] = (u16)(h23>>16);
      SL[rb       ] = (u16)q01; SL[rb+AS   ] = (u16)(q01>>16);
      SL[rb+2*AS  ] = (u16)q23; SL[rb+3*AS ] = (u16)(q23>>16);
    }
  }
  __syncthreads();

  // ---- layer 3, phase A: primary ntile w (compute -> epilogue, acc fully consumed) ----
  {
    f32x4 acc[4];
    #pragma unroll
    for(int mt=0;mt<4;mt++) acc[mt] = (f32x4){0.f,0.f,0.f,0.f};
    #pragma unroll
    for(int ks=0;ks<4;ks++){
      bfrag8 bh = *(const bfrag8*)(P3h + ((size_t)(w*4+ks))*512 + lane*8);
      bfrag8 bl = *(const bfrag8*)(P3l + ((size_t)(w*4+ks))*512 + lane*8);
      #pragma unroll
      for(int mt=0;mt<4;mt++){
        bfrag8 ah = *(const bfrag8*)(SH + (mt*16+r16)*AS + g*8 + ks*32);
        bfrag8 al = *(const bfrag8*)(SL + (mt*16+r16)*AS + g*8 + ks*32);
        acc[mt]=MFMA(ah,bh,acc[mt]); acc[mt]=MFMA(ah,bl,acc[mt]); acc[mt]=MFMA(al,bh,acc[mt]);
      }
    }
    const int c = w*16 + r16;        // primary column, < 128
    float bv = b3[c];
    float cs0=0,cs1=0,cs2=0, cw0=0,cw1=0,cw2=0;
    #pragma unroll
    for(int mt=0;mt<4;mt++){
      #pragma unroll
      for(int r=0;r<4;r++){
        int p = mt*16 + g*4 + r;
        float e = __expf(acc[mt][r] + bv);
        float y = Y[(p0+p)*NB + c];
        float ey = e*y;
        int k = cis[p];
        cs0 += (k==0)?e:0.f;  cs1 += (k==1)?e:0.f;  cs2 += (k==2)?e:0.f;
        cw0 += (k==0)?ey:0.f; cw1 += (k==1)?ey:0.f; cw2 += (k==2)?ey:0.f;
      }
    }
    #define GRED(v) { v += __shfl_xor(v,16,64); v += __shfl_xor(v,32,64); }
    GRED(cs0) GRED(cs1) GRED(cs2) GRED(cw0) GRED(cw1) GRED(cw2)
    if(g==0){
      csum[c]       = cs0; csum[160+c]  = cs1; csum[320+c]  = cs2;
      cwsum[c]      = cw0; cwsum[160+c] = cw1; cwsum[320+c] = cw2;
    }
  }
  // ---- layer 3, phase B: secondary ntile 8+w (waves 0,1 only), fully after phase A ----
  if(w < 2){
    const int c2 = 128 + w*16 + r16;
    f32x4 acc2[4];
    #pragma unroll
    for(int mt=0;mt<4;mt++) acc2[mt] = (f32x4){0.f,0.f,0.f,0.f};
    #pragma unroll
    for(int ks=0;ks<4;ks++){
      bfrag8 bh = *(const bfrag8*)(P3h + ((size_t)((8+w)*4+ks))*512 + lane*8);
      bfrag8 bl = *(const bfrag8*)(P3l + ((size_t)((8+w)*4+ks))*512 + lane*8);
      #pragma unroll
      for(int mt=0;mt<4;mt++){
        bfrag8 ah = *(const bfrag8*)(SH + (mt*16+r16)*AS + g*8 + ks*32);
        bfrag8 al = *(const bfrag8*)(SL + (mt*16+r16)*AS + g*8 + ks*32);
        acc2[mt]=MFMA(ah,bh,acc2[mt]); acc2[mt]=MFMA(ah,bl,acc2[mt]); acc2[mt]=MFMA(al,bh,acc2[mt]);
      }
    }
    float ds0=0,ds1=0,ds2=0, dw0=0,dw1=0,dw2=0;
    if(c2 < 156){
      float bv2 = b3[c2];
      #pragma unroll
      for(int mt=0;mt<4;mt++){
        #pragma unroll
        for(int r=0;r<4;r++){
          int p = mt*16 + g*4 + r;
          float e = __expf(acc2[mt][r] + bv2);
          float y = Y[(p0+p)*NB + c2];
          float ey = e*y;
          int k = cis[p];
          ds0 += (k==0)?e:0.f;  ds1 += (k==1)?e:0.f;  ds2 += (k==2)?e:0.f;
          dw0 += (k==0)?ey:0.f; dw1 += (k==1)?ey:0.f; dw2 += (k==2)?ey:0.f;
        }
      }
    }
    GRED(ds0) GRED(ds1) GRED(ds2) GRED(dw0) GRED(dw1) GRED(dw2)
    #undef GRED
    if(g==0 && c2 < 156){
      csum[c2]       = ds0; csum[160+c2]  = ds1; csum[320+c2]  = ds2;
      cwsum[c2]      = dw0; cwsum[160+c2] = dw1; cwsum[320+c2] = dw2;
    }
  }
  __syncthreads();
  // flush to 256 rotation slots (skip unwritten cols 156..159 of each class)
  float* gs = gsum  + (size_t)(blockIdx.x & 255)*480;
  float* gw = gwsum + (size_t)(blockIdx.x & 255)*480;
  for(int i=t;i<480;i+=512){
    if((i % 160) < 156){
      atomicAdd(&gs[i], csum[i]);
      atomicAdd(&gw[i], cwsum[i]);
    }
  }
}

// ---------- final M: one block per (cls,c), 256 threads = 256 slots ----------
__global__ __launch_bounds__(256) void k_finalM(const float* __restrict__ gsump, const float* __restrict__ gwsump,
                                                float* __restrict__ M){
  __shared__ float rs[4], rw[4];
  int e = blockIdx.x;                 // 0..467
  int cls = e/156, c = e - cls*156;
  int off = cls*160 + c;
  int t = threadIdx.x, w = t>>6, lane = t&63;
  float s  = gsump[(size_t)t*480 + off];
  float wv = gwsump[(size_t)t*480 + off];
  s = waveReduceSum(s); wv = waveReduceSum(wv);
  if(lane==0){ rs[w]=s; rw[w]=wv; }
  __syncthreads();
  if(t==0){
    float S = rs[0]+rs[1]+rs[2]+rs[3];
    float W = rw[0]+rw[1]+rw[2]+rw[3];
    M[e] = (S > 0.f) ? (W / fmaxf(S, 1e-30f)) : 0.f;
  }
}

// ---------- Y_hat = S_flat @ M, float4 stores ----------
__global__ void k_yhat4(const float* __restrict__ Sf, const float* __restrict__ M, float4* __restrict__ out){
  unsigned idx = blockIdx.x*256u + threadIdx.x;   // N_PIX*39 float4s, grid exact
  unsigned p = idx / 39u, q = idx - p*39u;
  unsigned c0 = q*4u;
  float4 m0 = *(const float4*)(M + c0);
  float4 m1 = *(const float4*)(M + 156 + c0);
  float4 m2 = *(const float4*)(M + 312 + c0);
  float s0 = Sf[(size_t)p*3+0], s1 = Sf[(size_t)p*3+1], s2 = Sf[(size_t)p*3+2];
  float4 r;
  r.x = s0*m0.x + s1*m1.x + s2*m2.x;
  r.y = s0*m0.y + s1*m1.y + s2*m2.y;
  r.z = s0*m0.z + s1*m1.z + s2*m2.z;
  r.w = s0*m0.w + s1*m1.w + s2*m2.w;
  out[idx] = r;
}

extern "C" void kernel_launch(void* const* d_in, const int* in_sizes, int n_in,
                              void* d_out, int out_size, void* d_ws, size_t ws_size,
                              hipStream_t stream){
  const float* Y    = (const float*)d_in[0];
  const int*   seg0 = (const int*)d_in[1];
  const int*   A0   = (const int*)d_in[2];
  const int*   seg1 = (const int*)d_in[3];
  const int*   A1   = (const int*)d_in[4];
  const int*   seg2 = (const int*)d_in[5];
  const int*   A2   = (const int*)d_in[6];
  const float* attn = (const float*)d_in[7];
  const float* alpha= (const float*)d_in[8];
  const float* sw   = (const float*)d_in[9];
  const float* W1a[3] = {(const float*)d_in[10], (const float*)d_in[14], (const float*)d_in[18]};
  const float* b1a[3] = {(const float*)d_in[11], (const float*)d_in[15], (const float*)d_in[19]};
  const float* W2a[3] = {(const float*)d_in[12], (const float*)d_in[16], (const float*)d_in[20]};
  const float* b2a[3] = {(const float*)d_in[13], (const float*)d_in[17], (const float*)d_in[21]};
  const float* Wm1=(const float*)d_in[22]; const float* bm1=(const float*)d_in[23];
  const float* Wm2=(const float*)d_in[24]; const float* bm2=(const float*)d_in[25];
  const float* Wm3=(const float*)d_in[26]; const float* bm3=(const float*)d_in[27];
  float* out = (float*)d_out;

  char* base = (char*)d_ws;
  size_t off = 0;
  auto alloc = [&](size_t bytes)->char*{
    char* r = base + off;
    off += (bytes + 255) & ~(size_t)255;
    return r;
  };
  int* cntAll = (int*)alloc((size_t)3500*4);
  int* cnt[3] = {cntAll, cntAll+2000, cntAll+3000};
  int* offs[3]; int* cur[3]; int* lst[3];
  for(int i=0;i<3;i++) offs[i] = (int*)alloc((size_t)(i==0?2000:(i==1?1000:500))*4);
  for(int i=0;i<3;i++) cur[i]  = (int*)alloc((size_t)(i==0?2000:(i==1?1000:500))*4);
  for(int i=0;i<3;i++) lst[i]  = (int*)alloc((size_t)N_PIX*4);
  float* X_all   = (float*)alloc((size_t)3500*NB*4);
  float* Hn_all  = (float*)alloc((size_t)3500*64*4);
  float* x1b_all = (float*)alloc((size_t)3500*64*4);
  float* Hn2_all = (float*)alloc((size_t)3500*3*4);
  float* Ss_all  = (float*)alloc((size_t)3500*3*4);
  float* cst   = (float*)alloc(64);
  float* spsum = (float*)alloc((size_t)2000*3*4);
  float* smth  = (float*)alloc((size_t)2000*3*4);
  float* Sf    = (float*)alloc((size_t)N_PIX*3*4);
  u16* P1h = (u16*)alloc((size_t)20480*2); u16* P1l = (u16*)alloc((size_t)20480*2);
  u16* P2h = (u16*)alloc((size_t)16384*2); u16* P2l = (u16*)alloc((size_t)16384*2);
  u16* P3h = (u16*)alloc((size_t)20480*2); u16* P3l = (u16*)alloc((size_t)20480*2);
  float* gsump  = (float*)alloc((size_t)256*480*4);
  float* gwsump = (float*)alloc((size_t)256*480*4);
  float* Mbuf   = (float*)alloc((size_t)480*4);

  float* X0 = X_all;            float* X1 = X_all + (size_t)2000*NB;   float* X2 = X_all + (size_t)3000*NB;
  const float* Ss0 = Ss_all;    const float* Ss1 = Ss_all + 2000*3;    const float* Ss2 = Ss_all + 3000*3;

  // merged: prep + weight pre-pack + zero(gsump,gwsump,cntAll) — replaces 3 memsets + prep
  k_prep_pack<<<1199,256,0,stream>>>(sw, alpha, cst, Wm1, Wm2, Wm3,
                                     P1h,P1l,P2h,P2l,P3h,P3l, gsump, gwsump, cntAll);

  // CSR + segment means
  k_count<<<N_PIX/256,256,0,stream>>>(seg0,seg1,seg2,cnt[0],cnt[1],cnt[2]);
  k_scan<<<3,256,0,stream>>>(cnt[0],cnt[1],cnt[2],offs[0],offs[1],offs[2],cur[0],cur[1],cur[2]);
  k_fill<<<N_PIX/256,256,0,stream>>>(seg0,seg1,seg2,cur[0],cur[1],cur[2],lst[0],lst[1],lst[2]);
  k_segmean3<<<3500,192,0,stream>>>(Y,
      offs[0],cnt[0],lst[0],X0,
      offs[1],cnt[1],lst[1],X1,
      offs[2],cnt[2],lst[2],X2);

  // Multi-scale GAT encoder (batched: 4 launches total)
  k_linearB<<<(3500*64+255)/256,256,0,stream>>>(X_all, NB, 64,
      W1a[0],b1a[0],W1a[1],b1a[1],W1a[2],b1a[2], Hn_all);
  k_attn4B<64,false><<<875,256,0,stream>>>(Hn_all, A0,A1,A2, x1b_all);
  k_linearB<<<(3500*3+255)/256,256,0,stream>>>(x1b_all, 64, 3,
      W2a[0],b2a[0],W2a[1],b2a[1],W2a[2],b2a[2], Hn2_all);
  k_attn4B<3,true><<<875,256,0,stream>>>(Hn2_all, A0,A1,A2, Ss_all);

  // spsum (fused inline) + PCR
  k_spsum0<<<2000,128,0,stream>>>(seg1, seg2, Ss0, Ss1, Ss2, cst, offs[0], cnt[0], lst[0], spsum);
  k_pcr<<<2000,256,0,stream>>>(attn, spsum, cnt[0], smth);

  // ACDE: MFMA MLP (64 px/block) with sflat fused into staging
  k_mlp_mfma<<<N_PIX/64,512,0,stream>>>(Y, seg0, seg1, seg2, Ss0, Ss1, Ss2, smth, cst, Sf,
                                        P1h,P1l,P2h,P2l,P3h,P3l, bm1,bm2,bm3, gsump, gwsump);
  k_finalM<<<468,256,0,stream>>>(gsump, gwsump, Mbuf);
  k_yhat4<<<(N_PIX/256)*39,256,0,stream>>>(Sf, Mbuf, (float4*)out);
  (void)in_sizes; (void)n_in; (void)out_size;
}